// Round 1
// baseline (1636.994 us; speedup 1.0000x reference)
//
#include <hip/hip_runtime.h>
#include <hip/hip_bf16.h>

#define N_NODES 50000
#define N_EDGES 800000
#define F_IN 128
#define DIM 256
#define NUM_CLASSES 10
#define NUM_GRAPHS 256

// ---------------- CSR build ----------------

__global__ void hist_kernel(const int* __restrict__ dst, int* __restrict__ counts, int E) {
    int e = blockIdx.x * blockDim.x + threadIdx.x;
    if (e < E) atomicAdd(&counts[dst[e]], 1);
}

__global__ void scan_kernel(const int* __restrict__ counts, int* __restrict__ offs, int n) {
    __shared__ int sd[1024];
    int tid = threadIdx.x;
    int carry = 0;
    for (int base = 0; base < n; base += 1024) {
        int i = base + tid;
        int v = (i < n) ? counts[i] : 0;
        sd[tid] = v;
        __syncthreads();
        for (int off = 1; off < 1024; off <<= 1) {
            int t = (tid >= off) ? sd[tid - off] : 0;
            __syncthreads();
            sd[tid] += t;
            __syncthreads();
        }
        if (i < n) offs[i] = carry + sd[tid] - v;  // exclusive
        carry += sd[1023];
        __syncthreads();
    }
    if (tid == 0) offs[n] = carry;
}

__global__ void fill_kernel(const int* __restrict__ src, const int* __restrict__ dst,
                            const float* __restrict__ ew, const int* __restrict__ offs,
                            int* __restrict__ cursor, int* __restrict__ esrc,
                            float* __restrict__ ewl, int E) {
    int e = blockIdx.x * blockDim.x + threadIdx.x;
    if (e < E) {
        int d = dst[e];
        int pos = offs[d] + atomicAdd(&cursor[d], 1);
        esrc[pos] = src[e];
        ewl[pos] = ew[e];
    }
}

// ---------------- per-node aggregation (gather-sum) ----------------

template <int F>
__global__ void agg_kernel(const float* __restrict__ h, const int* __restrict__ offs,
                           const int* __restrict__ esrc, const float* __restrict__ ewl,
                           float* __restrict__ agg) {
    int node = blockIdx.x * (blockDim.x >> 6) + (threadIdx.x >> 6);
    if (node >= N_NODES) return;
    int lane = threadIdx.x & 63;
    int s0 = offs[node], s1 = offs[node + 1];
    if (F == 256) {
        float4 acc = {0.f, 0.f, 0.f, 0.f};
        for (int p = s0; p < s1; ++p) {
            int s = esrc[p];
            float w = ewl[p];
            float4 r = ((const float4*)(h + (size_t)s * 256))[lane];
            acc.x += w * r.x; acc.y += w * r.y; acc.z += w * r.z; acc.w += w * r.w;
        }
        ((float4*)(agg + (size_t)node * 256))[lane] = acc;
    } else {
        float2 acc = {0.f, 0.f};
        for (int p = s0; p < s1; ++p) {
            int s = esrc[p];
            float w = ewl[p];
            float2 r = ((const float2*)(h + (size_t)s * 128))[lane];
            acc.x += w * r.x; acc.y += w * r.y;
        }
        ((float2*)(agg + (size_t)node * 128))[lane] = acc;
    }
}

// ---------------- fused dual GEMM: out = relu(A1@B1 + A2@B2 + bias) ----------------
// A1,A2: [N_NODES, K] row-major.  B1,B2: [K, 256] row-major.  out: [N_NODES, 256].

__global__ __launch_bounds__(256) void gemm_dual_relu(
    const float* __restrict__ A1, const float* __restrict__ A2,
    const float* __restrict__ B1, const float* __restrict__ B2,
    const float* __restrict__ bias, float* __restrict__ out, int K) {
    __shared__ float As[16][68];
    __shared__ float Bs[16][68];
    int tid = threadIdx.x;
    int row0 = blockIdx.x * 64, col0 = blockIdx.y * 64;
    int tx = tid & 15, ty = tid >> 4;
    int arow = tid >> 2, kq = tid & 3;   // A-tile load: 64 rows x 16 k, float4 per thread
    int brow = tid >> 4, bq = tid & 15;  // B-tile load: 16 rows x 64 cols, float4 per thread
    float c[4][4] = {};
    int nt = (2 * K) / 16;
    for (int kt = 0; kt < nt; ++kt) {
        const float* A;
        const float* B;
        int kk = kt * 16;
        if (kk < K) { A = A1; B = B1; } else { A = A2; B = B2; kk -= K; }
        int rr = row0 + arow;
        if (rr >= N_NODES) rr = N_NODES - 1;
        float4 a = *(const float4*)(A + (size_t)rr * K + kk + kq * 4);
        As[kq * 4 + 0][arow] = a.x;
        As[kq * 4 + 1][arow] = a.y;
        As[kq * 4 + 2][arow] = a.z;
        As[kq * 4 + 3][arow] = a.w;
        float4 b = *(const float4*)(B + (size_t)(kk + brow) * DIM + col0 + bq * 4);
        *(float4*)(&Bs[brow][bq * 4]) = b;
        __syncthreads();
#pragma unroll
        for (int k = 0; k < 16; ++k) {
            float4 af = *(const float4*)(&As[k][ty * 4]);
            float4 bf = *(const float4*)(&Bs[k][tx * 4]);
            float a_[4] = {af.x, af.y, af.z, af.w};
            float b_[4] = {bf.x, bf.y, bf.z, bf.w};
#pragma unroll
            for (int i = 0; i < 4; ++i)
#pragma unroll
                for (int j = 0; j < 4; ++j) c[i][j] += a_[i] * b_[j];
        }
        __syncthreads();
    }
#pragma unroll
    for (int i = 0; i < 4; ++i) {
        int r = row0 + ty * 4 + i;
        if (r < N_NODES) {
            float4 bv = *(const float4*)(bias + col0 + tx * 4);
            float4 v;
            v.x = fmaxf(c[i][0] + bv.x, 0.f);
            v.y = fmaxf(c[i][1] + bv.y, 0.f);
            v.z = fmaxf(c[i][2] + bv.z, 0.f);
            v.w = fmaxf(c[i][3] + bv.w, 0.f);
            *(float4*)(out + (size_t)r * DIM + col0 + tx * 4) = v;
        }
    }
}

// ---------------- pooling over sorted batch ----------------

__global__ void pool_kernel(const float* __restrict__ h, const int* __restrict__ batch,
                            float* __restrict__ pooled) {
    int g = blockIdx.x;
    int f = threadIdx.x;  // 256 threads
    int lo = 0, hi = N_NODES;
    while (lo < hi) { int m = (lo + hi) >> 1; if (batch[m] < g) lo = m + 1; else hi = m; }
    int start = lo;
    lo = 0; hi = N_NODES;
    while (lo < hi) { int m = (lo + hi) >> 1; if (batch[m] < g + 1) lo = m + 1; else hi = m; }
    int end = lo;
    float acc = 0.f;
    for (int i = start; i < end; ++i) acc += h[(size_t)i * DIM + f];
    pooled[g * DIM + f] = acc;
}

// ---------------- FC head + log_softmax ----------------

__global__ void head_kernel(const float* __restrict__ pooled, const float* __restrict__ Wfc1,
                            const float* __restrict__ bfc1, const float* __restrict__ Wfc2,
                            const float* __restrict__ bfc2, float* __restrict__ out) {
    __shared__ float row[DIM];
    __shared__ float fc1[DIM];
    __shared__ float logits[NUM_CLASSES];
    __shared__ float red[2];
    int g = blockIdx.x, t = threadIdx.x;
    row[t] = pooled[g * DIM + t];
    __syncthreads();
    float acc = bfc1[t];
    for (int k = 0; k < DIM; ++k) acc += row[k] * Wfc1[k * DIM + t];
    fc1[t] = fmaxf(acc, 0.f);
    __syncthreads();
    if (t < NUM_CLASSES) {
        float a = bfc2[t];
        for (int k = 0; k < DIM; ++k) a += fc1[k] * Wfc2[k * NUM_CLASSES + t];
        logits[t] = a;
    }
    __syncthreads();
    if (t == 0) {
        float mx = -INFINITY;
        for (int c2 = 0; c2 < NUM_CLASSES; ++c2) mx = fmaxf(mx, logits[c2]);
        float s = 0.f;
        for (int c2 = 0; c2 < NUM_CLASSES; ++c2) s += expf(logits[c2] - mx);
        red[0] = mx;
        red[1] = logf(s);
    }
    __syncthreads();
    if (t < NUM_CLASSES) out[g * NUM_CLASSES + t] = logits[t] - red[0] - red[1];
}

// ---------------- launch ----------------

extern "C" void kernel_launch(void* const* d_in, const int* in_sizes, int n_in,
                              void* d_out, int out_size, void* d_ws, size_t ws_size,
                              hipStream_t stream) {
    const float* x = (const float*)d_in[0];
    const int* ei = (const int*)d_in[1];
    const int* batch = (const int*)d_in[2];
    const float* ew = (const float*)d_in[3];
    const float *Wr[5], *br[5], *Wo[5];
    for (int i = 0; i < 5; ++i) {
        Wr[i] = (const float*)d_in[4 + 3 * i];
        br[i] = (const float*)d_in[5 + 3 * i];
        Wo[i] = (const float*)d_in[6 + 3 * i];
    }
    const float* Wfc1 = (const float*)d_in[19];
    const float* bfc1 = (const float*)d_in[20];
    const float* Wfc2 = (const float*)d_in[21];
    const float* bfc2 = (const float*)d_in[22];
    float* out = (float*)d_out;

    char* ws = (char*)d_ws;
    size_t off = 0;
    auto alloc = [&](size_t bytes) {
        void* p = ws + off;
        off += (bytes + 255) & ~(size_t)255;
        return p;
    };
    float* h0 = (float*)alloc((size_t)N_NODES * DIM * 4);
    float* h1 = (float*)alloc((size_t)N_NODES * DIM * 4);
    float* agg = (float*)alloc((size_t)N_NODES * DIM * 4);
    int* offs = (int*)alloc((N_NODES + 1) * 4);
    int* counts = (int*)alloc((size_t)2 * N_NODES * 4);  // counts + cursor contiguous
    int* cursor = counts + N_NODES;
    int* esrc = (int*)alloc((size_t)N_EDGES * 4);
    float* ewl = (float*)alloc((size_t)N_EDGES * 4);
    float* pooled = (float*)alloc((size_t)NUM_GRAPHS * DIM * 4);

    const int* src = ei;
    const int* dstp = ei + N_EDGES;

    hipMemsetAsync(counts, 0, (size_t)2 * N_NODES * 4, stream);
    hist_kernel<<<(N_EDGES + 255) / 256, 256, 0, stream>>>(dstp, counts, N_EDGES);
    scan_kernel<<<1, 1024, 0, stream>>>(counts, offs, N_NODES);
    fill_kernel<<<(N_EDGES + 255) / 256, 256, 0, stream>>>(src, dstp, ew, offs, cursor, esrc,
                                                           ewl, N_EDGES);

    dim3 gemm_grid((N_NODES + 63) / 64, DIM / 64);

    // layer 1 (K = 128)
    agg_kernel<128><<<(N_NODES + 3) / 4, 256, 0, stream>>>(x, offs, esrc, ewl, agg);
    gemm_dual_relu<<<gemm_grid, 256, 0, stream>>>(agg, x, Wr[0], Wo[0], br[0], h0, F_IN);

    const float* hp = h0;
    float* hn = h1;
    for (int L = 1; L < 5; ++L) {
        agg_kernel<256><<<(N_NODES + 3) / 4, 256, 0, stream>>>(hp, offs, esrc, ewl, agg);
        gemm_dual_relu<<<gemm_grid, 256, 0, stream>>>(agg, hp, Wr[L], Wo[L], br[L], hn, DIM);
        float* t = (float*)hp;
        hp = hn;
        hn = t;
    }

    pool_kernel<<<NUM_GRAPHS, 256, 0, stream>>>(hp, batch, pooled);
    head_kernel<<<NUM_GRAPHS, 256, 0, stream>>>(pooled, Wfc1, bfc1, Wfc2, bfc2, out);
}

// Round 5
// 787.262 us; speedup vs baseline: 2.0794x; 2.0794x over previous
//
#include <hip/hip_runtime.h>
#include <hip/hip_bf16.h>

#define N_NODES 50000
#define N_EDGES 800000
#define F_IN 128
#define DIM 256
#define NUM_CLASSES 10
#define NUM_GRAPHS 256

typedef short bf16x8 __attribute__((ext_vector_type(8)));
typedef float f32x4 __attribute__((ext_vector_type(4)));

__device__ __forceinline__ float bf2f(unsigned short u) {
    union { unsigned int u; float f; } c;
    c.u = ((unsigned int)u) << 16;
    return c.f;
}
__device__ __forceinline__ unsigned short f2bf(float f) {
    union { float f; unsigned int u; } c;
    c.f = f;
    unsigned int r = (c.u + 0x7fffu + ((c.u >> 16) & 1u)) >> 16;
    return (unsigned short)r;
}

__device__ __forceinline__ void gload16(const unsigned short* g, unsigned short* l) {
    __builtin_amdgcn_global_load_lds(
        (const __attribute__((address_space(1))) unsigned int*)(g),
        (__attribute__((address_space(3))) unsigned int*)(l), 16, 0, 0);
}

// ---------------- CSR build ----------------

__global__ void hist_kernel(const int* __restrict__ dst, int* __restrict__ counts, int E) {
    int e = blockIdx.x * blockDim.x + threadIdx.x;
    if (e < E) atomicAdd(&counts[dst[e]], 1);
}

__global__ void scan_kernel(const int* __restrict__ counts, int* __restrict__ offs, int n) {
    __shared__ int ps[1024];
    int t = threadIdx.x;
    int chunk = (n + 1023) >> 10;
    int lo = t * chunk;
    if (lo > n) lo = n;
    int hi = lo + chunk;
    if (hi > n) hi = n;
    int s = 0;
    for (int i = lo; i < hi; ++i) s += counts[i];
    ps[t] = s;
    __syncthreads();
    for (int off = 1; off < 1024; off <<= 1) {
        int v = (t >= off) ? ps[t - off] : 0;
        __syncthreads();
        ps[t] += v;
        __syncthreads();
    }
    int run = (t == 0) ? 0 : ps[t - 1];
    for (int i = lo; i < hi; ++i) {
        offs[i] = run;
        run += counts[i];
    }
    if (t == 1023) offs[n] = ps[1023];
}

__global__ void fill_kernel(const int* __restrict__ src, const int* __restrict__ dst,
                            const float* __restrict__ ew, const int* __restrict__ offs,
                            int* __restrict__ cursor, int* __restrict__ esrc,
                            float* __restrict__ ewl, int E) {
    int e = blockIdx.x * blockDim.x + threadIdx.x;
    if (e < E) {
        int d = dst[e];
        int pos = offs[d] + atomicAdd(&cursor[d], 1);
        esrc[pos] = src[e];
        ewl[pos] = ew[e];
    }
}

// ---------------- dtype prep ----------------

__global__ void conv_x(const float* __restrict__ x, unsigned short* __restrict__ xb, int n4) {
    int i = blockIdx.x * blockDim.x + threadIdx.x;
    if (i >= n4) return;
    float4 v = ((const float4*)x)[i];
    ushort4 o;
    o.x = f2bf(v.x); o.y = f2bf(v.y); o.z = f2bf(v.z); o.w = f2bf(v.w);
    ((ushort4*)xb)[i] = o;
}

// Bt[c][k] = (k<K ? W_rel[k][c] : W_root[k-K][c]), bf16, shape [256][2K]
__global__ void pack_w(const float* __restrict__ Wr, const float* __restrict__ Wo,
                       unsigned short* __restrict__ Bt, int K) {
    int idx = blockIdx.x * blockDim.x + threadIdx.x;
    int total = 2 * K * DIM;
    if (idx >= total) return;
    int k = idx / DIM, c = idx % DIM;
    float v = (k < K) ? Wr[k * DIM + c] : Wo[(k - K) * DIM + c];
    Bt[(size_t)c * (2 * K) + k] = f2bf(v);
}

// ---------------- per-node aggregation (bf16 gather-sum) ----------------

template <int F>
__global__ void agg_bf16(const unsigned short* __restrict__ h, const int* __restrict__ offs,
                         const int* __restrict__ esrc, const float* __restrict__ ewl,
                         unsigned short* __restrict__ agg) {
    int node = blockIdx.x * (blockDim.x >> 6) + (threadIdx.x >> 6);
    if (node >= N_NODES) return;
    int lane = threadIdx.x & 63;
    int s0 = offs[node], s1 = offs[node + 1];
    if (F == 256) {
        float a0 = 0.f, a1 = 0.f, a2 = 0.f, a3 = 0.f;
        int p = s0;
        for (; p + 1 < s1; p += 2) {
            int sa = esrc[p], sb = esrc[p + 1];
            float wa = ewl[p], wb = ewl[p + 1];
            uint2 ra = *(const uint2*)(h + (size_t)sa * 256 + lane * 4);
            uint2 rb = *(const uint2*)(h + (size_t)sb * 256 + lane * 4);
            a0 += wa * bf2f((unsigned short)ra.x);
            a1 += wa * bf2f((unsigned short)(ra.x >> 16));
            a2 += wa * bf2f((unsigned short)ra.y);
            a3 += wa * bf2f((unsigned short)(ra.y >> 16));
            a0 += wb * bf2f((unsigned short)rb.x);
            a1 += wb * bf2f((unsigned short)(rb.x >> 16));
            a2 += wb * bf2f((unsigned short)rb.y);
            a3 += wb * bf2f((unsigned short)(rb.y >> 16));
        }
        if (p < s1) {
            int sa = esrc[p];
            float wa = ewl[p];
            uint2 ra = *(const uint2*)(h + (size_t)sa * 256 + lane * 4);
            a0 += wa * bf2f((unsigned short)ra.x);
            a1 += wa * bf2f((unsigned short)(ra.x >> 16));
            a2 += wa * bf2f((unsigned short)ra.y);
            a3 += wa * bf2f((unsigned short)(ra.y >> 16));
        }
        ushort4 o;
        o.x = f2bf(a0); o.y = f2bf(a1); o.z = f2bf(a2); o.w = f2bf(a3);
        *(ushort4*)(agg + (size_t)node * 256 + lane * 4) = o;
    } else {
        float a0 = 0.f, a1 = 0.f;
        int p = s0;
        for (; p + 1 < s1; p += 2) {
            int sa = esrc[p], sb = esrc[p + 1];
            float wa = ewl[p], wb = ewl[p + 1];
            unsigned int ra = *(const unsigned int*)(h + (size_t)sa * 128 + lane * 2);
            unsigned int rb = *(const unsigned int*)(h + (size_t)sb * 128 + lane * 2);
            a0 += wa * bf2f((unsigned short)ra);
            a1 += wa * bf2f((unsigned short)(ra >> 16));
            a0 += wb * bf2f((unsigned short)rb);
            a1 += wb * bf2f((unsigned short)(rb >> 16));
        }
        if (p < s1) {
            int sa = esrc[p];
            float wa = ewl[p];
            unsigned int ra = *(const unsigned int*)(h + (size_t)sa * 128 + lane * 2);
            a0 += wa * bf2f((unsigned short)ra);
            a1 += wa * bf2f((unsigned short)(ra >> 16));
        }
        ushort2 o;
        o.x = f2bf(a0); o.y = f2bf(a1);
        *(ushort2*)(agg + (size_t)node * 128 + lane * 2) = o;
    }
}

// ---------------- MFMA dual GEMM: out = relu([A1|A2] @ Bt^T + bias), bf16 ----------------
// A1,A2: [M][K] bf16 row-major. Bt: [256][2K] bf16 (pre-transposed stacked weights).
// out: [M][256] bf16.

template <int K>
__global__ __launch_bounds__(256) void gemm_mfma(
    const unsigned short* __restrict__ A1, const unsigned short* __restrict__ A2,
    const unsigned short* __restrict__ Bt, const float* __restrict__ bias,
    unsigned short* __restrict__ out) {
    __shared__ unsigned short As[128 * 32];
    __shared__ unsigned short Bs[128 * 32];
    const int t = threadIdx.x;
    const int lane = t & 63;
    const int w = t >> 6;
    const int wr = w >> 1, wc = w & 1;
    const int row0 = blockIdx.x * 128, col0 = blockIdx.y * 128;
    const int fr = lane & 15, fq = lane >> 4;

    const int srow = t >> 2;
    const int schunk = t & 3;
    int ar0 = row0 + srow;
    if (ar0 >= N_NODES) ar0 = N_NODES - 1;
    int ar1 = row0 + 64 + srow;
    if (ar1 >= N_NODES) ar1 = N_NODES - 1;
    const int bc0 = col0 + srow;
    const int bc1 = col0 + 64 + srow;

    unsigned short* asb0 = As + w * 512;         // byte w*1024
    unsigned short* asb1 = As + 2048 + w * 512;  // byte 4096 + w*1024
    unsigned short* bsb0 = Bs + w * 512;
    unsigned short* bsb1 = Bs + 2048 + w * 512;

    f32x4 acc[4][4] = {};

    constexpr int NT = (2 * K) / 32;
    for (int kt = 0; kt < NT; ++kt) {
        const int kk = kt * 32;
        const unsigned short* Ap;
        int ka;
        if (kk < K) { Ap = A1; ka = kk; } else { Ap = A2; ka = kk - K; }
        gload16(Ap + (size_t)ar0 * K + ka + schunk * 8, asb0);
        gload16(Ap + (size_t)ar1 * K + ka + schunk * 8, asb1);
        gload16(Bt + (size_t)bc0 * (2 * K) + kk + schunk * 8, bsb0);
        gload16(Bt + (size_t)bc1 * (2 * K) + kk + schunk * 8, bsb1);
        __syncthreads();
        bf16x8 a[4], b[4];
#pragma unroll
        for (int m = 0; m < 4; ++m)
            a[m] = *(const bf16x8*)(As + (wr * 64 + m * 16 + fr) * 32 + fq * 8);
#pragma unroll
        for (int n = 0; n < 4; ++n)
            b[n] = *(const bf16x8*)(Bs + (wc * 64 + n * 16 + fr) * 32 + fq * 8);
#pragma unroll
        for (int m = 0; m < 4; ++m)
#pragma unroll
            for (int n = 0; n < 4; ++n)
                acc[m][n] = __builtin_amdgcn_mfma_f32_16x16x32_bf16(a[m], b[n], acc[m][n], 0, 0, 0);
        __syncthreads();
    }

#pragma unroll
    for (int n = 0; n < 4; ++n) {
        const int col = col0 + wc * 64 + n * 16 + fr;
        const float bv = bias[col];
#pragma unroll
        for (int m = 0; m < 4; ++m) {
            const int rbase = row0 + wr * 64 + m * 16 + fq * 4;
#pragma unroll
            for (int j = 0; j < 4; ++j) {
                const int r = rbase + j;
                if (r < N_NODES)
                    out[(size_t)r * DIM + col] = f2bf(fmaxf(acc[m][n][j] + bv, 0.f));
            }
        }
    }
}

// ---------------- pooling over sorted batch (bf16 in, f32 out) ----------------

__global__ void pool_kernel(const unsigned short* __restrict__ h, const int* __restrict__ batch,
                            float* __restrict__ pooled) {
    int g = blockIdx.x;
    int f = threadIdx.x;  // 256 threads
    int lo = 0, hi = N_NODES;
    while (lo < hi) { int m = (lo + hi) >> 1; if (batch[m] < g) lo = m + 1; else hi = m; }
    int start = lo;
    lo = 0; hi = N_NODES;
    while (lo < hi) { int m = (lo + hi) >> 1; if (batch[m] < g + 1) lo = m + 1; else hi = m; }
    int end = lo;
    float acc = 0.f;
    for (int i = start; i < end; ++i) acc += bf2f(h[(size_t)i * DIM + f]);
    pooled[g * DIM + f] = acc;
}

// ---------------- FC head + log_softmax ----------------

__global__ void head_kernel(const float* __restrict__ pooled, const float* __restrict__ Wfc1,
                            const float* __restrict__ bfc1, const float* __restrict__ Wfc2,
                            const float* __restrict__ bfc2, float* __restrict__ out) {
    __shared__ float row[DIM];
    __shared__ float fc1[DIM];
    __shared__ float logits[NUM_CLASSES];
    __shared__ float red[2];
    int g = blockIdx.x, t = threadIdx.x;
    row[t] = pooled[g * DIM + t];
    __syncthreads();
    float acc = bfc1[t];
    for (int k = 0; k < DIM; ++k) acc += row[k] * Wfc1[k * DIM + t];
    fc1[t] = fmaxf(acc, 0.f);
    __syncthreads();
    if (t < NUM_CLASSES) {
        float a = bfc2[t];
        for (int k = 0; k < DIM; ++k) a += fc1[k] * Wfc2[k * NUM_CLASSES + t];
        logits[t] = a;
    }
    __syncthreads();
    if (t == 0) {
        float mx = -INFINITY;
        for (int c2 = 0; c2 < NUM_CLASSES; ++c2) mx = fmaxf(mx, logits[c2]);
        float s = 0.f;
        for (int c2 = 0; c2 < NUM_CLASSES; ++c2) s += expf(logits[c2] - mx);
        red[0] = mx;
        red[1] = logf(s);
    }
    __syncthreads();
    if (t < NUM_CLASSES) out[g * NUM_CLASSES + t] = logits[t] - red[0] - red[1];
}

// ---------------- launch ----------------

extern "C" void kernel_launch(void* const* d_in, const int* in_sizes, int n_in,
                              void* d_out, int out_size, void* d_ws, size_t ws_size,
                              hipStream_t stream) {
    const float* x = (const float*)d_in[0];
    const int* ei = (const int*)d_in[1];
    const int* batch = (const int*)d_in[2];
    const float* ew = (const float*)d_in[3];
    const float *Wr[5], *br[5], *Wo[5];
    for (int i = 0; i < 5; ++i) {
        Wr[i] = (const float*)d_in[4 + 3 * i];
        br[i] = (const float*)d_in[5 + 3 * i];
        Wo[i] = (const float*)d_in[6 + 3 * i];
    }
    const float* Wfc1 = (const float*)d_in[19];
    const float* bfc1 = (const float*)d_in[20];
    const float* Wfc2 = (const float*)d_in[21];
    const float* bfc2 = (const float*)d_in[22];
    float* out = (float*)d_out;

    char* ws = (char*)d_ws;
    size_t off = 0;
    auto alloc = [&](size_t bytes) {
        void* p = ws + off;
        off += (bytes + 255) & ~(size_t)255;
        return p;
    };
    unsigned short* xb = (unsigned short*)alloc((size_t)N_NODES * F_IN * 2);
    unsigned short* h0 = (unsigned short*)alloc((size_t)N_NODES * DIM * 2);
    unsigned short* h1 = (unsigned short*)alloc((size_t)N_NODES * DIM * 2);
    unsigned short* aggb = (unsigned short*)alloc((size_t)N_NODES * DIM * 2);
    unsigned short* Bt[5];
    Bt[0] = (unsigned short*)alloc((size_t)2 * F_IN * DIM * 2);
    for (int i = 1; i < 5; ++i) Bt[i] = (unsigned short*)alloc((size_t)2 * DIM * DIM * 2);
    int* offs = (int*)alloc((N_NODES + 1) * 4);
    int* counts = (int*)alloc((size_t)2 * N_NODES * 4);
    int* cursor = counts + N_NODES;
    int* esrc = (int*)alloc((size_t)N_EDGES * 4);
    float* ewl = (float*)alloc((size_t)N_EDGES * 4);
    float* pooled = (float*)alloc((size_t)NUM_GRAPHS * DIM * 4);

    const int* src = ei;
    const int* dstp = ei + N_EDGES;

    hipMemsetAsync(counts, 0, (size_t)2 * N_NODES * 4, stream);
    hist_kernel<<<(N_EDGES + 255) / 256, 256, 0, stream>>>(dstp, counts, N_EDGES);
    scan_kernel<<<1, 1024, 0, stream>>>(counts, offs, N_NODES);
    fill_kernel<<<(N_EDGES + 255) / 256, 256, 0, stream>>>(src, dstp, ew, offs, cursor, esrc,
                                                           ewl, N_EDGES);

    conv_x<<<((N_NODES * F_IN / 4) + 255) / 256, 256, 0, stream>>>(x, xb, N_NODES * F_IN / 4);
    pack_w<<<(2 * F_IN * DIM + 255) / 256, 256, 0, stream>>>(Wr[0], Wo[0], Bt[0], F_IN);
    for (int i = 1; i < 5; ++i)
        pack_w<<<(2 * DIM * DIM + 255) / 256, 256, 0, stream>>>(Wr[i], Wo[i], Bt[i], DIM);

    dim3 ggrid((N_NODES + 127) / 128, 2);

    // layer 1 (K = 128)
    agg_bf16<128><<<(N_NODES + 3) / 4, 256, 0, stream>>>(xb, offs, esrc, ewl, aggb);
    gemm_mfma<128><<<ggrid, 256, 0, stream>>>(aggb, xb, Bt[0], br[0], h0);

    const unsigned short* hp = h0;
    unsigned short* hn = h1;
    for (int L = 1; L < 5; ++L) {
        agg_bf16<256><<<(N_NODES + 3) / 4, 256, 0, stream>>>(hp, offs, esrc, ewl, aggb);
        gemm_mfma<256><<<ggrid, 256, 0, stream>>>(aggb, hp, Bt[L], br[L], hn);
        unsigned short* t2 = (unsigned short*)hp;
        hp = hn;
        hn = t2;
    }

    pool_kernel<<<NUM_GRAPHS, 256, 0, stream>>>(hp, batch, pooled);
    head_kernel<<<NUM_GRAPHS, 256, 0, stream>>>(pooled, Wfc1, bfc1, Wfc2, bfc2, out);
}

// Round 6
// 643.403 us; speedup vs baseline: 2.5443x; 1.2236x over previous
//
#include <hip/hip_runtime.h>
#include <hip/hip_bf16.h>

#define N_NODES 50000
#define N_EDGES 800000
#define F_IN 128
#define DIM 256
#define NUM_CLASSES 10
#define NUM_GRAPHS 256
#define NB_SCAN ((N_NODES + 255) / 256)

typedef short bf16x8 __attribute__((ext_vector_type(8)));
typedef float f32x4 __attribute__((ext_vector_type(4)));

__device__ __forceinline__ float bf2f(unsigned short u) {
    union { unsigned int u; float f; } c;
    c.u = ((unsigned int)u) << 16;
    return c.f;
}
__device__ __forceinline__ unsigned short f2bf(float f) {
    union { float f; unsigned int u; } c;
    c.f = f;
    unsigned int r = (c.u + 0x7fffu + ((c.u >> 16) & 1u)) >> 16;
    return (unsigned short)r;
}

__device__ __forceinline__ void gload16(const unsigned short* g, unsigned short* l) {
    __builtin_amdgcn_global_load_lds(
        (const __attribute__((address_space(1))) unsigned int*)(g),
        (__attribute__((address_space(3))) unsigned int*)(l), 16, 0, 0);
}

// ---------------- CSR build ----------------

__global__ void hist_kernel(const int* __restrict__ dst, int* __restrict__ counts, int E) {
    int e = blockIdx.x * blockDim.x + threadIdx.x;
    if (e < E) atomicAdd(&counts[dst[e]], 1);
}

// pass 1: per-256-chunk sums
__global__ void scan_part(const int* __restrict__ counts, int* __restrict__ bsum, int n) {
    __shared__ int sd[256];
    int t = threadIdx.x, b = blockIdx.x;
    int i = b * 256 + t;
    sd[t] = (i < n) ? counts[i] : 0;
    __syncthreads();
    for (int off = 128; off > 0; off >>= 1) {
        if (t < off) sd[t] += sd[t + off];
        __syncthreads();
    }
    if (t == 0) bsum[b] = sd[0];
}

// pass 2: exclusive scan of block sums (nb <= 256)
__global__ void scan_bsum(int* __restrict__ bsum, int nb) {
    __shared__ int sd[256];
    int t = threadIdx.x;
    int v = (t < nb) ? bsum[t] : 0;
    sd[t] = v;
    __syncthreads();
    for (int off = 1; off < 256; off <<= 1) {
        int u = (t >= off) ? sd[t - off] : 0;
        __syncthreads();
        sd[t] += u;
        __syncthreads();
    }
    if (t < nb) bsum[t] = sd[t] - v;  // exclusive
}

// pass 3: per-chunk exclusive scan + base
__global__ void scan_final(const int* __restrict__ counts, const int* __restrict__ bsum,
                           int* __restrict__ offs, int n) {
    __shared__ int sd[256];
    int t = threadIdx.x, b = blockIdx.x;
    int i = b * 256 + t;
    int v = (i < n) ? counts[i] : 0;
    sd[t] = v;
    __syncthreads();
    for (int off = 1; off < 256; off <<= 1) {
        int u = (t >= off) ? sd[t - off] : 0;
        __syncthreads();
        sd[t] += u;
        __syncthreads();
    }
    if (i < n) offs[i] = bsum[b] + sd[t] - v;
    if (i == n - 1) offs[n] = bsum[b] + sd[t];
}

__global__ void fill_kernel(const int* __restrict__ src, const int* __restrict__ dst,
                            const float* __restrict__ ew, const int* __restrict__ offs,
                            int* __restrict__ cursor, int* __restrict__ esrc,
                            float* __restrict__ ewl, int E) {
    int e = blockIdx.x * blockDim.x + threadIdx.x;
    if (e < E) {
        int d = dst[e];
        int pos = offs[d] + atomicAdd(&cursor[d], 1);
        esrc[pos] = src[e];
        ewl[pos] = ew[e];
    }
}

// ---------------- dtype prep ----------------

__global__ void conv_x(const float* __restrict__ x, unsigned short* __restrict__ xb, int n4) {
    int i = blockIdx.x * blockDim.x + threadIdx.x;
    if (i >= n4) return;
    float4 v = ((const float4*)x)[i];
    ushort4 o;
    o.x = f2bf(v.x); o.y = f2bf(v.y); o.z = f2bf(v.z); o.w = f2bf(v.w);
    ((ushort4*)xb)[i] = o;
}

// Bt[c][k] = (k<K ? W_rel[k][c] : W_root[k-K][c]), bf16, shape [256][2K]
__global__ void pack_w(const float* __restrict__ Wr, const float* __restrict__ Wo,
                       unsigned short* __restrict__ Bt, int K) {
    int idx = blockIdx.x * blockDim.x + threadIdx.x;
    int total = 2 * K * DIM;
    if (idx >= total) return;
    int k = idx / DIM, c = idx % DIM;
    float v = (k < K) ? Wr[k * DIM + c] : Wo[(k - K) * DIM + c];
    Bt[(size_t)c * (2 * K) + k] = f2bf(v);
}

// layers 2-5 share shape: one launch, blockIdx.y = layer
__global__ void pack_w4(const float* __restrict__ W2r, const float* __restrict__ W2o,
                        const float* __restrict__ W3r, const float* __restrict__ W3o,
                        const float* __restrict__ W4r, const float* __restrict__ W4o,
                        const float* __restrict__ W5r, const float* __restrict__ W5o,
                        unsigned short* __restrict__ B2, unsigned short* __restrict__ B3,
                        unsigned short* __restrict__ B4, unsigned short* __restrict__ B5) {
    int idx = blockIdx.x * blockDim.x + threadIdx.x;
    int total = 2 * DIM * DIM;
    if (idx >= total) return;
    int L = blockIdx.y;
    const float* Wr = (L == 0) ? W2r : (L == 1) ? W3r : (L == 2) ? W4r : W5r;
    const float* Wo = (L == 0) ? W2o : (L == 1) ? W3o : (L == 2) ? W4o : W5o;
    unsigned short* Bt = (L == 0) ? B2 : (L == 1) ? B3 : (L == 2) ? B4 : B5;
    int k = idx / DIM, c = idx % DIM;
    float v = (k < DIM) ? Wr[k * DIM + c] : Wo[(k - DIM) * DIM + c];
    Bt[(size_t)c * (2 * DIM) + k] = f2bf(v);
}

// ---------------- per-node aggregation (bf16 gather-sum, 4-edge unroll) ----------------

template <int F>
__global__ void agg_bf16(const unsigned short* __restrict__ h, const int* __restrict__ offs,
                         const int* __restrict__ esrc, const float* __restrict__ ewl,
                         unsigned short* __restrict__ agg) {
    int node = blockIdx.x * (blockDim.x >> 6) + (threadIdx.x >> 6);
    if (node >= N_NODES) return;
    int lane = threadIdx.x & 63;
    int s0 = offs[node], s1 = offs[node + 1];
    if (F == 256) {
        const unsigned short* hb = h + lane * 4;
        float a0 = 0.f, a1 = 0.f, a2 = 0.f, a3 = 0.f;
        float b0 = 0.f, b1 = 0.f, b2 = 0.f, b3 = 0.f;
        int p = s0;
        for (; p + 3 < s1; p += 4) {
            int s_0 = esrc[p], s_1 = esrc[p + 1], s_2 = esrc[p + 2], s_3 = esrc[p + 3];
            float w0 = ewl[p], w1 = ewl[p + 1], w2 = ewl[p + 2], w3 = ewl[p + 3];
            uint2 r0 = *(const uint2*)(hb + (size_t)s_0 * 256);
            uint2 r1 = *(const uint2*)(hb + (size_t)s_1 * 256);
            uint2 r2 = *(const uint2*)(hb + (size_t)s_2 * 256);
            uint2 r3 = *(const uint2*)(hb + (size_t)s_3 * 256);
            a0 += w0 * bf2f((unsigned short)r0.x);
            a1 += w0 * bf2f((unsigned short)(r0.x >> 16));
            a2 += w0 * bf2f((unsigned short)r0.y);
            a3 += w0 * bf2f((unsigned short)(r0.y >> 16));
            b0 += w1 * bf2f((unsigned short)r1.x);
            b1 += w1 * bf2f((unsigned short)(r1.x >> 16));
            b2 += w1 * bf2f((unsigned short)r1.y);
            b3 += w1 * bf2f((unsigned short)(r1.y >> 16));
            a0 += w2 * bf2f((unsigned short)r2.x);
            a1 += w2 * bf2f((unsigned short)(r2.x >> 16));
            a2 += w2 * bf2f((unsigned short)r2.y);
            a3 += w2 * bf2f((unsigned short)(r2.y >> 16));
            b0 += w3 * bf2f((unsigned short)r3.x);
            b1 += w3 * bf2f((unsigned short)(r3.x >> 16));
            b2 += w3 * bf2f((unsigned short)r3.y);
            b3 += w3 * bf2f((unsigned short)(r3.y >> 16));
        }
        for (; p < s1; ++p) {
            int sa = esrc[p];
            float wa = ewl[p];
            uint2 ra = *(const uint2*)(hb + (size_t)sa * 256);
            a0 += wa * bf2f((unsigned short)ra.x);
            a1 += wa * bf2f((unsigned short)(ra.x >> 16));
            a2 += wa * bf2f((unsigned short)ra.y);
            a3 += wa * bf2f((unsigned short)(ra.y >> 16));
        }
        a0 += b0; a1 += b1; a2 += b2; a3 += b3;
        ushort4 o;
        o.x = f2bf(a0); o.y = f2bf(a1); o.z = f2bf(a2); o.w = f2bf(a3);
        *(ushort4*)(agg + (size_t)node * 256 + lane * 4) = o;
    } else {
        const unsigned short* hb = h + lane * 2;
        float a0 = 0.f, a1 = 0.f, b0 = 0.f, b1 = 0.f;
        int p = s0;
        for (; p + 3 < s1; p += 4) {
            int s_0 = esrc[p], s_1 = esrc[p + 1], s_2 = esrc[p + 2], s_3 = esrc[p + 3];
            float w0 = ewl[p], w1 = ewl[p + 1], w2 = ewl[p + 2], w3 = ewl[p + 3];
            unsigned int r0 = *(const unsigned int*)(hb + (size_t)s_0 * 128);
            unsigned int r1 = *(const unsigned int*)(hb + (size_t)s_1 * 128);
            unsigned int r2 = *(const unsigned int*)(hb + (size_t)s_2 * 128);
            unsigned int r3 = *(const unsigned int*)(hb + (size_t)s_3 * 128);
            a0 += w0 * bf2f((unsigned short)r0);
            a1 += w0 * bf2f((unsigned short)(r0 >> 16));
            b0 += w1 * bf2f((unsigned short)r1);
            b1 += w1 * bf2f((unsigned short)(r1 >> 16));
            a0 += w2 * bf2f((unsigned short)r2);
            a1 += w2 * bf2f((unsigned short)(r2 >> 16));
            b0 += w3 * bf2f((unsigned short)r3);
            b1 += w3 * bf2f((unsigned short)(r3 >> 16));
        }
        for (; p < s1; ++p) {
            int sa = esrc[p];
            float wa = ewl[p];
            unsigned int ra = *(const unsigned int*)(hb + (size_t)sa * 128);
            a0 += wa * bf2f((unsigned short)ra);
            a1 += wa * bf2f((unsigned short)(ra >> 16));
        }
        a0 += b0; a1 += b1;
        ushort2 o;
        o.x = f2bf(a0); o.y = f2bf(a1);
        *(ushort2*)(agg + (size_t)node * 128 + lane * 2) = o;
    }
}

// ---------------- MFMA dual GEMM: out = relu([A1|A2] @ Bt^T + bias), bf16 ----------------

template <int K>
__global__ __launch_bounds__(256) void gemm_mfma(
    const unsigned short* __restrict__ A1, const unsigned short* __restrict__ A2,
    const unsigned short* __restrict__ Bt, const float* __restrict__ bias,
    unsigned short* __restrict__ out) {
    __shared__ unsigned short As[128 * 32];
    __shared__ unsigned short Bs[128 * 32];
    const int t = threadIdx.x;
    const int lane = t & 63;
    const int w = t >> 6;
    const int wr = w >> 1, wc = w & 1;
    const int row0 = blockIdx.x * 128, col0 = blockIdx.y * 128;
    const int fr = lane & 15, fq = lane >> 4;

    const int srow = t >> 2;
    const int schunk = t & 3;
    int ar0 = row0 + srow;
    if (ar0 >= N_NODES) ar0 = N_NODES - 1;
    int ar1 = row0 + 64 + srow;
    if (ar1 >= N_NODES) ar1 = N_NODES - 1;
    const int bc0 = col0 + srow;
    const int bc1 = col0 + 64 + srow;

    unsigned short* asb0 = As + w * 512;
    unsigned short* asb1 = As + 2048 + w * 512;
    unsigned short* bsb0 = Bs + w * 512;
    unsigned short* bsb1 = Bs + 2048 + w * 512;

    f32x4 acc[4][4] = {};

    constexpr int NT = (2 * K) / 32;
    for (int kt = 0; kt < NT; ++kt) {
        const int kk = kt * 32;
        const unsigned short* Ap;
        int ka;
        if (kk < K) { Ap = A1; ka = kk; } else { Ap = A2; ka = kk - K; }
        gload16(Ap + (size_t)ar0 * K + ka + schunk * 8, asb0);
        gload16(Ap + (size_t)ar1 * K + ka + schunk * 8, asb1);
        gload16(Bt + (size_t)bc0 * (2 * K) + kk + schunk * 8, bsb0);
        gload16(Bt + (size_t)bc1 * (2 * K) + kk + schunk * 8, bsb1);
        __syncthreads();
        bf16x8 a[4], b[4];
#pragma unroll
        for (int m = 0; m < 4; ++m)
            a[m] = *(const bf16x8*)(As + (wr * 64 + m * 16 + fr) * 32 + fq * 8);
#pragma unroll
        for (int n = 0; n < 4; ++n)
            b[n] = *(const bf16x8*)(Bs + (wc * 64 + n * 16 + fr) * 32 + fq * 8);
#pragma unroll
        for (int m = 0; m < 4; ++m)
#pragma unroll
            for (int n = 0; n < 4; ++n)
                acc[m][n] = __builtin_amdgcn_mfma_f32_16x16x32_bf16(a[m], b[n], acc[m][n], 0, 0, 0);
        __syncthreads();
    }

#pragma unroll
    for (int n = 0; n < 4; ++n) {
        const int col = col0 + wc * 64 + n * 16 + fr;
        const float bv = bias[col];
#pragma unroll
        for (int m = 0; m < 4; ++m) {
            const int rbase = row0 + wr * 64 + m * 16 + fq * 4;
#pragma unroll
            for (int j = 0; j < 4; ++j) {
                const int r = rbase + j;
                if (r < N_NODES)
                    out[(size_t)r * DIM + col] = f2bf(fmaxf(acc[m][n][j] + bv, 0.f));
            }
        }
    }
}

// ---------------- pooling over sorted batch (wave-per-row, 4 rows in flight) ----------------

__global__ void pool_kernel(const unsigned short* __restrict__ h, const int* __restrict__ batch,
                            float* __restrict__ pooled) {
    __shared__ float4 sd[4][64];
    int g = blockIdx.x;
    int t = threadIdx.x;
    int wv = t >> 6, lane = t & 63;
    int lo = 0, hi = N_NODES;
    while (lo < hi) { int m = (lo + hi) >> 1; if (batch[m] < g) lo = m + 1; else hi = m; }
    int start = lo;
    lo = 0; hi = N_NODES;
    while (lo < hi) { int m = (lo + hi) >> 1; if (batch[m] < g + 1) lo = m + 1; else hi = m; }
    int end = lo;
    float4 acc = {0.f, 0.f, 0.f, 0.f};
    for (int i = start + wv; i < end; i += 4) {
        uint2 r = *(const uint2*)(h + (size_t)i * 256 + lane * 4);
        acc.x += bf2f((unsigned short)r.x);
        acc.y += bf2f((unsigned short)(r.x >> 16));
        acc.z += bf2f((unsigned short)r.y);
        acc.w += bf2f((unsigned short)(r.y >> 16));
    }
    sd[wv][lane] = acc;
    __syncthreads();
    if (wv == 0) {
        float4 a = sd[0][lane], b = sd[1][lane], c = sd[2][lane], d = sd[3][lane];
        float4 s;
        s.x = a.x + b.x + c.x + d.x;
        s.y = a.y + b.y + c.y + d.y;
        s.z = a.z + b.z + c.z + d.z;
        s.w = a.w + b.w + c.w + d.w;
        *(float4*)(pooled + g * DIM + lane * 4) = s;
    }
}

// ---------------- FC head + log_softmax ----------------

__global__ void head_kernel(const float* __restrict__ pooled, const float* __restrict__ Wfc1,
                            const float* __restrict__ bfc1, const float* __restrict__ Wfc2,
                            const float* __restrict__ bfc2, float* __restrict__ out) {
    __shared__ float row[DIM];
    __shared__ float fc1[DIM];
    __shared__ float logits[NUM_CLASSES];
    __shared__ float red[2];
    int g = blockIdx.x, t = threadIdx.x;
    row[t] = pooled[g * DIM + t];
    __syncthreads();
    float acc = bfc1[t];
    for (int k = 0; k < DIM; ++k) acc += row[k] * Wfc1[k * DIM + t];
    fc1[t] = fmaxf(acc, 0.f);
    __syncthreads();
    if (t < NUM_CLASSES) {
        float a = bfc2[t];
        for (int k = 0; k < DIM; ++k) a += fc1[k] * Wfc2[k * NUM_CLASSES + t];
        logits[t] = a;
    }
    __syncthreads();
    if (t == 0) {
        float mx = -INFINITY;
        for (int c2 = 0; c2 < NUM_CLASSES; ++c2) mx = fmaxf(mx, logits[c2]);
        float s = 0.f;
        for (int c2 = 0; c2 < NUM_CLASSES; ++c2) s += expf(logits[c2] - mx);
        red[0] = mx;
        red[1] = logf(s);
    }
    __syncthreads();
    if (t < NUM_CLASSES) out[g * NUM_CLASSES + t] = logits[t] - red[0] - red[1];
}

// ---------------- launch ----------------

extern "C" void kernel_launch(void* const* d_in, const int* in_sizes, int n_in,
                              void* d_out, int out_size, void* d_ws, size_t ws_size,
                              hipStream_t stream) {
    const float* x = (const float*)d_in[0];
    const int* ei = (const int*)d_in[1];
    const int* batch = (const int*)d_in[2];
    const float* ew = (const float*)d_in[3];
    const float *Wr[5], *br[5], *Wo[5];
    for (int i = 0; i < 5; ++i) {
        Wr[i] = (const float*)d_in[4 + 3 * i];
        br[i] = (const float*)d_in[5 + 3 * i];
        Wo[i] = (const float*)d_in[6 + 3 * i];
    }
    const float* Wfc1 = (const float*)d_in[19];
    const float* bfc1 = (const float*)d_in[20];
    const float* Wfc2 = (const float*)d_in[21];
    const float* bfc2 = (const float*)d_in[22];
    float* out = (float*)d_out;

    char* ws = (char*)d_ws;
    size_t off = 0;
    auto alloc = [&](size_t bytes) {
        void* p = ws + off;
        off += (bytes + 255) & ~(size_t)255;
        return p;
    };
    unsigned short* xb = (unsigned short*)alloc((size_t)N_NODES * F_IN * 2);
    unsigned short* h0 = (unsigned short*)alloc((size_t)N_NODES * DIM * 2);
    unsigned short* h1 = (unsigned short*)alloc((size_t)N_NODES * DIM * 2);
    unsigned short* aggb = (unsigned short*)alloc((size_t)N_NODES * DIM * 2);
    unsigned short* Bt[5];
    Bt[0] = (unsigned short*)alloc((size_t)2 * F_IN * DIM * 2);
    for (int i = 1; i < 5; ++i) Bt[i] = (unsigned short*)alloc((size_t)2 * DIM * DIM * 2);
    int* offs = (int*)alloc((N_NODES + 1) * 4);
    int* counts = (int*)alloc((size_t)2 * N_NODES * 4);
    int* cursor = counts + N_NODES;
    int* bsum = (int*)alloc(NB_SCAN * 4);
    int* esrc = (int*)alloc((size_t)N_EDGES * 4);
    float* ewl = (float*)alloc((size_t)N_EDGES * 4);
    float* pooled = (float*)alloc((size_t)NUM_GRAPHS * DIM * 4);

    const int* src = ei;
    const int* dstp = ei + N_EDGES;

    hipMemsetAsync(counts, 0, (size_t)2 * N_NODES * 4, stream);
    hist_kernel<<<(N_EDGES + 255) / 256, 256, 0, stream>>>(dstp, counts, N_EDGES);
    scan_part<<<NB_SCAN, 256, 0, stream>>>(counts, bsum, N_NODES);
    scan_bsum<<<1, 256, 0, stream>>>(bsum, NB_SCAN);
    scan_final<<<NB_SCAN, 256, 0, stream>>>(counts, bsum, offs, N_NODES);
    fill_kernel<<<(N_EDGES + 255) / 256, 256, 0, stream>>>(src, dstp, ew, offs, cursor, esrc,
                                                           ewl, N_EDGES);

    conv_x<<<((N_NODES * F_IN / 4) + 255) / 256, 256, 0, stream>>>(x, xb, N_NODES * F_IN / 4);
    pack_w<<<(2 * F_IN * DIM + 255) / 256, 256, 0, stream>>>(Wr[0], Wo[0], Bt[0], F_IN);
    {
        dim3 pg((2 * DIM * DIM + 255) / 256, 4);
        pack_w4<<<pg, 256, 0, stream>>>(Wr[1], Wo[1], Wr[2], Wo[2], Wr[3], Wo[3], Wr[4], Wo[4],
                                        Bt[1], Bt[2], Bt[3], Bt[4]);
    }

    dim3 ggrid((N_NODES + 127) / 128, 2);

    // layer 1 (K = 128)
    agg_bf16<128><<<(N_NODES + 3) / 4, 256, 0, stream>>>(xb, offs, esrc, ewl, aggb);
    gemm_mfma<128><<<ggrid, 256, 0, stream>>>(aggb, xb, Bt[0], br[0], h0);

    const unsigned short* hp = h0;
    unsigned short* hn = h1;
    for (int L = 1; L < 5; ++L) {
        agg_bf16<256><<<(N_NODES + 3) / 4, 256, 0, stream>>>(hp, offs, esrc, ewl, aggb);
        gemm_mfma<256><<<ggrid, 256, 0, stream>>>(aggb, hp, Bt[L], br[L], hn);
        unsigned short* t2 = (unsigned short*)hp;
        hp = hn;
        hn = t2;
    }

    pool_kernel<<<NUM_GRAPHS, 256, 0, stream>>>(hp, batch, pooled);
    head_kernel<<<NUM_GRAPHS, 256, 0, stream>>>(pooled, Wfc1, bfc1, Wfc2, bfc2, out);
}

// Round 9
// 630.651 us; speedup vs baseline: 2.5957x; 1.0202x over previous
//
#include <hip/hip_runtime.h>
#include <hip/hip_bf16.h>

#define N_NODES 50000
#define N_EDGES 800000
#define F_IN 128
#define DIM 256
#define NUM_CLASSES 10
#define NUM_GRAPHS 256
#define NB_SCAN ((N_NODES + 255) / 256)

typedef short bf16x8 __attribute__((ext_vector_type(8)));
typedef float f32x4 __attribute__((ext_vector_type(4)));

__device__ __forceinline__ float bf2f(unsigned short u) {
    union { unsigned int u; float f; } c;
    c.u = ((unsigned int)u) << 16;
    return c.f;
}
__device__ __forceinline__ unsigned short f2bf(float f) {
    union { float f; unsigned int u; } c;
    c.f = f;
    unsigned int r = (c.u + 0x7fffu + ((c.u >> 16) & 1u)) >> 16;
    return (unsigned short)r;
}
__device__ __forceinline__ float u2f(unsigned int u) {
    union { unsigned int u; float f; } c;
    c.u = u;
    return c.f;
}
__device__ __forceinline__ unsigned int f2u(float f) {
    union { float f; unsigned int u; } c;
    c.f = f;
    return c.u;
}

__device__ __forceinline__ void gload16(const unsigned short* g, unsigned short* l) {
    __builtin_amdgcn_global_load_lds(
        (const __attribute__((address_space(1))) unsigned int*)(g),
        (__attribute__((address_space(3))) unsigned int*)(l), 16, 0, 0);
}

// ---------------- CSR build ----------------

__global__ void hist_kernel(const int* __restrict__ dst, int* __restrict__ counts, int E) {
    int e = blockIdx.x * blockDim.x + threadIdx.x;
    if (e < E) atomicAdd(&counts[dst[e]], 1);
}

// pass 1: per-256-chunk sums
__global__ void scan_part(const int* __restrict__ counts, int* __restrict__ bsum, int n) {
    __shared__ int sd[256];
    int t = threadIdx.x, b = blockIdx.x;
    int i = b * 256 + t;
    sd[t] = (i < n) ? counts[i] : 0;
    __syncthreads();
    for (int off = 128; off > 0; off >>= 1) {
        if (t < off) sd[t] += sd[t + off];
        __syncthreads();
    }
    if (t == 0) bsum[b] = sd[0];
}

// pass 2: exclusive scan of block sums (nb <= 256)
__global__ void scan_bsum(int* __restrict__ bsum, int nb) {
    __shared__ int sd[256];
    int t = threadIdx.x;
    int v = (t < nb) ? bsum[t] : 0;
    sd[t] = v;
    __syncthreads();
    for (int off = 1; off < 256; off <<= 1) {
        int u = (t >= off) ? sd[t - off] : 0;
        __syncthreads();
        sd[t] += u;
        __syncthreads();
    }
    if (t < nb) bsum[t] = sd[t] - v;  // exclusive
}

// pass 3: per-chunk exclusive scan + base
__global__ void scan_final(const int* __restrict__ counts, const int* __restrict__ bsum,
                           int* __restrict__ offs, int n) {
    __shared__ int sd[256];
    int t = threadIdx.x, b = blockIdx.x;
    int i = b * 256 + t;
    int v = (i < n) ? counts[i] : 0;
    sd[t] = v;
    __syncthreads();
    for (int off = 1; off < 256; off <<= 1) {
        int u = (t >= off) ? sd[t - off] : 0;
        __syncthreads();
        sd[t] += u;
        __syncthreads();
    }
    if (i < n) offs[i] = bsum[b] + sd[t] - v;
    if (i == n - 1) offs[n] = bsum[b] + sd[t];
}

// scatter (src, weight) packed as one 8-byte store into a single buffer
__global__ void fill_kernel(const int* __restrict__ src, const int* __restrict__ dst,
                            const float* __restrict__ ew, const int* __restrict__ offs,
                            int* __restrict__ cursor, uint2* __restrict__ edata, int E) {
    int e = blockIdx.x * blockDim.x + threadIdx.x;
    if (e < E) {
        int d = dst[e];
        int pos = offs[d] + atomicAdd(&cursor[d], 1);
        edata[pos] = make_uint2((unsigned int)src[e], f2u(ew[e]));
    }
}

// ---------------- dtype prep ----------------

__global__ void conv_x(const float* __restrict__ x, unsigned short* __restrict__ xb, int n4) {
    int i = blockIdx.x * blockDim.x + threadIdx.x;
    if (i >= n4) return;
    float4 v = ((const float4*)x)[i];
    ushort4 o;
    o.x = f2bf(v.x); o.y = f2bf(v.y); o.z = f2bf(v.z); o.w = f2bf(v.w);
    ((ushort4*)xb)[i] = o;
}

// Bt[c][k] = (k<K ? W_rel[k][c] : W_root[k-K][c]), bf16, shape [256][2K]
__global__ void pack_w(const float* __restrict__ Wr, const float* __restrict__ Wo,
                       unsigned short* __restrict__ Bt, int K) {
    int idx = blockIdx.x * blockDim.x + threadIdx.x;
    int total = 2 * K * DIM;
    if (idx >= total) return;
    int k = idx / DIM, c = idx % DIM;
    float v = (k < K) ? Wr[k * DIM + c] : Wo[(k - K) * DIM + c];
    Bt[(size_t)c * (2 * K) + k] = f2bf(v);
}

// layers 2-5 share shape: one launch, blockIdx.y = layer
__global__ void pack_w4(const float* __restrict__ W2r, const float* __restrict__ W2o,
                        const float* __restrict__ W3r, const float* __restrict__ W3o,
                        const float* __restrict__ W4r, const float* __restrict__ W4o,
                        const float* __restrict__ W5r, const float* __restrict__ W5o,
                        unsigned short* __restrict__ B2, unsigned short* __restrict__ B3,
                        unsigned short* __restrict__ B4, unsigned short* __restrict__ B5) {
    int idx = blockIdx.x * blockDim.x + threadIdx.x;
    int total = 2 * DIM * DIM;
    if (idx >= total) return;
    int L = blockIdx.y;
    const float* Wr = (L == 0) ? W2r : (L == 1) ? W3r : (L == 2) ? W4r : W5r;
    const float* Wo = (L == 0) ? W2o : (L == 1) ? W3o : (L == 2) ? W4o : W5o;
    unsigned short* Bt = (L == 0) ? B2 : (L == 1) ? B3 : (L == 2) ? B4 : B5;
    int k = idx / DIM, c = idx % DIM;
    float v = (k < DIM) ? Wr[k * DIM + c] : Wo[(k - DIM) * DIM + c];
    Bt[(size_t)c * (2 * DIM) + k] = f2bf(v);
}

// ---------------- per-node aggregation (bf16 gather-sum, 4-edge unroll, packed edata) ----------------

template <int F>
__global__ void agg_bf16(const unsigned short* __restrict__ h, const int* __restrict__ offs,
                         const uint2* __restrict__ edata, unsigned short* __restrict__ agg) {
    int node = blockIdx.x * (blockDim.x >> 6) + (threadIdx.x >> 6);
    if (node >= N_NODES) return;
    int lane = threadIdx.x & 63;
    int s0 = offs[node], s1 = offs[node + 1];
    if (F == 256) {
        const unsigned short* hb = h + lane * 4;
        float a0 = 0.f, a1 = 0.f, a2 = 0.f, a3 = 0.f;
        float b0 = 0.f, b1 = 0.f, b2 = 0.f, b3 = 0.f;
        int p = s0;
        for (; p + 3 < s1; p += 4) {
            uint2 e0 = edata[p], e1 = edata[p + 1], e2 = edata[p + 2], e3 = edata[p + 3];
            float w0 = u2f(e0.y), w1 = u2f(e1.y), w2 = u2f(e2.y), w3 = u2f(e3.y);
            uint2 r0 = *(const uint2*)(hb + (size_t)e0.x * 256);
            uint2 r1 = *(const uint2*)(hb + (size_t)e1.x * 256);
            uint2 r2 = *(const uint2*)(hb + (size_t)e2.x * 256);
            uint2 r3 = *(const uint2*)(hb + (size_t)e3.x * 256);
            a0 += w0 * bf2f((unsigned short)r0.x);
            a1 += w0 * bf2f((unsigned short)(r0.x >> 16));
            a2 += w0 * bf2f((unsigned short)r0.y);
            a3 += w0 * bf2f((unsigned short)(r0.y >> 16));
            b0 += w1 * bf2f((unsigned short)r1.x);
            b1 += w1 * bf2f((unsigned short)(r1.x >> 16));
            b2 += w1 * bf2f((unsigned short)r1.y);
            b3 += w1 * bf2f((unsigned short)(r1.y >> 16));
            a0 += w2 * bf2f((unsigned short)r2.x);
            a1 += w2 * bf2f((unsigned short)(r2.x >> 16));
            a2 += w2 * bf2f((unsigned short)r2.y);
            a3 += w2 * bf2f((unsigned short)(r2.y >> 16));
            b0 += w3 * bf2f((unsigned short)r3.x);
            b1 += w3 * bf2f((unsigned short)(r3.x >> 16));
            b2 += w3 * bf2f((unsigned short)r3.y);
            b3 += w3 * bf2f((unsigned short)(r3.y >> 16));
        }
        for (; p < s1; ++p) {
            uint2 e0 = edata[p];
            float wa = u2f(e0.y);
            uint2 ra = *(const uint2*)(hb + (size_t)e0.x * 256);
            a0 += wa * bf2f((unsigned short)ra.x);
            a1 += wa * bf2f((unsigned short)(ra.x >> 16));
            a2 += wa * bf2f((unsigned short)ra.y);
            a3 += wa * bf2f((unsigned short)(ra.y >> 16));
        }
        a0 += b0; a1 += b1; a2 += b2; a3 += b3;
        ushort4 o;
        o.x = f2bf(a0); o.y = f2bf(a1); o.z = f2bf(a2); o.w = f2bf(a3);
        *(ushort4*)(agg + (size_t)node * 256 + lane * 4) = o;
    } else {
        const unsigned short* hb = h + lane * 2;
        float a0 = 0.f, a1 = 0.f, b0 = 0.f, b1 = 0.f;
        int p = s0;
        for (; p + 3 < s1; p += 4) {
            uint2 e0 = edata[p], e1 = edata[p + 1], e2 = edata[p + 2], e3 = edata[p + 3];
            float w0 = u2f(e0.y), w1 = u2f(e1.y), w2 = u2f(e2.y), w3 = u2f(e3.y);
            unsigned int r0 = *(const unsigned int*)(hb + (size_t)e0.x * 128);
            unsigned int r1 = *(const unsigned int*)(hb + (size_t)e1.x * 128);
            unsigned int r2 = *(const unsigned int*)(hb + (size_t)e2.x * 128);
            unsigned int r3 = *(const unsigned int*)(hb + (size_t)e3.x * 128);
            a0 += w0 * bf2f((unsigned short)r0);
            a1 += w0 * bf2f((unsigned short)(r0 >> 16));
            b0 += w1 * bf2f((unsigned short)r1);
            b1 += w1 * bf2f((unsigned short)(r1 >> 16));
            a0 += w2 * bf2f((unsigned short)r2);
            a1 += w2 * bf2f((unsigned short)(r2 >> 16));
            b0 += w3 * bf2f((unsigned short)r3);
            b1 += w3 * bf2f((unsigned short)(r3 >> 16));
        }
        for (; p < s1; ++p) {
            uint2 e0 = edata[p];
            float wa = u2f(e0.y);
            unsigned int ra = *(const unsigned int*)(hb + (size_t)e0.x * 128);
            a0 += wa * bf2f((unsigned short)ra);
            a1 += wa * bf2f((unsigned short)(ra >> 16));
        }
        a0 += b0; a1 += b1;
        ushort2 o;
        o.x = f2bf(a0); o.y = f2bf(a1);
        *(ushort2*)(agg + (size_t)node * 128 + lane * 2) = o;
    }
}

// ---------------- MFMA dual GEMM: out = relu([A1|A2] @ Bt^T + bias), bf16 ----------------

template <int K>
__global__ __launch_bounds__(256) void gemm_mfma(
    const unsigned short* __restrict__ A1, const unsigned short* __restrict__ A2,
    const unsigned short* __restrict__ Bt, const float* __restrict__ bias,
    unsigned short* __restrict__ out) {
    __shared__ unsigned short As[128 * 32];
    __shared__ unsigned short Bs[128 * 32];
    const int t = threadIdx.x;
    const int lane = t & 63;
    const int w = t >> 6;
    const int wr = w >> 1, wc = w & 1;
    const int row0 = blockIdx.x * 128, col0 = blockIdx.y * 128;
    const int fr = lane & 15, fq = lane >> 4;

    const int srow = t >> 2;
    const int schunk = t & 3;
    int ar0 = row0 + srow;
    if (ar0 >= N_NODES) ar0 = N_NODES - 1;
    int ar1 = row0 + 64 + srow;
    if (ar1 >= N_NODES) ar1 = N_NODES - 1;
    const int bc0 = col0 + srow;
    const int bc1 = col0 + 64 + srow;

    unsigned short* asb0 = As + w * 512;
    unsigned short* asb1 = As + 2048 + w * 512;
    unsigned short* bsb0 = Bs + w * 512;
    unsigned short* bsb1 = Bs + 2048 + w * 512;

    f32x4 acc[4][4] = {};

    constexpr int NT = (2 * K) / 32;
    for (int kt = 0; kt < NT; ++kt) {
        const int kk = kt * 32;
        const unsigned short* Ap;
        int ka;
        if (kk < K) { Ap = A1; ka = kk; } else { Ap = A2; ka = kk - K; }
        gload16(Ap + (size_t)ar0 * K + ka + schunk * 8, asb0);
        gload16(Ap + (size_t)ar1 * K + ka + schunk * 8, asb1);
        gload16(Bt + (size_t)bc0 * (2 * K) + kk + schunk * 8, bsb0);
        gload16(Bt + (size_t)bc1 * (2 * K) + kk + schunk * 8, bsb1);
        __syncthreads();
        bf16x8 a[4], b[4];
#pragma unroll
        for (int m = 0; m < 4; ++m)
            a[m] = *(const bf16x8*)(As + (wr * 64 + m * 16 + fr) * 32 + fq * 8);
#pragma unroll
        for (int n = 0; n < 4; ++n)
            b[n] = *(const bf16x8*)(Bs + (wc * 64 + n * 16 + fr) * 32 + fq * 8);
#pragma unroll
        for (int m = 0; m < 4; ++m)
#pragma unroll
            for (int n = 0; n < 4; ++n)
                acc[m][n] = __builtin_amdgcn_mfma_f32_16x16x32_bf16(a[m], b[n], acc[m][n], 0, 0, 0);
        __syncthreads();
    }

#pragma unroll
    for (int n = 0; n < 4; ++n) {
        const int col = col0 + wc * 64 + n * 16 + fr;
        const float bv = bias[col];
#pragma unroll
        for (int m = 0; m < 4; ++m) {
            const int rbase = row0 + wr * 64 + m * 16 + fq * 4;
#pragma unroll
            for (int j = 0; j < 4; ++j) {
                const int r = rbase + j;
                if (r < N_NODES)
                    out[(size_t)r * DIM + col] = f2bf(fmaxf(acc[m][n][j] + bv, 0.f));
            }
        }
    }
}

// ---------------- pooling over sorted batch (wave-per-row, 4 rows in flight) ----------------

__global__ void pool_kernel(const unsigned short* __restrict__ h, const int* __restrict__ batch,
                            float* __restrict__ pooled) {
    __shared__ float4 sd[4][64];
    int g = blockIdx.x;
    int t = threadIdx.x;
    int wv = t >> 6, lane = t & 63;
    int lo = 0, hi = N_NODES;
    while (lo < hi) { int m = (lo + hi) >> 1; if (batch[m] < g) lo = m + 1; else hi = m; }
    int start = lo;
    lo = 0; hi = N_NODES;
    while (lo < hi) { int m = (lo + hi) >> 1; if (batch[m] < g + 1) lo = m + 1; else hi = m; }
    int end = lo;
    float4 acc = {0.f, 0.f, 0.f, 0.f};
    for (int i = start + wv; i < end; i += 4) {
        uint2 r = *(const uint2*)(h + (size_t)i * 256 + lane * 4);
        acc.x += bf2f((unsigned short)r.x);
        acc.y += bf2f((unsigned short)(r.x >> 16));
        acc.z += bf2f((unsigned short)r.y);
        acc.w += bf2f((unsigned short)(r.y >> 16));
    }
    sd[wv][lane] = acc;
    __syncthreads();
    if (wv == 0) {
        float4 a = sd[0][lane], b = sd[1][lane], c = sd[2][lane], d = sd[3][lane];
        float4 s;
        s.x = a.x + b.x + c.x + d.x;
        s.y = a.y + b.y + c.y + d.y;
        s.z = a.z + b.z + c.z + d.z;
        s.w = a.w + b.w + c.w + d.w;
        *(float4*)(pooled + g * DIM + lane * 4) = s;
    }
}

// ---------------- FC head + log_softmax ----------------

__global__ void head_kernel(const float* __restrict__ pooled, const float* __restrict__ Wfc1,
                            const float* __restrict__ bfc1, const float* __restrict__ Wfc2,
                            const float* __restrict__ bfc2, float* __restrict__ out) {
    __shared__ float row[DIM];
    __shared__ float fc1[DIM];
    __shared__ float logits[NUM_CLASSES];
    __shared__ float red[2];
    int g = blockIdx.x, t = threadIdx.x;
    row[t] = pooled[g * DIM + t];
    __syncthreads();
    float acc = bfc1[t];
    for (int k = 0; k < DIM; ++k) acc += row[k] * Wfc1[k * DIM + t];
    fc1[t] = fmaxf(acc, 0.f);
    __syncthreads();
    if (t < NUM_CLASSES) {
        float a = bfc2[t];
        for (int k = 0; k < DIM; ++k) a += fc1[k] * Wfc2[k * NUM_CLASSES + t];
        logits[t] = a;
    }
    __syncthreads();
    if (t == 0) {
        float mx = -INFINITY;
        for (int c2 = 0; c2 < NUM_CLASSES; ++c2) mx = fmaxf(mx, logits[c2]);
        float s = 0.f;
        for (int c2 = 0; c2 < NUM_CLASSES; ++c2) s += expf(logits[c2] - mx);
        red[0] = mx;
        red[1] = logf(s);
    }
    __syncthreads();
    if (t < NUM_CLASSES) out[g * NUM_CLASSES + t] = logits[t] - red[0] - red[1];
}

// ---------------- launch ----------------

extern "C" void kernel_launch(void* const* d_in, const int* in_sizes, int n_in,
                              void* d_out, int out_size, void* d_ws, size_t ws_size,
                              hipStream_t stream) {
    const float* x = (const float*)d_in[0];
    const int* ei = (const int*)d_in[1];
    const int* batch = (const int*)d_in[2];
    const float* ew = (const float*)d_in[3];
    const float *Wr[5], *br[5], *Wo[5];
    for (int i = 0; i < 5; ++i) {
        Wr[i] = (const float*)d_in[4 + 3 * i];
        br[i] = (const float*)d_in[5 + 3 * i];
        Wo[i] = (const float*)d_in[6 + 3 * i];
    }
    const float* Wfc1 = (const float*)d_in[19];
    const float* bfc1 = (const float*)d_in[20];
    const float* Wfc2 = (const float*)d_in[21];
    const float* bfc2 = (const float*)d_in[22];
    float* out = (float*)d_out;

    char* ws = (char*)d_ws;
    size_t off = 0;
    auto alloc = [&](size_t bytes) {
        void* p = ws + off;
        off += (bytes + 255) & ~(size_t)255;
        return p;
    };
    unsigned short* xb = (unsigned short*)alloc((size_t)N_NODES * F_IN * 2);
    unsigned short* h0 = (unsigned short*)alloc((size_t)N_NODES * DIM * 2);
    unsigned short* h1 = (unsigned short*)alloc((size_t)N_NODES * DIM * 2);
    unsigned short* aggb = (unsigned short*)alloc((size_t)N_NODES * DIM * 2);
    unsigned short* Bt[5];
    Bt[0] = (unsigned short*)alloc((size_t)2 * F_IN * DIM * 2);
    for (int i = 1; i < 5; ++i) Bt[i] = (unsigned short*)alloc((size_t)2 * DIM * DIM * 2);
    int* offs = (int*)alloc((N_NODES + 1) * 4);
    int* counts = (int*)alloc((size_t)2 * N_NODES * 4);
    int* cursor = counts + N_NODES;
    int* bsum = (int*)alloc(NB_SCAN * 4);
    uint2* edata = (uint2*)alloc((size_t)N_EDGES * 8);
    float* pooled = (float*)alloc((size_t)NUM_GRAPHS * DIM * 4);

    const int* src = ei;
    const int* dstp = ei + N_EDGES;

    hipMemsetAsync(counts, 0, (size_t)2 * N_NODES * 4, stream);
    hist_kernel<<<(N_EDGES + 255) / 256, 256, 0, stream>>>(dstp, counts, N_EDGES);
    scan_part<<<NB_SCAN, 256, 0, stream>>>(counts, bsum, N_NODES);
    scan_bsum<<<1, 256, 0, stream>>>(bsum, NB_SCAN);
    scan_final<<<NB_SCAN, 256, 0, stream>>>(counts, bsum, offs, N_NODES);
    fill_kernel<<<(N_EDGES + 255) / 256, 256, 0, stream>>>(src, dstp, ew, offs, cursor, edata,
                                                           N_EDGES);

    conv_x<<<((N_NODES * F_IN / 4) + 255) / 256, 256, 0, stream>>>(x, xb, N_NODES * F_IN / 4);
    pack_w<<<(2 * F_IN * DIM + 255) / 256, 256, 0, stream>>>(Wr[0], Wo[0], Bt[0], F_IN);
    {
        dim3 pg((2 * DIM * DIM + 255) / 256, 4);
        pack_w4<<<pg, 256, 0, stream>>>(Wr[1], Wo[1], Wr[2], Wo[2], Wr[3], Wo[3], Wr[4], Wo[4],
                                        Bt[1], Bt[2], Bt[3], Bt[4]);
    }

    dim3 ggrid((N_NODES + 127) / 128, 2);

    // layer 1 (K = 128)
    agg_bf16<128><<<(N_NODES + 3) / 4, 256, 0, stream>>>(xb, offs, edata, aggb);
    gemm_mfma<128><<<ggrid, 256, 0, stream>>>(aggb, xb, Bt[0], br[0], h0);

    const unsigned short* hp = h0;
    unsigned short* hn = h1;
    for (int L = 1; L < 5; ++L) {
        agg_bf16<256><<<(N_NODES + 3) / 4, 256, 0, stream>>>(hp, offs, edata, aggb);
        gemm_mfma<256><<<ggrid, 256, 0, stream>>>(aggb, hp, Bt[L], br[L], hn);
        unsigned short* t2 = (unsigned short*)hp;
        hp = hn;
        hn = t2;
    }

    pool_kernel<<<NUM_GRAPHS, 256, 0, stream>>>(hp, batch, pooled);
    head_kernel<<<NUM_GRAPHS, 256, 0, stream>>>(pooled, Wfc1, bfc1, Wfc2, bfc2, out);
}

// Round 10
// 614.695 us; speedup vs baseline: 2.6631x; 1.0260x over previous
//
#include <hip/hip_runtime.h>
#include <hip/hip_bf16.h>

#define N_NODES 50000
#define N_EDGES 800000
#define F_IN 128
#define DIM 256
#define NUM_CLASSES 10
#define NUM_GRAPHS 256
#define NB_SCAN ((N_NODES + 255) / 256)

typedef short bf16x8 __attribute__((ext_vector_type(8)));
typedef float f32x4 __attribute__((ext_vector_type(4)));

__device__ __forceinline__ float bf2f(unsigned short u) {
    union { unsigned int u; float f; } c;
    c.u = ((unsigned int)u) << 16;
    return c.f;
}
__device__ __forceinline__ unsigned short f2bf(float f) {
    union { float f; unsigned int u; } c;
    c.f = f;
    unsigned int r = (c.u + 0x7fffu + ((c.u >> 16) & 1u)) >> 16;
    return (unsigned short)r;
}
__device__ __forceinline__ float u2f(unsigned int u) {
    union { unsigned int u; float f; } c;
    c.u = u;
    return c.f;
}
__device__ __forceinline__ unsigned int f2u(float f) {
    union { float f; unsigned int u; } c;
    c.f = f;
    return c.u;
}

__device__ __forceinline__ void gload16(const unsigned short* g, unsigned short* l) {
    __builtin_amdgcn_global_load_lds(
        (const __attribute__((address_space(1))) unsigned int*)(g),
        (__attribute__((address_space(3))) unsigned int*)(l), 16, 0, 0);
}

// ---------------- CSR build ----------------

__global__ void hist_kernel(const int* __restrict__ dst, int* __restrict__ counts, int E) {
    int e = blockIdx.x * blockDim.x + threadIdx.x;
    if (e < E) atomicAdd(&counts[dst[e]], 1);
}

__global__ void scan_part(const int* __restrict__ counts, int* __restrict__ bsum, int n) {
    __shared__ int sd[256];
    int t = threadIdx.x, b = blockIdx.x;
    int i = b * 256 + t;
    sd[t] = (i < n) ? counts[i] : 0;
    __syncthreads();
    for (int off = 128; off > 0; off >>= 1) {
        if (t < off) sd[t] += sd[t + off];
        __syncthreads();
    }
    if (t == 0) bsum[b] = sd[0];
}

__global__ void scan_bsum(int* __restrict__ bsum, int nb) {
    __shared__ int sd[256];
    int t = threadIdx.x;
    int v = (t < nb) ? bsum[t] : 0;
    sd[t] = v;
    __syncthreads();
    for (int off = 1; off < 256; off <<= 1) {
        int u = (t >= off) ? sd[t - off] : 0;
        __syncthreads();
        sd[t] += u;
        __syncthreads();
    }
    if (t < nb) bsum[t] = sd[t] - v;  // exclusive
}

__global__ void scan_final(const int* __restrict__ counts, const int* __restrict__ bsum,
                           int* __restrict__ offs, int n) {
    __shared__ int sd[256];
    int t = threadIdx.x, b = blockIdx.x;
    int i = b * 256 + t;
    int v = (i < n) ? counts[i] : 0;
    sd[t] = v;
    __syncthreads();
    for (int off = 1; off < 256; off <<= 1) {
        int u = (t >= off) ? sd[t - off] : 0;
        __syncthreads();
        sd[t] += u;
        __syncthreads();
    }
    if (i < n) offs[i] = bsum[b] + sd[t] - v;
    if (i == n - 1) offs[n] = bsum[b] + sd[t];
}

// scatter (src, weight) packed as one 8-byte store into a single buffer
__global__ void fill_kernel(const int* __restrict__ src, const int* __restrict__ dst,
                            const float* __restrict__ ew, const int* __restrict__ offs,
                            int* __restrict__ cursor, uint2* __restrict__ edata, int E) {
    int e = blockIdx.x * blockDim.x + threadIdx.x;
    if (e < E) {
        int d = dst[e];
        int pos = offs[d] + atomicAdd(&cursor[d], 1);
        edata[pos] = make_uint2((unsigned int)src[e], f2u(ew[e]));
    }
}

// ---------------- dtype prep ----------------

__global__ void conv_x(const float* __restrict__ x, unsigned short* __restrict__ xb, int n4) {
    int i = blockIdx.x * blockDim.x + threadIdx.x;
    if (i >= n4) return;
    float4 v = ((const float4*)x)[i];
    ushort4 o;
    o.x = f2bf(v.x); o.y = f2bf(v.y); o.z = f2bf(v.z); o.w = f2bf(v.w);
    ((ushort4*)xb)[i] = o;
}

__global__ void pack_w(const float* __restrict__ Wr, const float* __restrict__ Wo,
                       unsigned short* __restrict__ Bt, int K) {
    int idx = blockIdx.x * blockDim.x + threadIdx.x;
    int total = 2 * K * DIM;
    if (idx >= total) return;
    int k = idx / DIM, c = idx % DIM;
    float v = (k < K) ? Wr[k * DIM + c] : Wo[(k - K) * DIM + c];
    Bt[(size_t)c * (2 * K) + k] = f2bf(v);
}

__global__ void pack_w4(const float* __restrict__ W2r, const float* __restrict__ W2o,
                        const float* __restrict__ W3r, const float* __restrict__ W3o,
                        const float* __restrict__ W4r, const float* __restrict__ W4o,
                        const float* __restrict__ W5r, const float* __restrict__ W5o,
                        unsigned short* __restrict__ B2, unsigned short* __restrict__ B3,
                        unsigned short* __restrict__ B4, unsigned short* __restrict__ B5) {
    int idx = blockIdx.x * blockDim.x + threadIdx.x;
    int total = 2 * DIM * DIM;
    if (idx >= total) return;
    int L = blockIdx.y;
    const float* Wr = (L == 0) ? W2r : (L == 1) ? W3r : (L == 2) ? W4r : W5r;
    const float* Wo = (L == 0) ? W2o : (L == 1) ? W3o : (L == 2) ? W4o : W5o;
    unsigned short* Bt = (L == 0) ? B2 : (L == 1) ? B3 : (L == 2) ? B4 : B5;
    int k = idx / DIM, c = idx % DIM;
    float v = (k < DIM) ? Wr[k * DIM + c] : Wo[(k - DIM) * DIM + c];
    Bt[(size_t)c * (2 * DIM) + k] = f2bf(v);
}

// ---------------- per-node aggregation ----------------
// 2 edges per wave: half-wave hf handles edge p+hf, 32 sub-lanes x 16B (F=256)
// or 8B (F=128) cover the row. Halves merged via shfl_xor(32) at the end.

template <int F>
__global__ void agg_bf16(const unsigned short* __restrict__ hsrc, const int* __restrict__ offs,
                         const uint2* __restrict__ edata, unsigned short* __restrict__ agg) {
    int node = blockIdx.x * (blockDim.x >> 6) + (threadIdx.x >> 6);
    if (node >= N_NODES) return;
    int lane = threadIdx.x & 63;
    int hf = lane >> 5;
    int sl = lane & 31;
    int s0 = offs[node], s1 = offs[node + 1];
    if (F == 256) {
        const unsigned short* hb = hsrc + sl * 8;
        float accA[8] = {0.f, 0.f, 0.f, 0.f, 0.f, 0.f, 0.f, 0.f};
        float accB[8] = {0.f, 0.f, 0.f, 0.f, 0.f, 0.f, 0.f, 0.f};
        int p = s0;
        for (; p + 3 < s1; p += 4) {
            uint2 ea = edata[p + hf];
            uint2 eb = edata[p + 2 + hf];
            float wa = u2f(ea.y), wb = u2f(eb.y);
            uint4 ra = *(const uint4*)(hb + (size_t)ea.x * 256);
            uint4 rb = *(const uint4*)(hb + (size_t)eb.x * 256);
            accA[0] += wa * bf2f((unsigned short)ra.x);
            accA[1] += wa * bf2f((unsigned short)(ra.x >> 16));
            accA[2] += wa * bf2f((unsigned short)ra.y);
            accA[3] += wa * bf2f((unsigned short)(ra.y >> 16));
            accA[4] += wa * bf2f((unsigned short)ra.z);
            accA[5] += wa * bf2f((unsigned short)(ra.z >> 16));
            accA[6] += wa * bf2f((unsigned short)ra.w);
            accA[7] += wa * bf2f((unsigned short)(ra.w >> 16));
            accB[0] += wb * bf2f((unsigned short)rb.x);
            accB[1] += wb * bf2f((unsigned short)(rb.x >> 16));
            accB[2] += wb * bf2f((unsigned short)rb.y);
            accB[3] += wb * bf2f((unsigned short)(rb.y >> 16));
            accB[4] += wb * bf2f((unsigned short)rb.z);
            accB[5] += wb * bf2f((unsigned short)(rb.z >> 16));
            accB[6] += wb * bf2f((unsigned short)rb.w);
            accB[7] += wb * bf2f((unsigned short)(rb.w >> 16));
        }
        for (; p < s1; p += 2) {
            int pe = p + hf;
            bool v = pe < s1;
            uint2 e = edata[v ? pe : (s1 - 1)];
            float w = v ? u2f(e.y) : 0.f;
            uint4 r = *(const uint4*)(hb + (size_t)e.x * 256);
            accA[0] += w * bf2f((unsigned short)r.x);
            accA[1] += w * bf2f((unsigned short)(r.x >> 16));
            accA[2] += w * bf2f((unsigned short)r.y);
            accA[3] += w * bf2f((unsigned short)(r.y >> 16));
            accA[4] += w * bf2f((unsigned short)r.z);
            accA[5] += w * bf2f((unsigned short)(r.z >> 16));
            accA[6] += w * bf2f((unsigned short)r.w);
            accA[7] += w * bf2f((unsigned short)(r.w >> 16));
        }
        float tot[8];
#pragma unroll
        for (int i = 0; i < 8; ++i) {
            tot[i] = accA[i] + accB[i];
            tot[i] += __shfl_xor(tot[i], 32, 64);
        }
        if (hf == 0) {
            uint4 o;
            o.x = (unsigned)f2bf(tot[0]) | ((unsigned)f2bf(tot[1]) << 16);
            o.y = (unsigned)f2bf(tot[2]) | ((unsigned)f2bf(tot[3]) << 16);
            o.z = (unsigned)f2bf(tot[4]) | ((unsigned)f2bf(tot[5]) << 16);
            o.w = (unsigned)f2bf(tot[6]) | ((unsigned)f2bf(tot[7]) << 16);
            *(uint4*)(agg + (size_t)node * 256 + sl * 8) = o;
        }
    } else {
        const unsigned short* hb = hsrc + sl * 4;
        float accA[4] = {0.f, 0.f, 0.f, 0.f};
        float accB[4] = {0.f, 0.f, 0.f, 0.f};
        int p = s0;
        for (; p + 3 < s1; p += 4) {
            uint2 ea = edata[p + hf];
            uint2 eb = edata[p + 2 + hf];
            float wa = u2f(ea.y), wb = u2f(eb.y);
            uint2 ra = *(const uint2*)(hb + (size_t)ea.x * 128);
            uint2 rb = *(const uint2*)(hb + (size_t)eb.x * 128);
            accA[0] += wa * bf2f((unsigned short)ra.x);
            accA[1] += wa * bf2f((unsigned short)(ra.x >> 16));
            accA[2] += wa * bf2f((unsigned short)ra.y);
            accA[3] += wa * bf2f((unsigned short)(ra.y >> 16));
            accB[0] += wb * bf2f((unsigned short)rb.x);
            accB[1] += wb * bf2f((unsigned short)(rb.x >> 16));
            accB[2] += wb * bf2f((unsigned short)rb.y);
            accB[3] += wb * bf2f((unsigned short)(rb.y >> 16));
        }
        for (; p < s1; p += 2) {
            int pe = p + hf;
            bool v = pe < s1;
            uint2 e = edata[v ? pe : (s1 - 1)];
            float w = v ? u2f(e.y) : 0.f;
            uint2 r = *(const uint2*)(hb + (size_t)e.x * 128);
            accA[0] += w * bf2f((unsigned short)r.x);
            accA[1] += w * bf2f((unsigned short)(r.x >> 16));
            accA[2] += w * bf2f((unsigned short)r.y);
            accA[3] += w * bf2f((unsigned short)(r.y >> 16));
        }
        float tot[4];
#pragma unroll
        for (int i = 0; i < 4; ++i) {
            tot[i] = accA[i] + accB[i];
            tot[i] += __shfl_xor(tot[i], 32, 64);
        }
        if (hf == 0) {
            uint2 o;
            o.x = (unsigned)f2bf(tot[0]) | ((unsigned)f2bf(tot[1]) << 16);
            o.y = (unsigned)f2bf(tot[2]) | ((unsigned)f2bf(tot[3]) << 16);
            *(uint2*)(agg + (size_t)node * 128 + sl * 4) = o;
        }
    }
}

// ---------------- MFMA dual GEMM: out = relu([A1|A2] @ Bt^T + bias), bf16 ----------------

template <int K>
__global__ __launch_bounds__(256) void gemm_mfma(
    const unsigned short* __restrict__ A1, const unsigned short* __restrict__ A2,
    const unsigned short* __restrict__ Bt, const float* __restrict__ bias,
    unsigned short* __restrict__ out) {
    __shared__ unsigned short As[128 * 32];
    __shared__ unsigned short Bs[128 * 32];
    const int t = threadIdx.x;
    const int lane = t & 63;
    const int w = t >> 6;
    const int wr = w >> 1, wc = w & 1;
    const int row0 = blockIdx.x * 128, col0 = blockIdx.y * 128;
    const int fr = lane & 15, fq = lane >> 4;

    const int srow = t >> 2;
    const int schunk = t & 3;
    int ar0 = row0 + srow;
    if (ar0 >= N_NODES) ar0 = N_NODES - 1;
    int ar1 = row0 + 64 + srow;
    if (ar1 >= N_NODES) ar1 = N_NODES - 1;
    const int bc0 = col0 + srow;
    const int bc1 = col0 + 64 + srow;

    unsigned short* asb0 = As + w * 512;
    unsigned short* asb1 = As + 2048 + w * 512;
    unsigned short* bsb0 = Bs + w * 512;
    unsigned short* bsb1 = Bs + 2048 + w * 512;

    f32x4 acc[4][4] = {};

    constexpr int NT = (2 * K) / 32;
    for (int kt = 0; kt < NT; ++kt) {
        const int kk = kt * 32;
        const unsigned short* Ap;
        int ka;
        if (kk < K) { Ap = A1; ka = kk; } else { Ap = A2; ka = kk - K; }
        gload16(Ap + (size_t)ar0 * K + ka + schunk * 8, asb0);
        gload16(Ap + (size_t)ar1 * K + ka + schunk * 8, asb1);
        gload16(Bt + (size_t)bc0 * (2 * K) + kk + schunk * 8, bsb0);
        gload16(Bt + (size_t)bc1 * (2 * K) + kk + schunk * 8, bsb1);
        __syncthreads();
        bf16x8 a[4], b[4];
#pragma unroll
        for (int m = 0; m < 4; ++m)
            a[m] = *(const bf16x8*)(As + (wr * 64 + m * 16 + fr) * 32 + fq * 8);
#pragma unroll
        for (int n = 0; n < 4; ++n)
            b[n] = *(const bf16x8*)(Bs + (wc * 64 + n * 16 + fr) * 32 + fq * 8);
#pragma unroll
        for (int m = 0; m < 4; ++m)
#pragma unroll
            for (int n = 0; n < 4; ++n)
                acc[m][n] = __builtin_amdgcn_mfma_f32_16x16x32_bf16(a[m], b[n], acc[m][n], 0, 0, 0);
        __syncthreads();
    }

#pragma unroll
    for (int n = 0; n < 4; ++n) {
        const int col = col0 + wc * 64 + n * 16 + fr;
        const float bv = bias[col];
#pragma unroll
        for (int m = 0; m < 4; ++m) {
            const int rbase = row0 + wr * 64 + m * 16 + fq * 4;
#pragma unroll
            for (int j = 0; j < 4; ++j) {
                const int r = rbase + j;
                if (r < N_NODES)
                    out[(size_t)r * DIM + col] = f2bf(fmaxf(acc[m][n][j] + bv, 0.f));
            }
        }
    }
}

// ---------------- fused pool (sorted batch) + FC head + log_softmax ----------------

__global__ void pool_head_kernel(const unsigned short* __restrict__ h,
                                 const int* __restrict__ batch,
                                 const float* __restrict__ Wfc1, const float* __restrict__ bfc1,
                                 const float* __restrict__ Wfc2, const float* __restrict__ bfc2,
                                 float* __restrict__ out) {
    __shared__ float4 sd[4][64];
    __shared__ float row[DIM];
    __shared__ float fc1[DIM];
    __shared__ float logits[NUM_CLASSES];
    __shared__ float red[2];
    int g = blockIdx.x, t = threadIdx.x;
    int wv = t >> 6, lane = t & 63;
    int lo = 0, hi = N_NODES;
    while (lo < hi) { int m = (lo + hi) >> 1; if (batch[m] < g) lo = m + 1; else hi = m; }
    int start = lo;
    lo = 0; hi = N_NODES;
    while (lo < hi) { int m = (lo + hi) >> 1; if (batch[m] < g + 1) lo = m + 1; else hi = m; }
    int end = lo;
    float4 acc = {0.f, 0.f, 0.f, 0.f};
    for (int i = start + wv; i < end; i += 4) {
        uint2 r = *(const uint2*)(h + (size_t)i * 256 + lane * 4);
        acc.x += bf2f((unsigned short)r.x);
        acc.y += bf2f((unsigned short)(r.x >> 16));
        acc.z += bf2f((unsigned short)r.y);
        acc.w += bf2f((unsigned short)(r.y >> 16));
    }
    sd[wv][lane] = acc;
    __syncthreads();
    if (wv == 0) {
        float4 a = sd[0][lane], b = sd[1][lane], c = sd[2][lane], d = sd[3][lane];
        float4 s;
        s.x = a.x + b.x + c.x + d.x;
        s.y = a.y + b.y + c.y + d.y;
        s.z = a.z + b.z + c.z + d.z;
        s.w = a.w + b.w + c.w + d.w;
        *(float4*)(&row[lane * 4]) = s;
    }
    __syncthreads();
    float a1 = bfc1[t];
    for (int k = 0; k < DIM; ++k) a1 += row[k] * Wfc1[k * DIM + t];
    fc1[t] = fmaxf(a1, 0.f);
    __syncthreads();
    if (t < NUM_CLASSES) {
        float a = bfc2[t];
        for (int k = 0; k < DIM; ++k) a += fc1[k] * Wfc2[k * NUM_CLASSES + t];
        logits[t] = a;
    }
    __syncthreads();
    if (t == 0) {
        float mx = -INFINITY;
        for (int c2 = 0; c2 < NUM_CLASSES; ++c2) mx = fmaxf(mx, logits[c2]);
        float s = 0.f;
        for (int c2 = 0; c2 < NUM_CLASSES; ++c2) s += expf(logits[c2] - mx);
        red[0] = mx;
        red[1] = logf(s);
    }
    __syncthreads();
    if (t < NUM_CLASSES) out[g * NUM_CLASSES + t] = logits[t] - red[0] - red[1];
}

// ---------------- launch ----------------

extern "C" void kernel_launch(void* const* d_in, const int* in_sizes, int n_in,
                              void* d_out, int out_size, void* d_ws, size_t ws_size,
                              hipStream_t stream) {
    const float* x = (const float*)d_in[0];
    const int* ei = (const int*)d_in[1];
    const int* batch = (const int*)d_in[2];
    const float* ew = (const float*)d_in[3];
    const float *Wr[5], *br[5], *Wo[5];
    for (int i = 0; i < 5; ++i) {
        Wr[i] = (const float*)d_in[4 + 3 * i];
        br[i] = (const float*)d_in[5 + 3 * i];
        Wo[i] = (const float*)d_in[6 + 3 * i];
    }
    const float* Wfc1 = (const float*)d_in[19];
    const float* bfc1 = (const float*)d_in[20];
    const float* Wfc2 = (const float*)d_in[21];
    const float* bfc2 = (const float*)d_in[22];
    float* out = (float*)d_out;

    char* ws = (char*)d_ws;
    size_t off = 0;
    auto alloc = [&](size_t bytes) {
        void* p = ws + off;
        off += (bytes + 255) & ~(size_t)255;
        return p;
    };
    unsigned short* xb = (unsigned short*)alloc((size_t)N_NODES * F_IN * 2);
    unsigned short* h0 = (unsigned short*)alloc((size_t)N_NODES * DIM * 2);
    unsigned short* h1 = (unsigned short*)alloc((size_t)N_NODES * DIM * 2);
    unsigned short* aggb = (unsigned short*)alloc((size_t)N_NODES * DIM * 2);
    unsigned short* Bt[5];
    Bt[0] = (unsigned short*)alloc((size_t)2 * F_IN * DIM * 2);
    for (int i = 1; i < 5; ++i) Bt[i] = (unsigned short*)alloc((size_t)2 * DIM * DIM * 2);
    int* offs = (int*)alloc((N_NODES + 1) * 4);
    int* counts = (int*)alloc((size_t)2 * N_NODES * 4);
    int* cursor = counts + N_NODES;
    int* bsum = (int*)alloc(NB_SCAN * 4);
    uint2* edata = (uint2*)alloc((size_t)N_EDGES * 8);

    const int* src = ei;
    const int* dstp = ei + N_EDGES;

    hipMemsetAsync(counts, 0, (size_t)2 * N_NODES * 4, stream);
    hist_kernel<<<(N_EDGES + 255) / 256, 256, 0, stream>>>(dstp, counts, N_EDGES);
    scan_part<<<NB_SCAN, 256, 0, stream>>>(counts, bsum, N_NODES);
    scan_bsum<<<1, 256, 0, stream>>>(bsum, NB_SCAN);
    scan_final<<<NB_SCAN, 256, 0, stream>>>(counts, bsum, offs, N_NODES);
    fill_kernel<<<(N_EDGES + 255) / 256, 256, 0, stream>>>(src, dstp, ew, offs, cursor, edata,
                                                           N_EDGES);

    conv_x<<<((N_NODES * F_IN / 4) + 255) / 256, 256, 0, stream>>>(x, xb, N_NODES * F_IN / 4);
    pack_w<<<(2 * F_IN * DIM + 255) / 256, 256, 0, stream>>>(Wr[0], Wo[0], Bt[0], F_IN);
    {
        dim3 pg((2 * DIM * DIM + 255) / 256, 4);
        pack_w4<<<pg, 256, 0, stream>>>(Wr[1], Wo[1], Wr[2], Wo[2], Wr[3], Wo[3], Wr[4], Wo[4],
                                        Bt[1], Bt[2], Bt[3], Bt[4]);
    }

    dim3 ggrid((N_NODES + 127) / 128, 2);

    // layer 1 (K = 128)
    agg_bf16<128><<<(N_NODES + 3) / 4, 256, 0, stream>>>(xb, offs, edata, aggb);
    gemm_mfma<128><<<ggrid, 256, 0, stream>>>(aggb, xb, Bt[0], br[0], h0);

    const unsigned short* hp = h0;
    unsigned short* hn = h1;
    for (int L = 1; L < 5; ++L) {
        agg_bf16<256><<<(N_NODES + 3) / 4, 256, 0, stream>>>(hp, offs, edata, aggb);
        gemm_mfma<256><<<ggrid, 256, 0, stream>>>(aggb, hp, Bt[L], br[L], hn);
        unsigned short* t2 = (unsigned short*)hp;
        hp = hn;
        hn = t2;
    }

    pool_head_kernel<<<NUM_GRAPHS, 256, 0, stream>>>(hp, batch, Wfc1, bfc1, Wfc2, bfc2, out);
}

// Round 11
// 591.658 us; speedup vs baseline: 2.7668x; 1.0389x over previous
//
#include <hip/hip_runtime.h>
#include <hip/hip_bf16.h>

#define N_NODES 50000
#define N_EDGES 800000
#define F_IN 128
#define DIM 256
#define NUM_CLASSES 10
#define NUM_GRAPHS 256
#define NB_SCAN ((N_NODES + 255) / 256)
#define NBKT ((N_NODES + 255) / 256)
#define BCAP 8192

typedef short bf16x8 __attribute__((ext_vector_type(8)));
typedef float f32x4 __attribute__((ext_vector_type(4)));

__device__ __forceinline__ float bf2f(unsigned short u) {
    union { unsigned int u; float f; } c;
    c.u = ((unsigned int)u) << 16;
    return c.f;
}
__device__ __forceinline__ unsigned short f2bf(float f) {
    union { float f; unsigned int u; } c;
    c.f = f;
    unsigned int r = (c.u + 0x7fffu + ((c.u >> 16) & 1u)) >> 16;
    return (unsigned short)r;
}
__device__ __forceinline__ float u2f(unsigned int u) {
    union { unsigned int u; float f; } c;
    c.u = u;
    return c.f;
}
__device__ __forceinline__ unsigned int f2u(float f) {
    union { float f; unsigned int u; } c;
    c.f = f;
    return c.u;
}

__device__ __forceinline__ void gload16(const unsigned short* g, unsigned short* l) {
    __builtin_amdgcn_global_load_lds(
        (const __attribute__((address_space(1))) unsigned int*)(g),
        (__attribute__((address_space(3))) unsigned int*)(l), 16, 0, 0);
}

// ---------------- CSR build ----------------

__global__ void hist_kernel(const int* __restrict__ dst, int* __restrict__ counts, int E) {
    int e = blockIdx.x * blockDim.x + threadIdx.x;
    if (e < E) atomicAdd(&counts[dst[e]], 1);
}

__global__ void scan_part(const int* __restrict__ counts, int* __restrict__ bsum, int n) {
    __shared__ int sd[256];
    int t = threadIdx.x, b = blockIdx.x;
    int i = b * 256 + t;
    sd[t] = (i < n) ? counts[i] : 0;
    __syncthreads();
    for (int off = 128; off > 0; off >>= 1) {
        if (t < off) sd[t] += sd[t + off];
        __syncthreads();
    }
    if (t == 0) bsum[b] = sd[0];
}

// exclusive scan of block sums; also emits the per-bucket global cursors
__global__ void scan_bsum(int* __restrict__ bsum, int* __restrict__ gbase, int nb) {
    __shared__ int sd[256];
    int t = threadIdx.x;
    int v = (t < nb) ? bsum[t] : 0;
    sd[t] = v;
    __syncthreads();
    for (int off = 1; off < 256; off <<= 1) {
        int u = (t >= off) ? sd[t - off] : 0;
        __syncthreads();
        sd[t] += u;
        __syncthreads();
    }
    if (t < nb) {
        int ex = sd[t] - v;
        bsum[t] = ex;
        gbase[t] = ex;  // bucket b's region starts at offs[b*256] == exclusive bsum
    }
}

__global__ void scan_final(const int* __restrict__ counts, const int* __restrict__ bsum,
                           int* __restrict__ offs, int n) {
    __shared__ int sd[256];
    int t = threadIdx.x, b = blockIdx.x;
    int i = b * 256 + t;
    int v = (i < n) ? counts[i] : 0;
    sd[t] = v;
    __syncthreads();
    for (int off = 1; off < 256; off <<= 1) {
        int u = (t >= off) ? sd[t - off] : 0;
        __syncthreads();
        sd[t] += u;
        __syncthreads();
    }
    if (i < n) offs[i] = bsum[b] + sd[t] - v;
    if (i == n - 1) offs[n] = bsum[b] + sd[t];
}

// phase C: scatter edges into bucket-major staging, one contiguous run per (block,bucket)
__global__ __launch_bounds__(256) void bucket_scatter(
    const int* __restrict__ src, const int* __restrict__ dst, const float* __restrict__ ew,
    int* __restrict__ gbase, uint2* __restrict__ edata2, int E) {
    __shared__ int cnt[NBKT];
    __shared__ int base_s[NBKT];
    int t = threadIdx.x;
    int ebase = blockIdx.x * 4096 + t;
    for (int i = t; i < NBKT; i += 256) cnt[i] = 0;
    __syncthreads();
#pragma unroll
    for (int i = 0; i < 16; ++i) {
        int e = ebase + i * 256;
        if (e < E) atomicAdd(&cnt[dst[e] >> 8], 1);
    }
    __syncthreads();
    for (int i = t; i < NBKT; i += 256) {
        int c = cnt[i];
        base_s[i] = c ? atomicAdd(&gbase[i], c) : 0;
        cnt[i] = 0;
    }
    __syncthreads();
#pragma unroll
    for (int i = 0; i < 16; ++i) {
        int e = ebase + i * 256;
        if (e < E) {
            int d = dst[e];
            int bkt = d >> 8;
            int r = atomicAdd(&cnt[bkt], 1);
            edata2[base_s[bkt] + r] =
                make_uint2((unsigned)src[e] | ((unsigned)(d & 255) << 16), f2u(ew[e]));
        }
    }
}

// phase D: per-bucket LDS sort by exact dst, then fully-coalesced write to edata
__global__ __launch_bounds__(256) void bucket_sort(
    const int* __restrict__ offs, const uint2* __restrict__ edata2, int* __restrict__ gcur,
    uint2* __restrict__ edata) {
    __shared__ uint2 stage[BCAP];
    __shared__ int loff[256];
    __shared__ int cur[256];
    int b = blockIdx.x, t = threadIdx.x;
    int nfirst = b * 256;
    int lo = offs[nfirst];
    int nend = nfirst + 256;
    if (nend > N_NODES) nend = N_NODES;
    int hi = offs[nend];
    int cnt = hi - lo;
    int node = nfirst + t;
    loff[t] = (node < N_NODES) ? (offs[node] - lo) : cnt;
    cur[t] = 0;
    __syncthreads();
    if (cnt <= BCAP) {
        for (int i = t; i < cnt; i += 256) {
            uint2 e = edata2[lo + i];
            int dl = (e.x >> 16) & 255;
            int r = atomicAdd(&cur[dl], 1);
            stage[loff[dl] + r] = make_uint2(e.x & 0xFFFFu, e.y);
        }
        __syncthreads();
        for (int i = t; i < cnt; i += 256) edata[lo + i] = stage[i];
    } else {
        for (int i = t; i < cnt; i += 256) {
            uint2 e = edata2[lo + i];
            int dl = (e.x >> 16) & 255;
            int d = nfirst + dl;
            int r = atomicAdd(&gcur[d], 1);
            edata[offs[d] + r] = make_uint2(e.x & 0xFFFFu, e.y);
        }
    }
}

// ---------------- dtype prep ----------------

__global__ void conv_x(const float* __restrict__ x, unsigned short* __restrict__ xb, int n4) {
    int i = blockIdx.x * blockDim.x + threadIdx.x;
    if (i >= n4) return;
    float4 v = ((const float4*)x)[i];
    ushort4 o;
    o.x = f2bf(v.x); o.y = f2bf(v.y); o.z = f2bf(v.z); o.w = f2bf(v.w);
    ((ushort4*)xb)[i] = o;
}

__global__ void pack_w(const float* __restrict__ Wr, const float* __restrict__ Wo,
                       unsigned short* __restrict__ Bt, int K) {
    int idx = blockIdx.x * blockDim.x + threadIdx.x;
    int total = 2 * K * DIM;
    if (idx >= total) return;
    int k = idx / DIM, c = idx % DIM;
    float v = (k < K) ? Wr[k * DIM + c] : Wo[(k - K) * DIM + c];
    Bt[(size_t)c * (2 * K) + k] = f2bf(v);
}

__global__ void pack_w4(const float* __restrict__ W2r, const float* __restrict__ W2o,
                        const float* __restrict__ W3r, const float* __restrict__ W3o,
                        const float* __restrict__ W4r, const float* __restrict__ W4o,
                        const float* __restrict__ W5r, const float* __restrict__ W5o,
                        unsigned short* __restrict__ B2, unsigned short* __restrict__ B3,
                        unsigned short* __restrict__ B4, unsigned short* __restrict__ B5) {
    int idx = blockIdx.x * blockDim.x + threadIdx.x;
    int total = 2 * DIM * DIM;
    if (idx >= total) return;
    int L = blockIdx.y;
    const float* Wr = (L == 0) ? W2r : (L == 1) ? W3r : (L == 2) ? W4r : W5r;
    const float* Wo = (L == 0) ? W2o : (L == 1) ? W3o : (L == 2) ? W4o : W5o;
    unsigned short* Bt = (L == 0) ? B2 : (L == 1) ? B3 : (L == 2) ? B4 : B5;
    int k = idx / DIM, c = idx % DIM;
    float v = (k < DIM) ? Wr[k * DIM + c] : Wo[(k - DIM) * DIM + c];
    Bt[(size_t)c * (2 * DIM) + k] = f2bf(v);
}

// ---------------- per-node aggregation ----------------
// 2 edges per wave: half-wave hf handles edge p+hf, 32 sub-lanes x 16B (F=256)
// or 8B (F=128) cover the row. Halves merged via shfl_xor(32) at the end.

template <int F>
__global__ void agg_bf16(const unsigned short* __restrict__ hsrc, const int* __restrict__ offs,
                         const uint2* __restrict__ edata, unsigned short* __restrict__ agg) {
    int node = blockIdx.x * (blockDim.x >> 6) + (threadIdx.x >> 6);
    if (node >= N_NODES) return;
    int lane = threadIdx.x & 63;
    int hf = lane >> 5;
    int sl = lane & 31;
    int s0 = offs[node], s1 = offs[node + 1];
    if (F == 256) {
        const unsigned short* hb = hsrc + sl * 8;
        float accA[8] = {0.f, 0.f, 0.f, 0.f, 0.f, 0.f, 0.f, 0.f};
        float accB[8] = {0.f, 0.f, 0.f, 0.f, 0.f, 0.f, 0.f, 0.f};
        int p = s0;
        for (; p + 3 < s1; p += 4) {
            uint2 ea = edata[p + hf];
            uint2 eb = edata[p + 2 + hf];
            float wa = u2f(ea.y), wb = u2f(eb.y);
            uint4 ra = *(const uint4*)(hb + (size_t)ea.x * 256);
            uint4 rb = *(const uint4*)(hb + (size_t)eb.x * 256);
            accA[0] += wa * bf2f((unsigned short)ra.x);
            accA[1] += wa * bf2f((unsigned short)(ra.x >> 16));
            accA[2] += wa * bf2f((unsigned short)ra.y);
            accA[3] += wa * bf2f((unsigned short)(ra.y >> 16));
            accA[4] += wa * bf2f((unsigned short)ra.z);
            accA[5] += wa * bf2f((unsigned short)(ra.z >> 16));
            accA[6] += wa * bf2f((unsigned short)ra.w);
            accA[7] += wa * bf2f((unsigned short)(ra.w >> 16));
            accB[0] += wb * bf2f((unsigned short)rb.x);
            accB[1] += wb * bf2f((unsigned short)(rb.x >> 16));
            accB[2] += wb * bf2f((unsigned short)rb.y);
            accB[3] += wb * bf2f((unsigned short)(rb.y >> 16));
            accB[4] += wb * bf2f((unsigned short)rb.z);
            accB[5] += wb * bf2f((unsigned short)(rb.z >> 16));
            accB[6] += wb * bf2f((unsigned short)rb.w);
            accB[7] += wb * bf2f((unsigned short)(rb.w >> 16));
        }
        for (; p < s1; p += 2) {
            int pe = p + hf;
            bool v = pe < s1;
            uint2 e = edata[v ? pe : (s1 - 1)];
            float w = v ? u2f(e.y) : 0.f;
            uint4 r = *(const uint4*)(hb + (size_t)e.x * 256);
            accA[0] += w * bf2f((unsigned short)r.x);
            accA[1] += w * bf2f((unsigned short)(r.x >> 16));
            accA[2] += w * bf2f((unsigned short)r.y);
            accA[3] += w * bf2f((unsigned short)(r.y >> 16));
            accA[4] += w * bf2f((unsigned short)r.z);
            accA[5] += w * bf2f((unsigned short)(r.z >> 16));
            accA[6] += w * bf2f((unsigned short)r.w);
            accA[7] += w * bf2f((unsigned short)(r.w >> 16));
        }
        float tot[8];
#pragma unroll
        for (int i = 0; i < 8; ++i) {
            tot[i] = accA[i] + accB[i];
            tot[i] += __shfl_xor(tot[i], 32, 64);
        }
        if (hf == 0) {
            uint4 o;
            o.x = (unsigned)f2bf(tot[0]) | ((unsigned)f2bf(tot[1]) << 16);
            o.y = (unsigned)f2bf(tot[2]) | ((unsigned)f2bf(tot[3]) << 16);
            o.z = (unsigned)f2bf(tot[4]) | ((unsigned)f2bf(tot[5]) << 16);
            o.w = (unsigned)f2bf(tot[6]) | ((unsigned)f2bf(tot[7]) << 16);
            *(uint4*)(agg + (size_t)node * 256 + sl * 8) = o;
        }
    } else {
        const unsigned short* hb = hsrc + sl * 4;
        float accA[4] = {0.f, 0.f, 0.f, 0.f};
        float accB[4] = {0.f, 0.f, 0.f, 0.f};
        int p = s0;
        for (; p + 3 < s1; p += 4) {
            uint2 ea = edata[p + hf];
            uint2 eb = edata[p + 2 + hf];
            float wa = u2f(ea.y), wb = u2f(eb.y);
            uint2 ra = *(const uint2*)(hb + (size_t)ea.x * 128);
            uint2 rb = *(const uint2*)(hb + (size_t)eb.x * 128);
            accA[0] += wa * bf2f((unsigned short)ra.x);
            accA[1] += wa * bf2f((unsigned short)(ra.x >> 16));
            accA[2] += wa * bf2f((unsigned short)ra.y);
            accA[3] += wa * bf2f((unsigned short)(ra.y >> 16));
            accB[0] += wb * bf2f((unsigned short)rb.x);
            accB[1] += wb * bf2f((unsigned short)(rb.x >> 16));
            accB[2] += wb * bf2f((unsigned short)rb.y);
            accB[3] += wb * bf2f((unsigned short)(rb.y >> 16));
        }
        for (; p < s1; p += 2) {
            int pe = p + hf;
            bool v = pe < s1;
            uint2 e = edata[v ? pe : (s1 - 1)];
            float w = v ? u2f(e.y) : 0.f;
            uint2 r = *(const uint2*)(hb + (size_t)e.x * 128);
            accA[0] += w * bf2f((unsigned short)r.x);
            accA[1] += w * bf2f((unsigned short)(r.x >> 16));
            accA[2] += w * bf2f((unsigned short)r.y);
            accA[3] += w * bf2f((unsigned short)(r.y >> 16));
        }
        float tot[4];
#pragma unroll
        for (int i = 0; i < 4; ++i) {
            tot[i] = accA[i] + accB[i];
            tot[i] += __shfl_xor(tot[i], 32, 64);
        }
        if (hf == 0) {
            uint2 o;
            o.x = (unsigned)f2bf(tot[0]) | ((unsigned)f2bf(tot[1]) << 16);
            o.y = (unsigned)f2bf(tot[2]) | ((unsigned)f2bf(tot[3]) << 16);
            *(uint2*)(agg + (size_t)node * 128 + sl * 4) = o;
        }
    }
}

// ---------------- MFMA dual GEMM: out = relu([A1|A2] @ Bt^T + bias), bf16 ----------------

template <int K>
__global__ __launch_bounds__(256) void gemm_mfma(
    const unsigned short* __restrict__ A1, const unsigned short* __restrict__ A2,
    const unsigned short* __restrict__ Bt, const float* __restrict__ bias,
    unsigned short* __restrict__ out) {
    __shared__ unsigned short As[128 * 32];
    __shared__ unsigned short Bs[128 * 32];
    const int t = threadIdx.x;
    const int lane = t & 63;
    const int w = t >> 6;
    const int wr = w >> 1, wc = w & 1;
    const int row0 = blockIdx.x * 128, col0 = blockIdx.y * 128;
    const int fr = lane & 15, fq = lane >> 4;

    const int srow = t >> 2;
    const int schunk = t & 3;
    int ar0 = row0 + srow;
    if (ar0 >= N_NODES) ar0 = N_NODES - 1;
    int ar1 = row0 + 64 + srow;
    if (ar1 >= N_NODES) ar1 = N_NODES - 1;
    const int bc0 = col0 + srow;
    const int bc1 = col0 + 64 + srow;

    unsigned short* asb0 = As + w * 512;
    unsigned short* asb1 = As + 2048 + w * 512;
    unsigned short* bsb0 = Bs + w * 512;
    unsigned short* bsb1 = Bs + 2048 + w * 512;

    f32x4 acc[4][4] = {};

    constexpr int NT = (2 * K) / 32;
    for (int kt = 0; kt < NT; ++kt) {
        const int kk = kt * 32;
        const unsigned short* Ap;
        int ka;
        if (kk < K) { Ap = A1; ka = kk; } else { Ap = A2; ka = kk - K; }
        gload16(Ap + (size_t)ar0 * K + ka + schunk * 8, asb0);
        gload16(Ap + (size_t)ar1 * K + ka + schunk * 8, asb1);
        gload16(Bt + (size_t)bc0 * (2 * K) + kk + schunk * 8, bsb0);
        gload16(Bt + (size_t)bc1 * (2 * K) + kk + schunk * 8, bsb1);
        __syncthreads();
        bf16x8 a[4], b[4];
#pragma unroll
        for (int m = 0; m < 4; ++m)
            a[m] = *(const bf16x8*)(As + (wr * 64 + m * 16 + fr) * 32 + fq * 8);
#pragma unroll
        for (int n = 0; n < 4; ++n)
            b[n] = *(const bf16x8*)(Bs + (wc * 64 + n * 16 + fr) * 32 + fq * 8);
#pragma unroll
        for (int m = 0; m < 4; ++m)
#pragma unroll
            for (int n = 0; n < 4; ++n)
                acc[m][n] = __builtin_amdgcn_mfma_f32_16x16x32_bf16(a[m], b[n], acc[m][n], 0, 0, 0);
        __syncthreads();
    }

#pragma unroll
    for (int n = 0; n < 4; ++n) {
        const int col = col0 + wc * 64 + n * 16 + fr;
        const float bv = bias[col];
#pragma unroll
        for (int m = 0; m < 4; ++m) {
            const int rbase = row0 + wr * 64 + m * 16 + fq * 4;
#pragma unroll
            for (int j = 0; j < 4; ++j) {
                const int r = rbase + j;
                if (r < N_NODES)
                    out[(size_t)r * DIM + col] = f2bf(fmaxf(acc[m][n][j] + bv, 0.f));
            }
        }
    }
}

// ---------------- fused pool (sorted batch) + FC head + log_softmax ----------------

__global__ void pool_head_kernel(const unsigned short* __restrict__ h,
                                 const int* __restrict__ batch,
                                 const float* __restrict__ Wfc1, const float* __restrict__ bfc1,
                                 const float* __restrict__ Wfc2, const float* __restrict__ bfc2,
                                 float* __restrict__ out) {
    __shared__ float4 sd[4][64];
    __shared__ float row[DIM];
    __shared__ float fc1[DIM];
    __shared__ float logits[NUM_CLASSES];
    __shared__ float red[2];
    int g = blockIdx.x, t = threadIdx.x;
    int wv = t >> 6, lane = t & 63;
    int lo = 0, hi = N_NODES;
    while (lo < hi) { int m = (lo + hi) >> 1; if (batch[m] < g) lo = m + 1; else hi = m; }
    int start = lo;
    lo = 0; hi = N_NODES;
    while (lo < hi) { int m = (lo + hi) >> 1; if (batch[m] < g + 1) lo = m + 1; else hi = m; }
    int end = lo;
    float4 acc = {0.f, 0.f, 0.f, 0.f};
    for (int i = start + wv; i < end; i += 4) {
        uint2 r = *(const uint2*)(h + (size_t)i * 256 + lane * 4);
        acc.x += bf2f((unsigned short)r.x);
        acc.y += bf2f((unsigned short)(r.x >> 16));
        acc.z += bf2f((unsigned short)r.y);
        acc.w += bf2f((unsigned short)(r.y >> 16));
    }
    sd[wv][lane] = acc;
    __syncthreads();
    if (wv == 0) {
        float4 a = sd[0][lane], b = sd[1][lane], c = sd[2][lane], d = sd[3][lane];
        float4 s;
        s.x = a.x + b.x + c.x + d.x;
        s.y = a.y + b.y + c.y + d.y;
        s.z = a.z + b.z + c.z + d.z;
        s.w = a.w + b.w + c.w + d.w;
        *(float4*)(&row[lane * 4]) = s;
    }
    __syncthreads();
    float a1 = bfc1[t];
    for (int k = 0; k < DIM; ++k) a1 += row[k] * Wfc1[k * DIM + t];
    fc1[t] = fmaxf(a1, 0.f);
    __syncthreads();
    if (t < NUM_CLASSES) {
        float a = bfc2[t];
        for (int k = 0; k < DIM; ++k) a += fc1[k] * Wfc2[k * NUM_CLASSES + t];
        logits[t] = a;
    }
    __syncthreads();
    if (t == 0) {
        float mx = -INFINITY;
        for (int c2 = 0; c2 < NUM_CLASSES; ++c2) mx = fmaxf(mx, logits[c2]);
        float s = 0.f;
        for (int c2 = 0; c2 < NUM_CLASSES; ++c2) s += expf(logits[c2] - mx);
        red[0] = mx;
        red[1] = logf(s);
    }
    __syncthreads();
    if (t < NUM_CLASSES) out[g * NUM_CLASSES + t] = logits[t] - red[0] - red[1];
}

// ---------------- launch ----------------

extern "C" void kernel_launch(void* const* d_in, const int* in_sizes, int n_in,
                              void* d_out, int out_size, void* d_ws, size_t ws_size,
                              hipStream_t stream) {
    const float* x = (const float*)d_in[0];
    const int* ei = (const int*)d_in[1];
    const int* batch = (const int*)d_in[2];
    const float* ew = (const float*)d_in[3];
    const float *Wr[5], *br[5], *Wo[5];
    for (int i = 0; i < 5; ++i) {
        Wr[i] = (const float*)d_in[4 + 3 * i];
        br[i] = (const float*)d_in[5 + 3 * i];
        Wo[i] = (const float*)d_in[6 + 3 * i];
    }
    const float* Wfc1 = (const float*)d_in[19];
    const float* bfc1 = (const float*)d_in[20];
    const float* Wfc2 = (const float*)d_in[21];
    const float* bfc2 = (const float*)d_in[22];
    float* out = (float*)d_out;

    char* ws = (char*)d_ws;
    size_t off = 0;
    auto alloc = [&](size_t bytes) {
        void* p = ws + off;
        off += (bytes + 255) & ~(size_t)255;
        return p;
    };
    unsigned short* xb = (unsigned short*)alloc((size_t)N_NODES * F_IN * 2);
    unsigned short* h0 = (unsigned short*)alloc((size_t)N_NODES * DIM * 2);
    unsigned short* h1 = (unsigned short*)alloc((size_t)N_NODES * DIM * 2);
    unsigned short* aggb = (unsigned short*)alloc((size_t)N_NODES * DIM * 2);
    unsigned short* Bt[5];
    Bt[0] = (unsigned short*)alloc((size_t)2 * F_IN * DIM * 2);
    for (int i = 1; i < 5; ++i) Bt[i] = (unsigned short*)alloc((size_t)2 * DIM * DIM * 2);
    int* offs = (int*)alloc((N_NODES + 1) * 4);
    int* counts = (int*)alloc((size_t)2 * N_NODES * 4);
    int* cursor = counts + N_NODES;
    int* bsum = (int*)alloc(NB_SCAN * 4);
    int* gbase = (int*)alloc(NBKT * 4);
    uint2* edata = (uint2*)alloc((size_t)N_EDGES * 8);
    uint2* edata2 = (uint2*)alloc((size_t)N_EDGES * 8);

    const int* src = ei;
    const int* dstp = ei + N_EDGES;

    hipMemsetAsync(counts, 0, (size_t)2 * N_NODES * 4, stream);
    hist_kernel<<<(N_EDGES + 255) / 256, 256, 0, stream>>>(dstp, counts, N_EDGES);
    scan_part<<<NB_SCAN, 256, 0, stream>>>(counts, bsum, N_NODES);
    scan_bsum<<<1, 256, 0, stream>>>(bsum, gbase, NB_SCAN);
    scan_final<<<NB_SCAN, 256, 0, stream>>>(counts, bsum, offs, N_NODES);
    bucket_scatter<<<(N_EDGES + 4095) / 4096, 256, 0, stream>>>(src, dstp, ew, gbase, edata2,
                                                                N_EDGES);
    bucket_sort<<<NBKT, 256, 0, stream>>>(offs, edata2, cursor, edata);

    conv_x<<<((N_NODES * F_IN / 4) + 255) / 256, 256, 0, stream>>>(x, xb, N_NODES * F_IN / 4);
    pack_w<<<(2 * F_IN * DIM + 255) / 256, 256, 0, stream>>>(Wr[0], Wo[0], Bt[0], F_IN);
    {
        dim3 pg((2 * DIM * DIM + 255) / 256, 4);
        pack_w4<<<pg, 256, 0, stream>>>(Wr[1], Wo[1], Wr[2], Wo[2], Wr[3], Wo[3], Wr[4], Wo[4],
                                        Bt[1], Bt[2], Bt[3], Bt[4]);
    }

    dim3 ggrid((N_NODES + 127) / 128, 2);

    // layer 1 (K = 128)
    agg_bf16<128><<<(N_NODES + 3) / 4, 256, 0, stream>>>(xb, offs, edata, aggb);
    gemm_mfma<128><<<ggrid, 256, 0, stream>>>(aggb, xb, Bt[0], br[0], h0);

    const unsigned short* hp = h0;
    unsigned short* hn = h1;
    for (int L = 1; L < 5; ++L) {
        agg_bf16<256><<<(N_NODES + 3) / 4, 256, 0, stream>>>(hp, offs, edata, aggb);
        gemm_mfma<256><<<ggrid, 256, 0, stream>>>(aggb, hp, Bt[L], br[L], hn);
        unsigned short* t2 = (unsigned short*)hp;
        hp = hn;
        hn = t2;
    }

    pool_head_kernel<<<NUM_GRAPHS, 256, 0, stream>>>(hp, batch, Wfc1, bfc1, Wfc2, bfc2, out);
}

// Round 12
// 582.835 us; speedup vs baseline: 2.8087x; 1.0151x over previous
//
#include <hip/hip_runtime.h>
#include <hip/hip_bf16.h>

#define N_NODES 50000
#define N_EDGES 800000
#define F_IN 128
#define DIM 256
#define NUM_CLASSES 10
#define NUM_GRAPHS 256
#define NB_SCAN ((N_NODES + 255) / 256)
#define NBKT ((N_NODES + 255) / 256)
#define BCAP 8192

typedef short bf16x8 __attribute__((ext_vector_type(8)));
typedef float f32x4 __attribute__((ext_vector_type(4)));

__device__ __forceinline__ float bf2f(unsigned short u) {
    union { unsigned int u; float f; } c;
    c.u = ((unsigned int)u) << 16;
    return c.f;
}
__device__ __forceinline__ unsigned short f2bf(float f) {
    union { float f; unsigned int u; } c;
    c.f = f;
    unsigned int r = (c.u + 0x7fffu + ((c.u >> 16) & 1u)) >> 16;
    return (unsigned short)r;
}
__device__ __forceinline__ float u2f(unsigned int u) {
    union { unsigned int u; float f; } c;
    c.u = u;
    return c.f;
}
__device__ __forceinline__ unsigned int f2u(float f) {
    union { float f; unsigned int u; } c;
    c.f = f;
    return c.u;
}

__device__ __forceinline__ void gload16(const unsigned short* g, unsigned short* l) {
    __builtin_amdgcn_global_load_lds(
        (const __attribute__((address_space(1))) unsigned int*)(g),
        (__attribute__((address_space(3))) unsigned int*)(l), 16, 0, 0);
}

// ---------------- CSR build ----------------

__global__ void hist_kernel(const int* __restrict__ dst, int* __restrict__ counts, int E) {
    int e = blockIdx.x * blockDim.x + threadIdx.x;
    if (e < E) atomicAdd(&counts[dst[e]], 1);
}

__global__ void scan_part(const int* __restrict__ counts, int* __restrict__ bsum, int n) {
    __shared__ int sd[256];
    int t = threadIdx.x, b = blockIdx.x;
    int i = b * 256 + t;
    sd[t] = (i < n) ? counts[i] : 0;
    __syncthreads();
    for (int off = 128; off > 0; off >>= 1) {
        if (t < off) sd[t] += sd[t + off];
        __syncthreads();
    }
    if (t == 0) bsum[b] = sd[0];
}

// exclusive scan of block sums; also emits the per-bucket global cursors
__global__ void scan_bsum(int* __restrict__ bsum, int* __restrict__ gbase, int nb) {
    __shared__ int sd[256];
    int t = threadIdx.x;
    int v = (t < nb) ? bsum[t] : 0;
    sd[t] = v;
    __syncthreads();
    for (int off = 1; off < 256; off <<= 1) {
        int u = (t >= off) ? sd[t - off] : 0;
        __syncthreads();
        sd[t] += u;
        __syncthreads();
    }
    if (t < nb) {
        int ex = sd[t] - v;
        bsum[t] = ex;
        gbase[t] = ex;
    }
}

__global__ void scan_final(const int* __restrict__ counts, const int* __restrict__ bsum,
                           int* __restrict__ offs, int n) {
    __shared__ int sd[256];
    int t = threadIdx.x, b = blockIdx.x;
    int i = b * 256 + t;
    int v = (i < n) ? counts[i] : 0;
    sd[t] = v;
    __syncthreads();
    for (int off = 1; off < 256; off <<= 1) {
        int u = (t >= off) ? sd[t - off] : 0;
        __syncthreads();
        sd[t] += u;
        __syncthreads();
    }
    if (i < n) offs[i] = bsum[b] + sd[t] - v;
    if (i == n - 1) offs[n] = bsum[b] + sd[t];
}

// phase C: scatter edges into bucket-major staging, one contiguous run per (block,bucket)
__global__ __launch_bounds__(256) void bucket_scatter(
    const int* __restrict__ src, const int* __restrict__ dst, const float* __restrict__ ew,
    int* __restrict__ gbase, uint2* __restrict__ edata2, int E) {
    __shared__ int cnt[NBKT];
    __shared__ int base_s[NBKT];
    int t = threadIdx.x;
    int ebase = blockIdx.x * 4096 + t;
    for (int i = t; i < NBKT; i += 256) cnt[i] = 0;
    __syncthreads();
#pragma unroll
    for (int i = 0; i < 16; ++i) {
        int e = ebase + i * 256;
        if (e < E) atomicAdd(&cnt[dst[e] >> 8], 1);
    }
    __syncthreads();
    for (int i = t; i < NBKT; i += 256) {
        int c = cnt[i];
        base_s[i] = c ? atomicAdd(&gbase[i], c) : 0;
        cnt[i] = 0;
    }
    __syncthreads();
#pragma unroll
    for (int i = 0; i < 16; ++i) {
        int e = ebase + i * 256;
        if (e < E) {
            int d = dst[e];
            int bkt = d >> 8;
            int r = atomicAdd(&cnt[bkt], 1);
            edata2[base_s[bkt] + r] =
                make_uint2((unsigned)src[e] | ((unsigned)(d & 255) << 16), f2u(ew[e]));
        }
    }
}

// phase D: per-bucket LDS sort by exact dst, then fully-coalesced write to edata
__global__ __launch_bounds__(256) void bucket_sort(
    const int* __restrict__ offs, const uint2* __restrict__ edata2, int* __restrict__ gcur,
    uint2* __restrict__ edata) {
    __shared__ uint2 stage[BCAP];
    __shared__ int loff[256];
    __shared__ int cur[256];
    int b = blockIdx.x, t = threadIdx.x;
    int nfirst = b * 256;
    int lo = offs[nfirst];
    int nend = nfirst + 256;
    if (nend > N_NODES) nend = N_NODES;
    int hi = offs[nend];
    int cnt = hi - lo;
    int node = nfirst + t;
    loff[t] = (node < N_NODES) ? (offs[node] - lo) : cnt;
    cur[t] = 0;
    __syncthreads();
    if (cnt <= BCAP) {
        for (int i = t; i < cnt; i += 256) {
            uint2 e = edata2[lo + i];
            int dl = (e.x >> 16) & 255;
            int r = atomicAdd(&cur[dl], 1);
            stage[loff[dl] + r] = make_uint2(e.x & 0xFFFFu, e.y);
        }
        __syncthreads();
        for (int i = t; i < cnt; i += 256) edata[lo + i] = stage[i];
    } else {
        for (int i = t; i < cnt; i += 256) {
            uint2 e = edata2[lo + i];
            int dl = (e.x >> 16) & 255;
            int d = nfirst + dl;
            int r = atomicAdd(&gcur[d], 1);
            edata[offs[d] + r] = make_uint2(e.x & 0xFFFFu, e.y);
        }
    }
}

// ---------------- dtype prep ----------------

__global__ void conv_x(const float* __restrict__ x, unsigned short* __restrict__ xb, int n4) {
    int i = blockIdx.x * blockDim.x + threadIdx.x;
    if (i >= n4) return;
    float4 v = ((const float4*)x)[i];
    ushort4 o;
    o.x = f2bf(v.x); o.y = f2bf(v.y); o.z = f2bf(v.z); o.w = f2bf(v.w);
    ((ushort4*)xb)[i] = o;
}

__global__ void pack_w(const float* __restrict__ Wr, const float* __restrict__ Wo,
                       unsigned short* __restrict__ Bt, int K) {
    int idx = blockIdx.x * blockDim.x + threadIdx.x;
    int total = 2 * K * DIM;
    if (idx >= total) return;
    int k = idx / DIM, c = idx % DIM;
    float v = (k < K) ? Wr[k * DIM + c] : Wo[(k - K) * DIM + c];
    Bt[(size_t)c * (2 * K) + k] = f2bf(v);
}

__global__ void pack_w4(const float* __restrict__ W2r, const float* __restrict__ W2o,
                        const float* __restrict__ W3r, const float* __restrict__ W3o,
                        const float* __restrict__ W4r, const float* __restrict__ W4o,
                        const float* __restrict__ W5r, const float* __restrict__ W5o,
                        unsigned short* __restrict__ B2, unsigned short* __restrict__ B3,
                        unsigned short* __restrict__ B4, unsigned short* __restrict__ B5) {
    int idx = blockIdx.x * blockDim.x + threadIdx.x;
    int total = 2 * DIM * DIM;
    if (idx >= total) return;
    int L = blockIdx.y;
    const float* Wr = (L == 0) ? W2r : (L == 1) ? W3r : (L == 2) ? W4r : W5r;
    const float* Wo = (L == 0) ? W2o : (L == 1) ? W3o : (L == 2) ? W4o : W5o;
    unsigned short* Bt = (L == 0) ? B2 : (L == 1) ? B3 : (L == 2) ? B4 : B5;
    int k = idx / DIM, c = idx % DIM;
    float v = (k < DIM) ? Wr[k * DIM + c] : Wo[(k - DIM) * DIM + c];
    Bt[(size_t)c * (2 * DIM) + k] = f2bf(v);
}

// ---------------- per-node aggregation ----------------
// 2 edges per wave (half-wave hf), 32 sub-lanes x 16B per row. 8-edge unroll:
// 4 independent row loads in flight per lane for memory-level parallelism.

template <int F>
__global__ void agg_bf16(const unsigned short* __restrict__ hsrc, const int* __restrict__ offs,
                         const uint2* __restrict__ edata, unsigned short* __restrict__ agg) {
    int node = blockIdx.x * (blockDim.x >> 6) + (threadIdx.x >> 6);
    if (node >= N_NODES) return;
    int lane = threadIdx.x & 63;
    int hf = lane >> 5;
    int sl = lane & 31;
    int s0 = offs[node], s1 = offs[node + 1];
    if (F == 256) {
        const unsigned short* hb = hsrc + sl * 8;
        float acc[8] = {0.f, 0.f, 0.f, 0.f, 0.f, 0.f, 0.f, 0.f};
        int p = s0;
        for (; p + 7 < s1; p += 8) {
            uint2 e0 = edata[p + hf];
            uint2 e1 = edata[p + 2 + hf];
            uint2 e2 = edata[p + 4 + hf];
            uint2 e3 = edata[p + 6 + hf];
            float w0 = u2f(e0.y), w1 = u2f(e1.y), w2 = u2f(e2.y), w3 = u2f(e3.y);
            uint4 r0 = *(const uint4*)(hb + (size_t)e0.x * 256);
            uint4 r1 = *(const uint4*)(hb + (size_t)e1.x * 256);
            uint4 r2 = *(const uint4*)(hb + (size_t)e2.x * 256);
            uint4 r3 = *(const uint4*)(hb + (size_t)e3.x * 256);
            acc[0] += w0 * bf2f((unsigned short)r0.x);
            acc[1] += w0 * bf2f((unsigned short)(r0.x >> 16));
            acc[2] += w0 * bf2f((unsigned short)r0.y);
            acc[3] += w0 * bf2f((unsigned short)(r0.y >> 16));
            acc[4] += w0 * bf2f((unsigned short)r0.z);
            acc[5] += w0 * bf2f((unsigned short)(r0.z >> 16));
            acc[6] += w0 * bf2f((unsigned short)r0.w);
            acc[7] += w0 * bf2f((unsigned short)(r0.w >> 16));
            acc[0] += w1 * bf2f((unsigned short)r1.x);
            acc[1] += w1 * bf2f((unsigned short)(r1.x >> 16));
            acc[2] += w1 * bf2f((unsigned short)r1.y);
            acc[3] += w1 * bf2f((unsigned short)(r1.y >> 16));
            acc[4] += w1 * bf2f((unsigned short)r1.z);
            acc[5] += w1 * bf2f((unsigned short)(r1.z >> 16));
            acc[6] += w1 * bf2f((unsigned short)r1.w);
            acc[7] += w1 * bf2f((unsigned short)(r1.w >> 16));
            acc[0] += w2 * bf2f((unsigned short)r2.x);
            acc[1] += w2 * bf2f((unsigned short)(r2.x >> 16));
            acc[2] += w2 * bf2f((unsigned short)r2.y);
            acc[3] += w2 * bf2f((unsigned short)(r2.y >> 16));
            acc[4] += w2 * bf2f((unsigned short)r2.z);
            acc[5] += w2 * bf2f((unsigned short)(r2.z >> 16));
            acc[6] += w2 * bf2f((unsigned short)r2.w);
            acc[7] += w2 * bf2f((unsigned short)(r2.w >> 16));
            acc[0] += w3 * bf2f((unsigned short)r3.x);
            acc[1] += w3 * bf2f((unsigned short)(r3.x >> 16));
            acc[2] += w3 * bf2f((unsigned short)r3.y);
            acc[3] += w3 * bf2f((unsigned short)(r3.y >> 16));
            acc[4] += w3 * bf2f((unsigned short)r3.z);
            acc[5] += w3 * bf2f((unsigned short)(r3.z >> 16));
            acc[6] += w3 * bf2f((unsigned short)r3.w);
            acc[7] += w3 * bf2f((unsigned short)(r3.w >> 16));
        }
        for (; p + 3 < s1; p += 4) {
            uint2 e0 = edata[p + hf];
            uint2 e1 = edata[p + 2 + hf];
            float w0 = u2f(e0.y), w1 = u2f(e1.y);
            uint4 r0 = *(const uint4*)(hb + (size_t)e0.x * 256);
            uint4 r1 = *(const uint4*)(hb + (size_t)e1.x * 256);
            acc[0] += w0 * bf2f((unsigned short)r0.x);
            acc[1] += w0 * bf2f((unsigned short)(r0.x >> 16));
            acc[2] += w0 * bf2f((unsigned short)r0.y);
            acc[3] += w0 * bf2f((unsigned short)(r0.y >> 16));
            acc[4] += w0 * bf2f((unsigned short)r0.z);
            acc[5] += w0 * bf2f((unsigned short)(r0.z >> 16));
            acc[6] += w0 * bf2f((unsigned short)r0.w);
            acc[7] += w0 * bf2f((unsigned short)(r0.w >> 16));
            acc[0] += w1 * bf2f((unsigned short)r1.x);
            acc[1] += w1 * bf2f((unsigned short)(r1.x >> 16));
            acc[2] += w1 * bf2f((unsigned short)r1.y);
            acc[3] += w1 * bf2f((unsigned short)(r1.y >> 16));
            acc[4] += w1 * bf2f((unsigned short)r1.z);
            acc[5] += w1 * bf2f((unsigned short)(r1.z >> 16));
            acc[6] += w1 * bf2f((unsigned short)r1.w);
            acc[7] += w1 * bf2f((unsigned short)(r1.w >> 16));
        }
        for (; p < s1; p += 2) {
            int pe = p + hf;
            bool v = pe < s1;
            uint2 e = edata[v ? pe : (s1 - 1)];
            float w = v ? u2f(e.y) : 0.f;
            uint4 r = *(const uint4*)(hb + (size_t)e.x * 256);
            acc[0] += w * bf2f((unsigned short)r.x);
            acc[1] += w * bf2f((unsigned short)(r.x >> 16));
            acc[2] += w * bf2f((unsigned short)r.y);
            acc[3] += w * bf2f((unsigned short)(r.y >> 16));
            acc[4] += w * bf2f((unsigned short)r.z);
            acc[5] += w * bf2f((unsigned short)(r.z >> 16));
            acc[6] += w * bf2f((unsigned short)r.w);
            acc[7] += w * bf2f((unsigned short)(r.w >> 16));
        }
#pragma unroll
        for (int i = 0; i < 8; ++i) acc[i] += __shfl_xor(acc[i], 32, 64);
        if (hf == 0) {
            uint4 o;
            o.x = (unsigned)f2bf(acc[0]) | ((unsigned)f2bf(acc[1]) << 16);
            o.y = (unsigned)f2bf(acc[2]) | ((unsigned)f2bf(acc[3]) << 16);
            o.z = (unsigned)f2bf(acc[4]) | ((unsigned)f2bf(acc[5]) << 16);
            o.w = (unsigned)f2bf(acc[6]) | ((unsigned)f2bf(acc[7]) << 16);
            *(uint4*)(agg + (size_t)node * 256 + sl * 8) = o;
        }
    } else {
        const unsigned short* hb = hsrc + sl * 4;
        float acc[4] = {0.f, 0.f, 0.f, 0.f};
        int p = s0;
        for (; p + 7 < s1; p += 8) {
            uint2 e0 = edata[p + hf];
            uint2 e1 = edata[p + 2 + hf];
            uint2 e2 = edata[p + 4 + hf];
            uint2 e3 = edata[p + 6 + hf];
            float w0 = u2f(e0.y), w1 = u2f(e1.y), w2 = u2f(e2.y), w3 = u2f(e3.y);
            uint2 r0 = *(const uint2*)(hb + (size_t)e0.x * 128);
            uint2 r1 = *(const uint2*)(hb + (size_t)e1.x * 128);
            uint2 r2 = *(const uint2*)(hb + (size_t)e2.x * 128);
            uint2 r3 = *(const uint2*)(hb + (size_t)e3.x * 128);
            acc[0] += w0 * bf2f((unsigned short)r0.x);
            acc[1] += w0 * bf2f((unsigned short)(r0.x >> 16));
            acc[2] += w0 * bf2f((unsigned short)r0.y);
            acc[3] += w0 * bf2f((unsigned short)(r0.y >> 16));
            acc[0] += w1 * bf2f((unsigned short)r1.x);
            acc[1] += w1 * bf2f((unsigned short)(r1.x >> 16));
            acc[2] += w1 * bf2f((unsigned short)r1.y);
            acc[3] += w1 * bf2f((unsigned short)(r1.y >> 16));
            acc[0] += w2 * bf2f((unsigned short)r2.x);
            acc[1] += w2 * bf2f((unsigned short)(r2.x >> 16));
            acc[2] += w2 * bf2f((unsigned short)r2.y);
            acc[3] += w2 * bf2f((unsigned short)(r2.y >> 16));
            acc[0] += w3 * bf2f((unsigned short)r3.x);
            acc[1] += w3 * bf2f((unsigned short)(r3.x >> 16));
            acc[2] += w3 * bf2f((unsigned short)r3.y);
            acc[3] += w3 * bf2f((unsigned short)(r3.y >> 16));
        }
        for (; p + 3 < s1; p += 4) {
            uint2 e0 = edata[p + hf];
            uint2 e1 = edata[p + 2 + hf];
            float w0 = u2f(e0.y), w1 = u2f(e1.y);
            uint2 r0 = *(const uint2*)(hb + (size_t)e0.x * 128);
            uint2 r1 = *(const uint2*)(hb + (size_t)e1.x * 128);
            acc[0] += w0 * bf2f((unsigned short)r0.x);
            acc[1] += w0 * bf2f((unsigned short)(r0.x >> 16));
            acc[2] += w0 * bf2f((unsigned short)r0.y);
            acc[3] += w0 * bf2f((unsigned short)(r0.y >> 16));
            acc[0] += w1 * bf2f((unsigned short)r1.x);
            acc[1] += w1 * bf2f((unsigned short)(r1.x >> 16));
            acc[2] += w1 * bf2f((unsigned short)r1.y);
            acc[3] += w1 * bf2f((unsigned short)(r1.y >> 16));
        }
        for (; p < s1; p += 2) {
            int pe = p + hf;
            bool v = pe < s1;
            uint2 e = edata[v ? pe : (s1 - 1)];
            float w = v ? u2f(e.y) : 0.f;
            uint2 r = *(const uint2*)(hb + (size_t)e.x * 128);
            acc[0] += w * bf2f((unsigned short)r.x);
            acc[1] += w * bf2f((unsigned short)(r.x >> 16));
            acc[2] += w * bf2f((unsigned short)r.y);
            acc[3] += w * bf2f((unsigned short)(r.y >> 16));
        }
#pragma unroll
        for (int i = 0; i < 4; ++i) acc[i] += __shfl_xor(acc[i], 32, 64);
        if (hf == 0) {
            uint2 o;
            o.x = (unsigned)f2bf(acc[0]) | ((unsigned)f2bf(acc[1]) << 16);
            o.y = (unsigned)f2bf(acc[2]) | ((unsigned)f2bf(acc[3]) << 16);
            *(uint2*)(agg + (size_t)node * 128 + sl * 4) = o;
        }
    }
}

// ---------------- MFMA dual GEMM: out = relu([A1|A2] @ Bt^T + bias), bf16 ----------------

template <int K>
__global__ __launch_bounds__(256) void gemm_mfma(
    const unsigned short* __restrict__ A1, const unsigned short* __restrict__ A2,
    const unsigned short* __restrict__ Bt, const float* __restrict__ bias,
    unsigned short* __restrict__ out) {
    __shared__ unsigned short As[128 * 32];
    __shared__ unsigned short Bs[128 * 32];
    const int t = threadIdx.x;
    const int lane = t & 63;
    const int w = t >> 6;
    const int wr = w >> 1, wc = w & 1;
    const int row0 = blockIdx.x * 128, col0 = blockIdx.y * 128;
    const int fr = lane & 15, fq = lane >> 4;

    const int srow = t >> 2;
    const int schunk = t & 3;
    int ar0 = row0 + srow;
    if (ar0 >= N_NODES) ar0 = N_NODES - 1;
    int ar1 = row0 + 64 + srow;
    if (ar1 >= N_NODES) ar1 = N_NODES - 1;
    const int bc0 = col0 + srow;
    const int bc1 = col0 + 64 + srow;

    unsigned short* asb0 = As + w * 512;
    unsigned short* asb1 = As + 2048 + w * 512;
    unsigned short* bsb0 = Bs + w * 512;
    unsigned short* bsb1 = Bs + 2048 + w * 512;

    f32x4 acc[4][4] = {};

    constexpr int NT = (2 * K) / 32;
    for (int kt = 0; kt < NT; ++kt) {
        const int kk = kt * 32;
        const unsigned short* Ap;
        int ka;
        if (kk < K) { Ap = A1; ka = kk; } else { Ap = A2; ka = kk - K; }
        gload16(Ap + (size_t)ar0 * K + ka + schunk * 8, asb0);
        gload16(Ap + (size_t)ar1 * K + ka + schunk * 8, asb1);
        gload16(Bt + (size_t)bc0 * (2 * K) + kk + schunk * 8, bsb0);
        gload16(Bt + (size_t)bc1 * (2 * K) + kk + schunk * 8, bsb1);
        __syncthreads();
        bf16x8 a[4], b[4];
#pragma unroll
        for (int m = 0; m < 4; ++m)
            a[m] = *(const bf16x8*)(As + (wr * 64 + m * 16 + fr) * 32 + fq * 8);
#pragma unroll
        for (int n = 0; n < 4; ++n)
            b[n] = *(const bf16x8*)(Bs + (wc * 64 + n * 16 + fr) * 32 + fq * 8);
#pragma unroll
        for (int m = 0; m < 4; ++m)
#pragma unroll
            for (int n = 0; n < 4; ++n)
                acc[m][n] = __builtin_amdgcn_mfma_f32_16x16x32_bf16(a[m], b[n], acc[m][n], 0, 0, 0);
        __syncthreads();
    }

#pragma unroll
    for (int n = 0; n < 4; ++n) {
        const int col = col0 + wc * 64 + n * 16 + fr;
        const float bv = bias[col];
#pragma unroll
        for (int m = 0; m < 4; ++m) {
            const int rbase = row0 + wr * 64 + m * 16 + fq * 4;
#pragma unroll
            for (int j = 0; j < 4; ++j) {
                const int r = rbase + j;
                if (r < N_NODES)
                    out[(size_t)r * DIM + col] = f2bf(fmaxf(acc[m][n][j] + bv, 0.f));
            }
        }
    }
}

// ---------------- fused pool (sorted batch) + FC head + log_softmax ----------------

__global__ void pool_head_kernel(const unsigned short* __restrict__ h,
                                 const int* __restrict__ batch,
                                 const float* __restrict__ Wfc1, const float* __restrict__ bfc1,
                                 const float* __restrict__ Wfc2, const float* __restrict__ bfc2,
                                 float* __restrict__ out) {
    __shared__ float4 sd[4][64];
    __shared__ float row[DIM];
    __shared__ float fc1[DIM];
    __shared__ float logits[NUM_CLASSES];
    __shared__ float red[2];
    int g = blockIdx.x, t = threadIdx.x;
    int wv = t >> 6, lane = t & 63;
    int lo = 0, hi = N_NODES;
    while (lo < hi) { int m = (lo + hi) >> 1; if (batch[m] < g) lo = m + 1; else hi = m; }
    int start = lo;
    lo = 0; hi = N_NODES;
    while (lo < hi) { int m = (lo + hi) >> 1; if (batch[m] < g + 1) lo = m + 1; else hi = m; }
    int end = lo;
    float4 acc = {0.f, 0.f, 0.f, 0.f};
    for (int i = start + wv; i < end; i += 4) {
        uint2 r = *(const uint2*)(h + (size_t)i * 256 + lane * 4);
        acc.x += bf2f((unsigned short)r.x);
        acc.y += bf2f((unsigned short)(r.x >> 16));
        acc.z += bf2f((unsigned short)r.y);
        acc.w += bf2f((unsigned short)(r.y >> 16));
    }
    sd[wv][lane] = acc;
    __syncthreads();
    if (wv == 0) {
        float4 a = sd[0][lane], b = sd[1][lane], c = sd[2][lane], d = sd[3][lane];
        float4 s;
        s.x = a.x + b.x + c.x + d.x;
        s.y = a.y + b.y + c.y + d.y;
        s.z = a.z + b.z + c.z + d.z;
        s.w = a.w + b.w + c.w + d.w;
        *(float4*)(&row[lane * 4]) = s;
    }
    __syncthreads();
    float a1 = bfc1[t];
    for (int k = 0; k < DIM; ++k) a1 += row[k] * Wfc1[k * DIM + t];
    fc1[t] = fmaxf(a1, 0.f);
    __syncthreads();
    if (t < NUM_CLASSES) {
        float a = bfc2[t];
        for (int k = 0; k < DIM; ++k) a += fc1[k] * Wfc2[k * NUM_CLASSES + t];
        logits[t] = a;
    }
    __syncthreads();
    if (t == 0) {
        float mx = -INFINITY;
        for (int c2 = 0; c2 < NUM_CLASSES; ++c2) mx = fmaxf(mx, logits[c2]);
        float s = 0.f;
        for (int c2 = 0; c2 < NUM_CLASSES; ++c2) s += expf(logits[c2] - mx);
        red[0] = mx;
        red[1] = logf(s);
    }
    __syncthreads();
    if (t < NUM_CLASSES) out[g * NUM_CLASSES + t] = logits[t] - red[0] - red[1];
}

// ---------------- launch ----------------

extern "C" void kernel_launch(void* const* d_in, const int* in_sizes, int n_in,
                              void* d_out, int out_size, void* d_ws, size_t ws_size,
                              hipStream_t stream) {
    const float* x = (const float*)d_in[0];
    const int* ei = (const int*)d_in[1];
    const int* batch = (const int*)d_in[2];
    const float* ew = (const float*)d_in[3];
    const float *Wr[5], *br[5], *Wo[5];
    for (int i = 0; i < 5; ++i) {
        Wr[i] = (const float*)d_in[4 + 3 * i];
        br[i] = (const float*)d_in[5 + 3 * i];
        Wo[i] = (const float*)d_in[6 + 3 * i];
    }
    const float* Wfc1 = (const float*)d_in[19];
    const float* bfc1 = (const float*)d_in[20];
    const float* Wfc2 = (const float*)d_in[21];
    const float* bfc2 = (const float*)d_in[22];
    float* out = (float*)d_out;

    char* ws = (char*)d_ws;
    size_t off = 0;
    auto alloc = [&](size_t bytes) {
        void* p = ws + off;
        off += (bytes + 255) & ~(size_t)255;
        return p;
    };
    unsigned short* xb = (unsigned short*)alloc((size_t)N_NODES * F_IN * 2);
    unsigned short* h0 = (unsigned short*)alloc((size_t)N_NODES * DIM * 2);
    unsigned short* h1 = (unsigned short*)alloc((size_t)N_NODES * DIM * 2);
    unsigned short* aggb = (unsigned short*)alloc((size_t)N_NODES * DIM * 2);
    unsigned short* Bt[5];
    Bt[0] = (unsigned short*)alloc((size_t)2 * F_IN * DIM * 2);
    for (int i = 1; i < 5; ++i) Bt[i] = (unsigned short*)alloc((size_t)2 * DIM * DIM * 2);
    int* offs = (int*)alloc((N_NODES + 1) * 4);
    int* counts = (int*)alloc((size_t)2 * N_NODES * 4);
    int* cursor = counts + N_NODES;
    int* bsum = (int*)alloc(NB_SCAN * 4);
    int* gbase = (int*)alloc(NBKT * 4);
    uint2* edata = (uint2*)alloc((size_t)N_EDGES * 8);
    uint2* edata2 = (uint2*)alloc((size_t)N_EDGES * 8);

    const int* src = ei;
    const int* dstp = ei + N_EDGES;

    hipMemsetAsync(counts, 0, (size_t)2 * N_NODES * 4, stream);
    hist_kernel<<<(N_EDGES + 255) / 256, 256, 0, stream>>>(dstp, counts, N_EDGES);
    scan_part<<<NB_SCAN, 256, 0, stream>>>(counts, bsum, N_NODES);
    scan_bsum<<<1, 256, 0, stream>>>(bsum, gbase, NB_SCAN);
    scan_final<<<NB_SCAN, 256, 0, stream>>>(counts, bsum, offs, N_NODES);
    bucket_scatter<<<(N_EDGES + 4095) / 4096, 256, 0, stream>>>(src, dstp, ew, gbase, edata2,
                                                                N_EDGES);
    bucket_sort<<<NBKT, 256, 0, stream>>>(offs, edata2, cursor, edata);

    conv_x<<<((N_NODES * F_IN / 4) + 255) / 256, 256, 0, stream>>>(x, xb, N_NODES * F_IN / 4);
    pack_w<<<(2 * F_IN * DIM + 255) / 256, 256, 0, stream>>>(Wr[0], Wo[0], Bt[0], F_IN);
    {
        dim3 pg((2 * DIM * DIM + 255) / 256, 4);
        pack_w4<<<pg, 256, 0, stream>>>(Wr[1], Wo[1], Wr[2], Wo[2], Wr[3], Wo[3], Wr[4], Wo[4],
                                        Bt[1], Bt[2], Bt[3], Bt[4]);
    }

    dim3 ggrid((N_NODES + 127) / 128, 2);

    // layer 1 (K = 128)
    agg_bf16<128><<<(N_NODES + 3) / 4, 256, 0, stream>>>(xb, offs, edata, aggb);
    gemm_mfma<128><<<ggrid, 256, 0, stream>>>(aggb, xb, Bt[0], br[0], h0);

    const unsigned short* hp = h0;
    unsigned short* hn = h1;
    for (int L = 1; L < 5; ++L) {
        agg_bf16<256><<<(N_NODES + 3) / 4, 256, 0, stream>>>(hp, offs, edata, aggb);
        gemm_mfma<256><<<ggrid, 256, 0, stream>>>(aggb, hp, Bt[L], br[L], hn);
        unsigned short* t2 = (unsigned short*)hp;
        hp = hn;
        hn = t2;
    }

    pool_head_kernel<<<NUM_GRAPHS, 256, 0, stream>>>(hp, batch, Wfc1, bfc1, Wfc2, bfc2, out);
}

// Round 14
// 566.285 us; speedup vs baseline: 2.8908x; 1.0292x over previous
//
#include <hip/hip_runtime.h>
#include <hip/hip_bf16.h>

#define N_NODES 50000
#define N_EDGES 800000
#define F_IN 128
#define DIM 256
#define NUM_CLASSES 10
#define NUM_GRAPHS 256
#define NB_SCAN ((N_NODES + 255) / 256)
#define NBKT ((N_NODES + 255) / 256)
#define BCAP 8192

typedef short bf16x8 __attribute__((ext_vector_type(8)));
typedef float f32x4 __attribute__((ext_vector_type(4)));

__device__ __forceinline__ float bf2f(unsigned short u) {
    union { unsigned int u; float f; } c;
    c.u = ((unsigned int)u) << 16;
    return c.f;
}
__device__ __forceinline__ unsigned short f2bf(float f) {
    union { float f; unsigned int u; } c;
    c.f = f;
    unsigned int r = (c.u + 0x7fffu + ((c.u >> 16) & 1u)) >> 16;
    return (unsigned short)r;
}
__device__ __forceinline__ float u2f(unsigned int u) {
    union { unsigned int u; float f; } c;
    c.u = u;
    return c.f;
}
__device__ __forceinline__ unsigned int f2u(float f) {
    union { float f; unsigned int u; } c;
    c.f = f;
    return c.u;
}

__device__ __forceinline__ void gload16(const unsigned short* g, unsigned short* l) {
    __builtin_amdgcn_global_load_lds(
        (const __attribute__((address_space(1))) unsigned int*)(g),
        (__attribute__((address_space(3))) unsigned int*)(l), 16, 0, 0);
}

// ---------------- CSR build ----------------

__global__ void hist_kernel(const int* __restrict__ dst, int* __restrict__ counts, int E) {
    int e = blockIdx.x * blockDim.x + threadIdx.x;
    if (e < E) atomicAdd(&counts[dst[e]], 1);
}

__global__ void scan_part(const int* __restrict__ counts, int* __restrict__ bsum, int n) {
    __shared__ int sd[256];
    int t = threadIdx.x, b = blockIdx.x;
    int i = b * 256 + t;
    sd[t] = (i < n) ? counts[i] : 0;
    __syncthreads();
    for (int off = 128; off > 0; off >>= 1) {
        if (t < off) sd[t] += sd[t + off];
        __syncthreads();
    }
    if (t == 0) bsum[b] = sd[0];
}

// exclusive scan of block sums; also emits the per-bucket global cursors
__global__ void scan_bsum(int* __restrict__ bsum, int* __restrict__ gbase, int nb) {
    __shared__ int sd[256];
    int t = threadIdx.x;
    int v = (t < nb) ? bsum[t] : 0;
    sd[t] = v;
    __syncthreads();
    for (int off = 1; off < 256; off <<= 1) {
        int u = (t >= off) ? sd[t - off] : 0;
        __syncthreads();
        sd[t] += u;
        __syncthreads();
    }
    if (t < nb) {
        int ex = sd[t] - v;
        bsum[t] = ex;
        gbase[t] = ex;
    }
}

__global__ void scan_final(const int* __restrict__ counts, const int* __restrict__ bsum,
                           int* __restrict__ offs, int n) {
    __shared__ int sd[256];
    int t = threadIdx.x, b = blockIdx.x;
    int i = b * 256 + t;
    int v = (i < n) ? counts[i] : 0;
    sd[t] = v;
    __syncthreads();
    for (int off = 1; off < 256; off <<= 1) {
        int u = (t >= off) ? sd[t - off] : 0;
        __syncthreads();
        sd[t] += u;
        __syncthreads();
    }
    if (i < n) offs[i] = bsum[b] + sd[t] - v;
    if (i == n - 1) offs[n] = bsum[b] + sd[t];
}

// phase C: scatter edges into bucket-major staging, one contiguous run per (block,bucket)
__global__ __launch_bounds__(256) void bucket_scatter(
    const int* __restrict__ src, const int* __restrict__ dst, const float* __restrict__ ew,
    int* __restrict__ gbase, uint2* __restrict__ edata2, int E) {
    __shared__ int cnt[NBKT];
    __shared__ int base_s[NBKT];
    int t = threadIdx.x;
    int ebase = blockIdx.x * 4096 + t;
    for (int i = t; i < NBKT; i += 256) cnt[i] = 0;
    __syncthreads();
#pragma unroll
    for (int i = 0; i < 16; ++i) {
        int e = ebase + i * 256;
        if (e < E) atomicAdd(&cnt[dst[e] >> 8], 1);
    }
    __syncthreads();
    for (int i = t; i < NBKT; i += 256) {
        int c = cnt[i];
        base_s[i] = c ? atomicAdd(&gbase[i], c) : 0;
        cnt[i] = 0;
    }
    __syncthreads();
#pragma unroll
    for (int i = 0; i < 16; ++i) {
        int e = ebase + i * 256;
        if (e < E) {
            int d = dst[e];
            int bkt = d >> 8;
            int r = atomicAdd(&cnt[bkt], 1);
            edata2[base_s[bkt] + r] =
                make_uint2((unsigned)src[e] | ((unsigned)(d & 255) << 16), f2u(ew[e]));
        }
    }
}

// phase D: per-bucket LDS sort by exact dst, then fully-coalesced write to edata
__global__ __launch_bounds__(256) void bucket_sort(
    const int* __restrict__ offs, const uint2* __restrict__ edata2, int* __restrict__ gcur,
    uint2* __restrict__ edata) {
    __shared__ uint2 stage[BCAP];
    __shared__ int loff[256];
    __shared__ int cur[256];
    int b = blockIdx.x, t = threadIdx.x;
    int nfirst = b * 256;
    int lo = offs[nfirst];
    int nend = nfirst + 256;
    if (nend > N_NODES) nend = N_NODES;
    int hi = offs[nend];
    int cnt = hi - lo;
    int node = nfirst + t;
    loff[t] = (node < N_NODES) ? (offs[node] - lo) : cnt;
    cur[t] = 0;
    __syncthreads();
    if (cnt <= BCAP) {
        for (int i = t; i < cnt; i += 256) {
            uint2 e = edata2[lo + i];
            int dl = (e.x >> 16) & 255;
            int r = atomicAdd(&cur[dl], 1);
            stage[loff[dl] + r] = make_uint2(e.x & 0xFFFFu, e.y);
        }
        __syncthreads();
        for (int i = t; i < cnt; i += 256) edata[lo + i] = stage[i];
    } else {
        for (int i = t; i < cnt; i += 256) {
            uint2 e = edata2[lo + i];
            int dl = (e.x >> 16) & 255;
            int d = nfirst + dl;
            int r = atomicAdd(&gcur[d], 1);
            edata[offs[d] + r] = make_uint2(e.x & 0xFFFFu, e.y);
        }
    }
}

// ---------------- dtype prep ----------------

__global__ void conv_x(const float* __restrict__ x, unsigned short* __restrict__ xb, int n4) {
    int i = blockIdx.x * blockDim.x + threadIdx.x;
    if (i >= n4) return;
    float4 v = ((const float4*)x)[i];
    ushort4 o;
    o.x = f2bf(v.x); o.y = f2bf(v.y); o.z = f2bf(v.z); o.w = f2bf(v.w);
    ((ushort4*)xb)[i] = o;
}

__global__ void pack_w(const float* __restrict__ Wr, const float* __restrict__ Wo,
                       unsigned short* __restrict__ Bt, int K) {
    int idx = blockIdx.x * blockDim.x + threadIdx.x;
    int total = 2 * K * DIM;
    if (idx >= total) return;
    int k = idx / DIM, c = idx % DIM;
    float v = (k < K) ? Wr[k * DIM + c] : Wo[(k - K) * DIM + c];
    Bt[(size_t)c * (2 * K) + k] = f2bf(v);
}

__global__ void pack_w4(const float* __restrict__ W2r, const float* __restrict__ W2o,
                        const float* __restrict__ W3r, const float* __restrict__ W3o,
                        const float* __restrict__ W4r, const float* __restrict__ W4o,
                        const float* __restrict__ W5r, const float* __restrict__ W5o,
                        unsigned short* __restrict__ B2, unsigned short* __restrict__ B3,
                        unsigned short* __restrict__ B4, unsigned short* __restrict__ B5) {
    int idx = blockIdx.x * blockDim.x + threadIdx.x;
    int total = 2 * DIM * DIM;
    if (idx >= total) return;
    int L = blockIdx.y;
    const float* Wr = (L == 0) ? W2r : (L == 1) ? W3r : (L == 2) ? W4r : W5r;
    const float* Wo = (L == 0) ? W2o : (L == 1) ? W3o : (L == 2) ? W4o : W5o;
    unsigned short* Bt = (L == 0) ? B2 : (L == 1) ? B3 : (L == 2) ? B4 : B5;
    int k = idx / DIM, c = idx % DIM;
    float v = (k < DIM) ? Wr[k * DIM + c] : Wo[(k - DIM) * DIM + c];
    Bt[(size_t)c * (2 * DIM) + k] = f2bf(v);
}

// ---------------- per-node aggregation ----------------
// 2 edges per wave (half-wave hf), 32 sub-lanes x 16B per row, 8-edge unroll.

template <int F>
__global__ void agg_bf16(const unsigned short* __restrict__ hsrc, const int* __restrict__ offs,
                         const uint2* __restrict__ edata, unsigned short* __restrict__ agg) {
    int node = blockIdx.x * (blockDim.x >> 6) + (threadIdx.x >> 6);
    if (node >= N_NODES) return;
    int lane = threadIdx.x & 63;
    int hf = lane >> 5;
    int sl = lane & 31;
    int s0 = offs[node], s1 = offs[node + 1];
    if (F == 256) {
        const unsigned short* hb = hsrc + sl * 8;
        float acc[8] = {0.f, 0.f, 0.f, 0.f, 0.f, 0.f, 0.f, 0.f};
        int p = s0;
        for (; p + 7 < s1; p += 8) {
            uint2 e0 = edata[p + hf];
            uint2 e1 = edata[p + 2 + hf];
            uint2 e2 = edata[p + 4 + hf];
            uint2 e3 = edata[p + 6 + hf];
            float w0 = u2f(e0.y), w1 = u2f(e1.y), w2 = u2f(e2.y), w3 = u2f(e3.y);
            uint4 r0 = *(const uint4*)(hb + (size_t)e0.x * 256);
            uint4 r1 = *(const uint4*)(hb + (size_t)e1.x * 256);
            uint4 r2 = *(const uint4*)(hb + (size_t)e2.x * 256);
            uint4 r3 = *(const uint4*)(hb + (size_t)e3.x * 256);
            acc[0] += w0 * bf2f((unsigned short)r0.x);
            acc[1] += w0 * bf2f((unsigned short)(r0.x >> 16));
            acc[2] += w0 * bf2f((unsigned short)r0.y);
            acc[3] += w0 * bf2f((unsigned short)(r0.y >> 16));
            acc[4] += w0 * bf2f((unsigned short)r0.z);
            acc[5] += w0 * bf2f((unsigned short)(r0.z >> 16));
            acc[6] += w0 * bf2f((unsigned short)r0.w);
            acc[7] += w0 * bf2f((unsigned short)(r0.w >> 16));
            acc[0] += w1 * bf2f((unsigned short)r1.x);
            acc[1] += w1 * bf2f((unsigned short)(r1.x >> 16));
            acc[2] += w1 * bf2f((unsigned short)r1.y);
            acc[3] += w1 * bf2f((unsigned short)(r1.y >> 16));
            acc[4] += w1 * bf2f((unsigned short)r1.z);
            acc[5] += w1 * bf2f((unsigned short)(r1.z >> 16));
            acc[6] += w1 * bf2f((unsigned short)r1.w);
            acc[7] += w1 * bf2f((unsigned short)(r1.w >> 16));
            acc[0] += w2 * bf2f((unsigned short)r2.x);
            acc[1] += w2 * bf2f((unsigned short)(r2.x >> 16));
            acc[2] += w2 * bf2f((unsigned short)r2.y);
            acc[3] += w2 * bf2f((unsigned short)(r2.y >> 16));
            acc[4] += w2 * bf2f((unsigned short)r2.z);
            acc[5] += w2 * bf2f((unsigned short)(r2.z >> 16));
            acc[6] += w2 * bf2f((unsigned short)r2.w);
            acc[7] += w2 * bf2f((unsigned short)(r2.w >> 16));
            acc[0] += w3 * bf2f((unsigned short)r3.x);
            acc[1] += w3 * bf2f((unsigned short)(r3.x >> 16));
            acc[2] += w3 * bf2f((unsigned short)r3.y);
            acc[3] += w3 * bf2f((unsigned short)(r3.y >> 16));
            acc[4] += w3 * bf2f((unsigned short)r3.z);
            acc[5] += w3 * bf2f((unsigned short)(r3.z >> 16));
            acc[6] += w3 * bf2f((unsigned short)r3.w);
            acc[7] += w3 * bf2f((unsigned short)(r3.w >> 16));
        }
        for (; p + 3 < s1; p += 4) {
            uint2 e0 = edata[p + hf];
            uint2 e1 = edata[p + 2 + hf];
            float w0 = u2f(e0.y), w1 = u2f(e1.y);
            uint4 r0 = *(const uint4*)(hb + (size_t)e0.x * 256);
            uint4 r1 = *(const uint4*)(hb + (size_t)e1.x * 256);
            acc[0] += w0 * bf2f((unsigned short)r0.x);
            acc[1] += w0 * bf2f((unsigned short)(r0.x >> 16));
            acc[2] += w0 * bf2f((unsigned short)r0.y);
            acc[3] += w0 * bf2f((unsigned short)(r0.y >> 16));
            acc[4] += w0 * bf2f((unsigned short)r0.z);
            acc[5] += w0 * bf2f((unsigned short)(r0.z >> 16));
            acc[6] += w0 * bf2f((unsigned short)r0.w);
            acc[7] += w0 * bf2f((unsigned short)(r0.w >> 16));
            acc[0] += w1 * bf2f((unsigned short)r1.x);
            acc[1] += w1 * bf2f((unsigned short)(r1.x >> 16));
            acc[2] += w1 * bf2f((unsigned short)r1.y);
            acc[3] += w1 * bf2f((unsigned short)(r1.y >> 16));
            acc[4] += w1 * bf2f((unsigned short)r1.z);
            acc[5] += w1 * bf2f((unsigned short)(r1.z >> 16));
            acc[6] += w1 * bf2f((unsigned short)r1.w);
            acc[7] += w1 * bf2f((unsigned short)(r1.w >> 16));
        }
        for (; p < s1; p += 2) {
            int pe = p + hf;
            bool v = pe < s1;
            uint2 e = edata[v ? pe : (s1 - 1)];
            float w = v ? u2f(e.y) : 0.f;
            uint4 r = *(const uint4*)(hb + (size_t)e.x * 256);
            acc[0] += w * bf2f((unsigned short)r.x);
            acc[1] += w * bf2f((unsigned short)(r.x >> 16));
            acc[2] += w * bf2f((unsigned short)r.y);
            acc[3] += w * bf2f((unsigned short)(r.y >> 16));
            acc[4] += w * bf2f((unsigned short)r.z);
            acc[5] += w * bf2f((unsigned short)(r.z >> 16));
            acc[6] += w * bf2f((unsigned short)r.w);
            acc[7] += w * bf2f((unsigned short)(r.w >> 16));
        }
#pragma unroll
        for (int i = 0; i < 8; ++i) acc[i] += __shfl_xor(acc[i], 32, 64);
        if (hf == 0) {
            uint4 o;
            o.x = (unsigned)f2bf(acc[0]) | ((unsigned)f2bf(acc[1]) << 16);
            o.y = (unsigned)f2bf(acc[2]) | ((unsigned)f2bf(acc[3]) << 16);
            o.z = (unsigned)f2bf(acc[4]) | ((unsigned)f2bf(acc[5]) << 16);
            o.w = (unsigned)f2bf(acc[6]) | ((unsigned)f2bf(acc[7]) << 16);
            *(uint4*)(agg + (size_t)node * 256 + sl * 8) = o;
        }
    } else {
        const unsigned short* hb = hsrc + sl * 4;
        float acc[4] = {0.f, 0.f, 0.f, 0.f};
        int p = s0;
        for (; p + 7 < s1; p += 8) {
            uint2 e0 = edata[p + hf];
            uint2 e1 = edata[p + 2 + hf];
            uint2 e2 = edata[p + 4 + hf];
            uint2 e3 = edata[p + 6 + hf];
            float w0 = u2f(e0.y), w1 = u2f(e1.y), w2 = u2f(e2.y), w3 = u2f(e3.y);
            uint2 r0 = *(const uint2*)(hb + (size_t)e0.x * 128);
            uint2 r1 = *(const uint2*)(hb + (size_t)e1.x * 128);
            uint2 r2 = *(const uint2*)(hb + (size_t)e2.x * 128);
            uint2 r3 = *(const uint2*)(hb + (size_t)e3.x * 128);
            acc[0] += w0 * bf2f((unsigned short)r0.x);
            acc[1] += w0 * bf2f((unsigned short)(r0.x >> 16));
            acc[2] += w0 * bf2f((unsigned short)r0.y);
            acc[3] += w0 * bf2f((unsigned short)(r0.y >> 16));
            acc[0] += w1 * bf2f((unsigned short)r1.x);
            acc[1] += w1 * bf2f((unsigned short)(r1.x >> 16));
            acc[2] += w1 * bf2f((unsigned short)r1.y);
            acc[3] += w1 * bf2f((unsigned short)(r1.y >> 16));
            acc[0] += w2 * bf2f((unsigned short)r2.x);
            acc[1] += w2 * bf2f((unsigned short)(r2.x >> 16));
            acc[2] += w2 * bf2f((unsigned short)r2.y);
            acc[3] += w2 * bf2f((unsigned short)(r2.y >> 16));
            acc[0] += w3 * bf2f((unsigned short)r3.x);
            acc[1] += w3 * bf2f((unsigned short)(r3.x >> 16));
            acc[2] += w3 * bf2f((unsigned short)r3.y);
            acc[3] += w3 * bf2f((unsigned short)(r3.y >> 16));
        }
        for (; p + 3 < s1; p += 4) {
            uint2 e0 = edata[p + hf];
            uint2 e1 = edata[p + 2 + hf];
            float w0 = u2f(e0.y), w1 = u2f(e1.y);
            uint2 r0 = *(const uint2*)(hb + (size_t)e0.x * 128);
            uint2 r1 = *(const uint2*)(hb + (size_t)e1.x * 128);
            acc[0] += w0 * bf2f((unsigned short)r0.x);
            acc[1] += w0 * bf2f((unsigned short)(r0.x >> 16));
            acc[2] += w0 * bf2f((unsigned short)r0.y);
            acc[3] += w0 * bf2f((unsigned short)(r0.y >> 16));
            acc[0] += w1 * bf2f((unsigned short)r1.x);
            acc[1] += w1 * bf2f((unsigned short)(r1.x >> 16));
            acc[2] += w1 * bf2f((unsigned short)r1.y);
            acc[3] += w1 * bf2f((unsigned short)(r1.y >> 16));
        }
        for (; p < s1; p += 2) {
            int pe = p + hf;
            bool v = pe < s1;
            uint2 e = edata[v ? pe : (s1 - 1)];
            float w = v ? u2f(e.y) : 0.f;
            uint2 r = *(const uint2*)(hb + (size_t)e.x * 128);
            acc[0] += w * bf2f((unsigned short)r.x);
            acc[1] += w * bf2f((unsigned short)(r.x >> 16));
            acc[2] += w * bf2f((unsigned short)r.y);
            acc[3] += w * bf2f((unsigned short)(r.y >> 16));
        }
#pragma unroll
        for (int i = 0; i < 4; ++i) acc[i] += __shfl_xor(acc[i], 32, 64);
        if (hf == 0) {
            uint2 o;
            o.x = (unsigned)f2bf(acc[0]) | ((unsigned)f2bf(acc[1]) << 16);
            o.y = (unsigned)f2bf(acc[2]) | ((unsigned)f2bf(acc[3]) << 16);
            *(uint2*)(agg + (size_t)node * 128 + sl * 4) = o;
        }
    }
}

// ---------------- MFMA dual GEMM: out = relu([A1|A2] @ Bt^T + bias), bf16 ----------------
// BK=64, XOR chunk-swizzle: LDS tile [128 rows][8 chunks x 16B], physical chunk
// p holds logical chunk p ^ (row&7). Staged via linear global_load_lds with
// pre-swizzled GLOBAL source chunk; ds_read applies the same XOR -> 2-way (free).

template <int K>
__global__ __launch_bounds__(256) void gemm_mfma(
    const unsigned short* __restrict__ A1, const unsigned short* __restrict__ A2,
    const unsigned short* __restrict__ Bt, const float* __restrict__ bias,
    unsigned short* __restrict__ out) {
    __shared__ unsigned short As[128 * 64];
    __shared__ unsigned short Bs[128 * 64];
    const int t = threadIdx.x;
    const int lane = t & 63;
    const int w = t >> 6;
    const int wr = w >> 1, wc = w & 1;
    const int row0 = blockIdx.x * 128, col0 = blockIdx.y * 128;
    const int fr = lane & 15, fq = lane >> 4;

    const int srow = t >> 3;                  // 0..31 within a 32-row round
    const int schunk = (t & 7) ^ (srow & 7);  // swizzled source k-chunk

    int arow_[4];
#pragma unroll
    for (int g = 0; g < 4; ++g) {
        int r = row0 + g * 32 + srow;
        if (r >= N_NODES) r = N_NODES - 1;
        arow_[g] = r;
    }

    f32x4 acc[4][4] = {};

    constexpr int NT = (2 * K) / 64;
    for (int kt = 0; kt < NT; ++kt) {
        const int kk = kt * 64;
        const unsigned short* Ap;
        int ka;
        if (kk < K) { Ap = A1; ka = kk; } else { Ap = A2; ka = kk - K; }
#pragma unroll
        for (int g = 0; g < 4; ++g) {
            gload16(Ap + (size_t)arow_[g] * K + ka + schunk * 8, As + g * 2048 + w * 512);
            gload16(Bt + (size_t)(col0 + g * 32 + srow) * (2 * K) + kk + schunk * 8,
                    Bs + g * 2048 + w * 512);
        }
        __syncthreads();
        bf16x8 a[2][4], b[2][4];
#pragma unroll
        for (int kh = 0; kh < 2; ++kh) {
#pragma unroll
            for (int m = 0; m < 4; ++m) {
                int row = wr * 64 + m * 16 + fr;
                a[kh][m] = *(const bf16x8*)(As + row * 64 + ((kh * 4 + fq) ^ (row & 7)) * 8);
            }
#pragma unroll
            for (int n = 0; n < 4; ++n) {
                int row = wc * 64 + n * 16 + fr;
                b[kh][n] = *(const bf16x8*)(Bs + row * 64 + ((kh * 4 + fq) ^ (row & 7)) * 8);
            }
        }
#pragma unroll
        for (int kh = 0; kh < 2; ++kh)
#pragma unroll
            for (int m = 0; m < 4; ++m)
#pragma unroll
                for (int n = 0; n < 4; ++n)
                    acc[m][n] = __builtin_amdgcn_mfma_f32_16x16x32_bf16(a[kh][m], b[kh][n],
                                                                        acc[m][n], 0, 0, 0);
        __syncthreads();
    }

#pragma unroll
    for (int n = 0; n < 4; ++n) {
        const int col = col0 + wc * 64 + n * 16 + fr;
        const float bv = bias[col];
#pragma unroll
        for (int m = 0; m < 4; ++m) {
            const int rbase = row0 + wr * 64 + m * 16 + fq * 4;
#pragma unroll
            for (int j = 0; j < 4; ++j) {
                const int r = rbase + j;
                if (r < N_NODES)
                    out[(size_t)r * DIM + col] = f2bf(fmaxf(acc[m][n][j] + bv, 0.f));
            }
        }
    }
}

// ---------------- fused pool (sorted batch) + FC head + log_softmax ----------------

__global__ void pool_head_kernel(const unsigned short* __restrict__ h,
                                 const int* __restrict__ batch,
                                 const float* __restrict__ Wfc1, const float* __restrict__ bfc1,
                                 const float* __restrict__ Wfc2, const float* __restrict__ bfc2,
                                 float* __restrict__ out) {
    __shared__ float4 sd[4][64];
    __shared__ float row[DIM];
    __shared__ float fc1[DIM];
    __shared__ float logits[NUM_CLASSES];
    __shared__ float red[2];
    int g = blockIdx.x, t = threadIdx.x;
    int wv = t >> 6, lane = t & 63;
    int lo = 0, hi = N_NODES;
    while (lo < hi) { int m = (lo + hi) >> 1; if (batch[m] < g) lo = m + 1; else hi = m; }
    int start = lo;
    lo = 0; hi = N_NODES;
    while (lo < hi) { int m = (lo + hi) >> 1; if (batch[m] < g + 1) lo = m + 1; else hi = m; }
    int end = lo;
    float4 acc = {0.f, 0.f, 0.f, 0.f};
    for (int i = start + wv; i < end; i += 4) {
        uint2 r = *(const uint2*)(h + (size_t)i * 256 + lane * 4);
        acc.x += bf2f((unsigned short)r.x);
        acc.y += bf2f((unsigned short)(r.x >> 16));
        acc.z += bf2f((unsigned short)r.y);
        acc.w += bf2f((unsigned short)(r.y >> 16));
    }
    sd[wv][lane] = acc;
    __syncthreads();
    if (wv == 0) {
        float4 a = sd[0][lane], b = sd[1][lane], c = sd[2][lane], d = sd[3][lane];
        float4 s;
        s.x = a.x + b.x + c.x + d.x;
        s.y = a.y + b.y + c.y + d.y;
        s.z = a.z + b.z + c.z + d.z;
        s.w = a.w + b.w + c.w + d.w;
        *(float4*)(&row[lane * 4]) = s;
    }
    __syncthreads();
    float a1 = bfc1[t];
    for (int k = 0; k < DIM; ++k) a1 += row[k] * Wfc1[k * DIM + t];
    fc1[t] = fmaxf(a1, 0.f);
    __syncthreads();
    if (t < NUM_CLASSES) {
        float a = bfc2[t];
        for (int k = 0; k < DIM; ++k) a += fc1[k] * Wfc2[k * NUM_CLASSES + t];
        logits[t] = a;
    }
    __syncthreads();
    if (t == 0) {
        float mx = -INFINITY;
        for (int c2 = 0; c2 < NUM_CLASSES; ++c2) mx = fmaxf(mx, logits[c2]);
        float s = 0.f;
        for (int c2 = 0; c2 < NUM_CLASSES; ++c2) s += expf(logits[c2] - mx);
        red[0] = mx;
        red[1] = logf(s);
    }
    __syncthreads();
    if (t < NUM_CLASSES) out[g * NUM_CLASSES + t] = logits[t] - red[0] - red[1];
}

// ---------------- launch ----------------

extern "C" void kernel_launch(void* const* d_in, const int* in_sizes, int n_in,
                              void* d_out, int out_size, void* d_ws, size_t ws_size,
                              hipStream_t stream) {
    const float* x = (const float*)d_in[0];
    const int* ei = (const int*)d_in[1];
    const int* batch = (const int*)d_in[2];
    const float* ew = (const float*)d_in[3];
    const float *Wr[5], *br[5], *Wo[5];
    for (int i = 0; i < 5; ++i) {
        Wr[i] = (const float*)d_in[4 + 3 * i];
        br[i] = (const float*)d_in[5 + 3 * i];
        Wo[i] = (const float*)d_in[6 + 3 * i];
    }
    const float* Wfc1 = (const float*)d_in[19];
    const float* bfc1 = (const float*)d_in[20];
    const float* Wfc2 = (const float*)d_in[21];
    const float* bfc2 = (const float*)d_in[22];
    float* out = (float*)d_out;

    char* ws = (char*)d_ws;
    size_t off = 0;
    auto alloc = [&](size_t bytes) {
        void* p = ws + off;
        off += (bytes + 255) & ~(size_t)255;
        return p;
    };
    unsigned short* xb = (unsigned short*)alloc((size_t)N_NODES * F_IN * 2);
    unsigned short* h0 = (unsigned short*)alloc((size_t)N_NODES * DIM * 2);
    unsigned short* h1 = (unsigned short*)alloc((size_t)N_NODES * DIM * 2);
    unsigned short* aggb = (unsigned short*)alloc((size_t)N_NODES * DIM * 2);
    unsigned short* Bt[5];
    Bt[0] = (unsigned short*)alloc((size_t)2 * F_IN * DIM * 2);
    for (int i = 1; i < 5; ++i) Bt[i] = (unsigned short*)alloc((size_t)2 * DIM * DIM * 2);
    int* offs = (int*)alloc((N_NODES + 1) * 4);
    int* counts = (int*)alloc((size_t)2 * N_NODES * 4);
    int* cursor = counts + N_NODES;
    int* bsum = (int*)alloc(NB_SCAN * 4);
    int* gbase = (int*)alloc(NBKT * 4);
    uint2* edata = (uint2*)alloc((size_t)N_EDGES * 8);
    uint2* edata2 = (uint2*)alloc((size_t)N_EDGES * 8);

    const int* src = ei;
    const int* dstp = ei + N_EDGES;

    hipMemsetAsync(counts, 0, (size_t)2 * N_NODES * 4, stream);
    hist_kernel<<<(N_EDGES + 255) / 256, 256, 0, stream>>>(dstp, counts, N_EDGES);
    scan_part<<<NB_SCAN, 256, 0, stream>>>(counts, bsum, N_NODES);
    scan_bsum<<<1, 256, 0, stream>>>(bsum, gbase, NB_SCAN);
    scan_final<<<NB_SCAN, 256, 0, stream>>>(counts, bsum, offs, N_NODES);
    bucket_scatter<<<(N_EDGES + 4095) / 4096, 256, 0, stream>>>(src, dstp, ew, gbase, edata2,
                                                                N_EDGES);
    bucket_sort<<<NBKT, 256, 0, stream>>>(offs, edata2, cursor, edata);

    conv_x<<<((N_NODES * F_IN / 4) + 255) / 256, 256, 0, stream>>>(x, xb, N_NODES * F_IN / 4);
    pack_w<<<(2 * F_IN * DIM + 255) / 256, 256, 0, stream>>>(Wr[0], Wo[0], Bt[0], F_IN);
    {
        dim3 pg((2 * DIM * DIM + 255) / 256, 4);
        pack_w4<<<pg, 256, 0, stream>>>(Wr[1], Wo[1], Wr[2], Wo[2], Wr[3], Wo[3], Wr[4], Wo[4],
                                        Bt[1], Bt[2], Bt[3], Bt[4]);
    }

    dim3 ggrid((N_NODES + 127) / 128, 2);

    // layer 1 (K = 128)
    agg_bf16<128><<<(N_NODES + 3) / 4, 256, 0, stream>>>(xb, offs, edata, aggb);
    gemm_mfma<128><<<ggrid, 256, 0, stream>>>(aggb, xb, Bt[0], br[0], h0);

    const unsigned short* hp = h0;
    unsigned short* hn = h1;
    for (int L = 1; L < 5; ++L) {
        agg_bf16<256><<<(N_NODES + 3) / 4, 256, 0, stream>>>(hp, offs, edata, aggb);
        gemm_mfma<256><<<ggrid, 256, 0, stream>>>(aggb, hp, Bt[L], br[L], hn);
        unsigned short* t2 = (unsigned short*)hp;
        hp = hn;
        hn = t2;
    }

    pool_head_kernel<<<NUM_GRAPHS, 256, 0, stream>>>(hp, batch, Wfc1, bfc1, Wfc2, bfc2, out);
}

// Round 15
// 528.466 us; speedup vs baseline: 3.0976x; 1.0716x over previous
//
#include <hip/hip_runtime.h>
#include <hip/hip_bf16.h>

#define N_NODES 50000
#define N_EDGES 800000
#define F_IN 128
#define DIM 256
#define NUM_CLASSES 10
#define NUM_GRAPHS 256
#define NBKT ((N_NODES + 255) / 256)
#define BCAP 8192
#define NRT ((N_NODES + 127) / 128)

typedef short bf16x8 __attribute__((ext_vector_type(8)));
typedef float f32x4 __attribute__((ext_vector_type(4)));

__device__ __forceinline__ float bf2f(unsigned short u) {
    union { unsigned int u; float f; } c;
    c.u = ((unsigned int)u) << 16;
    return c.f;
}
__device__ __forceinline__ unsigned short f2bf(float f) {
    union { float f; unsigned int u; } c;
    c.f = f;
    unsigned int r = (c.u + 0x7fffu + ((c.u >> 16) & 1u)) >> 16;
    return (unsigned short)r;
}
__device__ __forceinline__ float u2f(unsigned int u) {
    union { unsigned int u; float f; } c;
    c.u = u;
    return c.f;
}
__device__ __forceinline__ unsigned int f2u(float f) {
    union { float f; unsigned int u; } c;
    c.f = f;
    return c.u;
}

__device__ __forceinline__ void gload16(const unsigned short* g, unsigned short* l) {
    __builtin_amdgcn_global_load_lds(
        (const __attribute__((address_space(1))) unsigned int*)(g),
        (__attribute__((address_space(3))) unsigned int*)(l), 16, 0, 0);
}

// ---------------- CSR build (bucket-level only) ----------------

// per-bucket histogram: 196 counters, LDS-aggregated
__global__ void bucket_hist(const int* __restrict__ dst, int* __restrict__ bcnt, int E) {
    __shared__ int c[NBKT];
    int t = threadIdx.x;
    for (int i = t; i < NBKT; i += 256) c[i] = 0;
    __syncthreads();
    int ebase = blockIdx.x * 4096 + t;
#pragma unroll
    for (int i = 0; i < 16; ++i) {
        int e = ebase + i * 256;
        if (e < E) atomicAdd(&c[dst[e] >> 8], 1);
    }
    __syncthreads();
    for (int i = t; i < NBKT; i += 256)
        if (c[i]) atomicAdd(&bcnt[i], c[i]);
}

// exclusive scan of bucket counts -> bbase[NBKT+1] and gbase (scatter cursors)
__global__ void scan_bkt(const int* __restrict__ bcnt, int* __restrict__ bbase,
                         int* __restrict__ gbase) {
    __shared__ int sd[256];
    int t = threadIdx.x;
    int v = (t < NBKT) ? bcnt[t] : 0;
    sd[t] = v;
    __syncthreads();
    for (int off = 1; off < 256; off <<= 1) {
        int u = (t >= off) ? sd[t - off] : 0;
        __syncthreads();
        sd[t] += u;
        __syncthreads();
    }
    if (t < NBKT) {
        int ex = sd[t] - v;
        bbase[t] = ex;
        gbase[t] = ex;
    }
    if (t == NBKT - 1) bbase[NBKT] = sd[t];
}

// phase C: scatter edges into bucket-major staging, one contiguous run per (block,bucket)
__global__ __launch_bounds__(256) void bucket_scatter(
    const int* __restrict__ src, const int* __restrict__ dst, const float* __restrict__ ew,
    int* __restrict__ gbase, uint2* __restrict__ edata2, int E) {
    __shared__ int cnt[NBKT];
    __shared__ int base_s[NBKT];
    int t = threadIdx.x;
    int ebase = blockIdx.x * 4096 + t;
    for (int i = t; i < NBKT; i += 256) cnt[i] = 0;
    __syncthreads();
#pragma unroll
    for (int i = 0; i < 16; ++i) {
        int e = ebase + i * 256;
        if (e < E) atomicAdd(&cnt[dst[e] >> 8], 1);
    }
    __syncthreads();
    for (int i = t; i < NBKT; i += 256) {
        int c = cnt[i];
        base_s[i] = c ? atomicAdd(&gbase[i], c) : 0;
        cnt[i] = 0;
    }
    __syncthreads();
#pragma unroll
    for (int i = 0; i < 16; ++i) {
        int e = ebase + i * 256;
        if (e < E) {
            int d = dst[e];
            int bkt = d >> 8;
            int r = atomicAdd(&cnt[bkt], 1);
            edata2[base_s[bkt] + r] =
                make_uint2((unsigned)src[e] | ((unsigned)(d & 255) << 16), f2u(ew[e]));
        }
    }
}

// phase D: per-bucket sort by exact dst + per-node offs derivation, coalesced output
__global__ __launch_bounds__(256) void bucket_sort(
    const int* __restrict__ bbase, const uint2* __restrict__ edata2, uint2* __restrict__ edata,
    int* __restrict__ offs) {
    __shared__ uint2 stage[BCAP];
    __shared__ int cnt[256];
    __shared__ int sd[256];
    int b = blockIdx.x, t = threadIdx.x;
    int lo = bbase[b];
    int hi = bbase[b + 1];
    int ce = hi - lo;
    cnt[t] = 0;
    __syncthreads();
    // pass 1: count per dst-low
    for (int i = t; i < ce; i += 256) {
        uint2 e = edata2[lo + i];
        atomicAdd(&cnt[(e.x >> 16) & 255], 1);
    }
    __syncthreads();
    int myc = cnt[t];
    sd[t] = myc;
    __syncthreads();
    for (int off = 1; off < 256; off <<= 1) {
        int u = (t >= off) ? sd[t - off] : 0;
        __syncthreads();
        sd[t] += u;
        __syncthreads();
    }
    int ex = sd[t] - myc;  // exclusive local offset
    __syncthreads();
    sd[t] = ex;  // sd now holds loff
    cnt[t] = 0;
    int node = b * 256 + t;
    if (node < N_NODES) offs[node] = lo + ex;
    if (node == N_NODES - 1) offs[N_NODES] = lo + ex + myc;
    __syncthreads();
    // pass 2: place
    if (ce <= BCAP) {
        for (int i = t; i < ce; i += 256) {
            uint2 e = edata2[lo + i];
            int dl = (e.x >> 16) & 255;
            int r = atomicAdd(&cnt[dl], 1);
            stage[sd[dl] + r] = make_uint2(e.x & 0xFFFFu, e.y);
        }
        __syncthreads();
        for (int i = t; i < ce; i += 256) edata[lo + i] = stage[i];
    } else {
        for (int i = t; i < ce; i += 256) {
            uint2 e = edata2[lo + i];
            int dl = (e.x >> 16) & 255;
            int r = atomicAdd(&cnt[dl], 1);
            edata[lo + sd[dl] + r] = make_uint2(e.x & 0xFFFFu, e.y);
        }
    }
}

// ---------------- dtype prep ----------------

__global__ void conv_x(const float* __restrict__ x, unsigned short* __restrict__ xb, int n4) {
    int i = blockIdx.x * blockDim.x + threadIdx.x;
    if (i >= n4) return;
    float4 v = ((const float4*)x)[i];
    ushort4 o;
    o.x = f2bf(v.x); o.y = f2bf(v.y); o.z = f2bf(v.z); o.w = f2bf(v.w);
    ((ushort4*)xb)[i] = o;
}

__global__ void pack_w(const float* __restrict__ Wr, const float* __restrict__ Wo,
                       unsigned short* __restrict__ Bt, int K) {
    int idx = blockIdx.x * blockDim.x + threadIdx.x;
    int total = 2 * K * DIM;
    if (idx >= total) return;
    int k = idx / DIM, c = idx % DIM;
    float v = (k < K) ? Wr[k * DIM + c] : Wo[(k - K) * DIM + c];
    Bt[(size_t)c * (2 * K) + k] = f2bf(v);
}

__global__ void pack_w4(const float* __restrict__ W2r, const float* __restrict__ W2o,
                        const float* __restrict__ W3r, const float* __restrict__ W3o,
                        const float* __restrict__ W4r, const float* __restrict__ W4o,
                        const float* __restrict__ W5r, const float* __restrict__ W5o,
                        unsigned short* __restrict__ B2, unsigned short* __restrict__ B3,
                        unsigned short* __restrict__ B4, unsigned short* __restrict__ B5) {
    int idx = blockIdx.x * blockDim.x + threadIdx.x;
    int total = 2 * DIM * DIM;
    if (idx >= total) return;
    int L = blockIdx.y;
    const float* Wr = (L == 0) ? W2r : (L == 1) ? W3r : (L == 2) ? W4r : W5r;
    const float* Wo = (L == 0) ? W2o : (L == 1) ? W3o : (L == 2) ? W4o : W5o;
    unsigned short* Bt = (L == 0) ? B2 : (L == 1) ? B3 : (L == 2) ? B4 : B5;
    int k = idx / DIM, c = idx % DIM;
    float v = (k < DIM) ? Wr[k * DIM + c] : Wo[(k - DIM) * DIM + c];
    Bt[(size_t)c * (2 * DIM) + k] = f2bf(v);
}

// ---------------- per-node aggregation ----------------
// 2 edges per wave (half-wave hf), 32 sub-lanes x 16B per row, 8-edge unroll.

template <int F>
__global__ void agg_bf16(const unsigned short* __restrict__ hsrc, const int* __restrict__ offs,
                         const uint2* __restrict__ edata, unsigned short* __restrict__ agg) {
    int node = blockIdx.x * (blockDim.x >> 6) + (threadIdx.x >> 6);
    if (node >= N_NODES) return;
    int lane = threadIdx.x & 63;
    int hf = lane >> 5;
    int sl = lane & 31;
    int s0 = offs[node], s1 = offs[node + 1];
    if (F == 256) {
        const unsigned short* hb = hsrc + sl * 8;
        float acc[8] = {0.f, 0.f, 0.f, 0.f, 0.f, 0.f, 0.f, 0.f};
        int p = s0;
        for (; p + 7 < s1; p += 8) {
            uint2 e0 = edata[p + hf];
            uint2 e1 = edata[p + 2 + hf];
            uint2 e2 = edata[p + 4 + hf];
            uint2 e3 = edata[p + 6 + hf];
            float w0 = u2f(e0.y), w1 = u2f(e1.y), w2 = u2f(e2.y), w3 = u2f(e3.y);
            uint4 r0 = *(const uint4*)(hb + (size_t)e0.x * 256);
            uint4 r1 = *(const uint4*)(hb + (size_t)e1.x * 256);
            uint4 r2 = *(const uint4*)(hb + (size_t)e2.x * 256);
            uint4 r3 = *(const uint4*)(hb + (size_t)e3.x * 256);
            acc[0] += w0 * bf2f((unsigned short)r0.x);
            acc[1] += w0 * bf2f((unsigned short)(r0.x >> 16));
            acc[2] += w0 * bf2f((unsigned short)r0.y);
            acc[3] += w0 * bf2f((unsigned short)(r0.y >> 16));
            acc[4] += w0 * bf2f((unsigned short)r0.z);
            acc[5] += w0 * bf2f((unsigned short)(r0.z >> 16));
            acc[6] += w0 * bf2f((unsigned short)r0.w);
            acc[7] += w0 * bf2f((unsigned short)(r0.w >> 16));
            acc[0] += w1 * bf2f((unsigned short)r1.x);
            acc[1] += w1 * bf2f((unsigned short)(r1.x >> 16));
            acc[2] += w1 * bf2f((unsigned short)r1.y);
            acc[3] += w1 * bf2f((unsigned short)(r1.y >> 16));
            acc[4] += w1 * bf2f((unsigned short)r1.z);
            acc[5] += w1 * bf2f((unsigned short)(r1.z >> 16));
            acc[6] += w1 * bf2f((unsigned short)r1.w);
            acc[7] += w1 * bf2f((unsigned short)(r1.w >> 16));
            acc[0] += w2 * bf2f((unsigned short)r2.x);
            acc[1] += w2 * bf2f((unsigned short)(r2.x >> 16));
            acc[2] += w2 * bf2f((unsigned short)r2.y);
            acc[3] += w2 * bf2f((unsigned short)(r2.y >> 16));
            acc[4] += w2 * bf2f((unsigned short)r2.z);
            acc[5] += w2 * bf2f((unsigned short)(r2.z >> 16));
            acc[6] += w2 * bf2f((unsigned short)r2.w);
            acc[7] += w2 * bf2f((unsigned short)(r2.w >> 16));
            acc[0] += w3 * bf2f((unsigned short)r3.x);
            acc[1] += w3 * bf2f((unsigned short)(r3.x >> 16));
            acc[2] += w3 * bf2f((unsigned short)r3.y);
            acc[3] += w3 * bf2f((unsigned short)(r3.y >> 16));
            acc[4] += w3 * bf2f((unsigned short)r3.z);
            acc[5] += w3 * bf2f((unsigned short)(r3.z >> 16));
            acc[6] += w3 * bf2f((unsigned short)r3.w);
            acc[7] += w3 * bf2f((unsigned short)(r3.w >> 16));
        }
        for (; p + 3 < s1; p += 4) {
            uint2 e0 = edata[p + hf];
            uint2 e1 = edata[p + 2 + hf];
            float w0 = u2f(e0.y), w1 = u2f(e1.y);
            uint4 r0 = *(const uint4*)(hb + (size_t)e0.x * 256);
            uint4 r1 = *(const uint4*)(hb + (size_t)e1.x * 256);
            acc[0] += w0 * bf2f((unsigned short)r0.x);
            acc[1] += w0 * bf2f((unsigned short)(r0.x >> 16));
            acc[2] += w0 * bf2f((unsigned short)r0.y);
            acc[3] += w0 * bf2f((unsigned short)(r0.y >> 16));
            acc[4] += w0 * bf2f((unsigned short)r0.z);
            acc[5] += w0 * bf2f((unsigned short)(r0.z >> 16));
            acc[6] += w0 * bf2f((unsigned short)r0.w);
            acc[7] += w0 * bf2f((unsigned short)(r0.w >> 16));
            acc[0] += w1 * bf2f((unsigned short)r1.x);
            acc[1] += w1 * bf2f((unsigned short)(r1.x >> 16));
            acc[2] += w1 * bf2f((unsigned short)r1.y);
            acc[3] += w1 * bf2f((unsigned short)(r1.y >> 16));
            acc[4] += w1 * bf2f((unsigned short)r1.z);
            acc[5] += w1 * bf2f((unsigned short)(r1.z >> 16));
            acc[6] += w1 * bf2f((unsigned short)r1.w);
            acc[7] += w1 * bf2f((unsigned short)(r1.w >> 16));
        }
        for (; p < s1; p += 2) {
            int pe = p + hf;
            bool v = pe < s1;
            uint2 e = edata[v ? pe : (s1 - 1)];
            float w = v ? u2f(e.y) : 0.f;
            uint4 r = *(const uint4*)(hb + (size_t)e.x * 256);
            acc[0] += w * bf2f((unsigned short)r.x);
            acc[1] += w * bf2f((unsigned short)(r.x >> 16));
            acc[2] += w * bf2f((unsigned short)r.y);
            acc[3] += w * bf2f((unsigned short)(r.y >> 16));
            acc[4] += w * bf2f((unsigned short)r.z);
            acc[5] += w * bf2f((unsigned short)(r.z >> 16));
            acc[6] += w * bf2f((unsigned short)r.w);
            acc[7] += w * bf2f((unsigned short)(r.w >> 16));
        }
#pragma unroll
        for (int i = 0; i < 8; ++i) acc[i] += __shfl_xor(acc[i], 32, 64);
        if (hf == 0) {
            uint4 o;
            o.x = (unsigned)f2bf(acc[0]) | ((unsigned)f2bf(acc[1]) << 16);
            o.y = (unsigned)f2bf(acc[2]) | ((unsigned)f2bf(acc[3]) << 16);
            o.z = (unsigned)f2bf(acc[4]) | ((unsigned)f2bf(acc[5]) << 16);
            o.w = (unsigned)f2bf(acc[6]) | ((unsigned)f2bf(acc[7]) << 16);
            *(uint4*)(agg + (size_t)node * 256 + sl * 8) = o;
        }
    } else {
        const unsigned short* hb = hsrc + sl * 4;
        float acc[4] = {0.f, 0.f, 0.f, 0.f};
        int p = s0;
        for (; p + 7 < s1; p += 8) {
            uint2 e0 = edata[p + hf];
            uint2 e1 = edata[p + 2 + hf];
            uint2 e2 = edata[p + 4 + hf];
            uint2 e3 = edata[p + 6 + hf];
            float w0 = u2f(e0.y), w1 = u2f(e1.y), w2 = u2f(e2.y), w3 = u2f(e3.y);
            uint2 r0 = *(const uint2*)(hb + (size_t)e0.x * 128);
            uint2 r1 = *(const uint2*)(hb + (size_t)e1.x * 128);
            uint2 r2 = *(const uint2*)(hb + (size_t)e2.x * 128);
            uint2 r3 = *(const uint2*)(hb + (size_t)e3.x * 128);
            acc[0] += w0 * bf2f((unsigned short)r0.x);
            acc[1] += w0 * bf2f((unsigned short)(r0.x >> 16));
            acc[2] += w0 * bf2f((unsigned short)r0.y);
            acc[3] += w0 * bf2f((unsigned short)(r0.y >> 16));
            acc[0] += w1 * bf2f((unsigned short)r1.x);
            acc[1] += w1 * bf2f((unsigned short)(r1.x >> 16));
            acc[2] += w1 * bf2f((unsigned short)r1.y);
            acc[3] += w1 * bf2f((unsigned short)(r1.y >> 16));
            acc[0] += w2 * bf2f((unsigned short)r2.x);
            acc[1] += w2 * bf2f((unsigned short)(r2.x >> 16));
            acc[2] += w2 * bf2f((unsigned short)r2.y);
            acc[3] += w2 * bf2f((unsigned short)(r2.y >> 16));
            acc[0] += w3 * bf2f((unsigned short)r3.x);
            acc[1] += w3 * bf2f((unsigned short)(r3.x >> 16));
            acc[2] += w3 * bf2f((unsigned short)r3.y);
            acc[3] += w3 * bf2f((unsigned short)(r3.y >> 16));
        }
        for (; p + 3 < s1; p += 4) {
            uint2 e0 = edata[p + hf];
            uint2 e1 = edata[p + 2 + hf];
            float w0 = u2f(e0.y), w1 = u2f(e1.y);
            uint2 r0 = *(const uint2*)(hb + (size_t)e0.x * 128);
            uint2 r1 = *(const uint2*)(hb + (size_t)e1.x * 128);
            acc[0] += w0 * bf2f((unsigned short)r0.x);
            acc[1] += w0 * bf2f((unsigned short)(r0.x >> 16));
            acc[2] += w0 * bf2f((unsigned short)r0.y);
            acc[3] += w0 * bf2f((unsigned short)(r0.y >> 16));
            acc[0] += w1 * bf2f((unsigned short)r1.x);
            acc[1] += w1 * bf2f((unsigned short)(r1.x >> 16));
            acc[2] += w1 * bf2f((unsigned short)r1.y);
            acc[3] += w1 * bf2f((unsigned short)(r1.y >> 16));
        }
        for (; p < s1; p += 2) {
            int pe = p + hf;
            bool v = pe < s1;
            uint2 e = edata[v ? pe : (s1 - 1)];
            float w = v ? u2f(e.y) : 0.f;
            uint2 r = *(const uint2*)(hb + (size_t)e.x * 128);
            acc[0] += w * bf2f((unsigned short)r.x);
            acc[1] += w * bf2f((unsigned short)(r.x >> 16));
            acc[2] += w * bf2f((unsigned short)r.y);
            acc[3] += w * bf2f((unsigned short)(r.y >> 16));
        }
#pragma unroll
        for (int i = 0; i < 4; ++i) acc[i] += __shfl_xor(acc[i], 32, 64);
        if (hf == 0) {
            uint2 o;
            o.x = (unsigned)f2bf(acc[0]) | ((unsigned)f2bf(acc[1]) << 16);
            o.y = (unsigned)f2bf(acc[2]) | ((unsigned)f2bf(acc[3]) << 16);
            *(uint2*)(agg + (size_t)node * 128 + sl * 4) = o;
        }
    }
}

// ---------------- MFMA dual GEMM: out = relu([A1|A2] @ Bt^T + bias), bf16 ----------------
// BK=64 + XOR chunk-swizzle (R13). NEW: 1-D grid in 16-block chunks of
// {8 row-tiles x 2 col-tiles}; the two col-tiles of a row are 8 ids apart ->
// same XCD under round-robin dispatch -> A-tile read once per XCD L2.

template <int K>
__global__ __launch_bounds__(256) void gemm_mfma(
    const unsigned short* __restrict__ A1, const unsigned short* __restrict__ A2,
    const unsigned short* __restrict__ Bt, const float* __restrict__ bias,
    unsigned short* __restrict__ out) {
    __shared__ unsigned short As[128 * 64];
    __shared__ unsigned short Bs[128 * 64];
    const int bb = blockIdx.x;
    const int chunkid = bb >> 4, ii = bb & 15;
    const int row_t = chunkid * 8 + (ii & 7);
    const int col_t = ii >> 3;
    if (row_t >= NRT) return;
    const int row0 = row_t * 128, col0 = col_t * 128;
    const int t = threadIdx.x;
    const int lane = t & 63;
    const int w = t >> 6;
    const int wr = w >> 1, wc = w & 1;
    const int fr = lane & 15, fq = lane >> 4;

    const int srow = t >> 3;                  // 0..31 within a 32-row round
    const int schunk = (t & 7) ^ (srow & 7);  // swizzled source k-chunk

    int arow_[4];
#pragma unroll
    for (int g = 0; g < 4; ++g) {
        int r = row0 + g * 32 + srow;
        if (r >= N_NODES) r = N_NODES - 1;
        arow_[g] = r;
    }

    f32x4 acc[4][4] = {};

    constexpr int NT = (2 * K) / 64;
    for (int kt = 0; kt < NT; ++kt) {
        const int kk = kt * 64;
        const unsigned short* Ap;
        int ka;
        if (kk < K) { Ap = A1; ka = kk; } else { Ap = A2; ka = kk - K; }
#pragma unroll
        for (int g = 0; g < 4; ++g) {
            gload16(Ap + (size_t)arow_[g] * K + ka + schunk * 8, As + g * 2048 + w * 512);
            gload16(Bt + (size_t)(col0 + g * 32 + srow) * (2 * K) + kk + schunk * 8,
                    Bs + g * 2048 + w * 512);
        }
        __syncthreads();
        bf16x8 a[2][4], b[2][4];
#pragma unroll
        for (int kh = 0; kh < 2; ++kh) {
#pragma unroll
            for (int m = 0; m < 4; ++m) {
                int row = wr * 64 + m * 16 + fr;
                a[kh][m] = *(const bf16x8*)(As + row * 64 + ((kh * 4 + fq) ^ (row & 7)) * 8);
            }
#pragma unroll
            for (int n = 0; n < 4; ++n) {
                int row = wc * 64 + n * 16 + fr;
                b[kh][n] = *(const bf16x8*)(Bs + row * 64 + ((kh * 4 + fq) ^ (row & 7)) * 8);
            }
        }
#pragma unroll
        for (int kh = 0; kh < 2; ++kh)
#pragma unroll
            for (int m = 0; m < 4; ++m)
#pragma unroll
                for (int n = 0; n < 4; ++n)
                    acc[m][n] = __builtin_amdgcn_mfma_f32_16x16x32_bf16(a[kh][m], b[kh][n],
                                                                        acc[m][n], 0, 0, 0);
        __syncthreads();
    }

#pragma unroll
    for (int n = 0; n < 4; ++n) {
        const int col = col0 + wc * 64 + n * 16 + fr;
        const float bv = bias[col];
#pragma unroll
        for (int m = 0; m < 4; ++m) {
            const int rbase = row0 + wr * 64 + m * 16 + fq * 4;
#pragma unroll
            for (int j = 0; j < 4; ++j) {
                const int r = rbase + j;
                if (r < N_NODES)
                    out[(size_t)r * DIM + col] = f2bf(fmaxf(acc[m][n][j] + bv, 0.f));
            }
        }
    }
}

// ---------------- fused pool (sorted batch) + FC head + log_softmax ----------------

__global__ void pool_head_kernel(const unsigned short* __restrict__ h,
                                 const int* __restrict__ batch,
                                 const float* __restrict__ Wfc1, const float* __restrict__ bfc1,
                                 const float* __restrict__ Wfc2, const float* __restrict__ bfc2,
                                 float* __restrict__ out) {
    __shared__ float4 sd[4][64];
    __shared__ float row[DIM];
    __shared__ float fc1[DIM];
    __shared__ float logits[NUM_CLASSES];
    __shared__ float red[2];
    int g = blockIdx.x, t = threadIdx.x;
    int wv = t >> 6, lane = t & 63;
    int lo = 0, hi = N_NODES;
    while (lo < hi) { int m = (lo + hi) >> 1; if (batch[m] < g) lo = m + 1; else hi = m; }
    int start = lo;
    lo = 0; hi = N_NODES;
    while (lo < hi) { int m = (lo + hi) >> 1; if (batch[m] < g + 1) lo = m + 1; else hi = m; }
    int end = lo;
    float4 acc = {0.f, 0.f, 0.f, 0.f};
    for (int i = start + wv; i < end; i += 4) {
        uint2 r = *(const uint2*)(h + (size_t)i * 256 + lane * 4);
        acc.x += bf2f((unsigned short)r.x);
        acc.y += bf2f((unsigned short)(r.x >> 16));
        acc.z += bf2f((unsigned short)r.y);
        acc.w += bf2f((unsigned short)(r.y >> 16));
    }
    sd[wv][lane] = acc;
    __syncthreads();
    if (wv == 0) {
        float4 a = sd[0][lane], b = sd[1][lane], c = sd[2][lane], d = sd[3][lane];
        float4 s;
        s.x = a.x + b.x + c.x + d.x;
        s.y = a.y + b.y + c.y + d.y;
        s.z = a.z + b.z + c.z + d.z;
        s.w = a.w + b.w + c.w + d.w;
        *(float4*)(&row[lane * 4]) = s;
    }
    __syncthreads();
    float a1 = bfc1[t];
    for (int k = 0; k < DIM; ++k) a1 += row[k] * Wfc1[k * DIM + t];
    fc1[t] = fmaxf(a1, 0.f);
    __syncthreads();
    if (t < NUM_CLASSES) {
        float a = bfc2[t];
        for (int k = 0; k < DIM; ++k) a += fc1[k] * Wfc2[k * NUM_CLASSES + t];
        logits[t] = a;
    }
    __syncthreads();
    if (t == 0) {
        float mx = -INFINITY;
        for (int c2 = 0; c2 < NUM_CLASSES; ++c2) mx = fmaxf(mx, logits[c2]);
        float s = 0.f;
        for (int c2 = 0; c2 < NUM_CLASSES; ++c2) s += expf(logits[c2] - mx);
        red[0] = mx;
        red[1] = logf(s);
    }
    __syncthreads();
    if (t < NUM_CLASSES) out[g * NUM_CLASSES + t] = logits[t] - red[0] - red[1];
}

// ---------------- launch ----------------

extern "C" void kernel_launch(void* const* d_in, const int* in_sizes, int n_in,
                              void* d_out, int out_size, void* d_ws, size_t ws_size,
                              hipStream_t stream) {
    const float* x = (const float*)d_in[0];
    const int* ei = (const int*)d_in[1];
    const int* batch = (const int*)d_in[2];
    const float* ew = (const float*)d_in[3];
    const float *Wr[5], *br[5], *Wo[5];
    for (int i = 0; i < 5; ++i) {
        Wr[i] = (const float*)d_in[4 + 3 * i];
        br[i] = (const float*)d_in[5 + 3 * i];
        Wo[i] = (const float*)d_in[6 + 3 * i];
    }
    const float* Wfc1 = (const float*)d_in[19];
    const float* bfc1 = (const float*)d_in[20];
    const float* Wfc2 = (const float*)d_in[21];
    const float* bfc2 = (const float*)d_in[22];
    float* out = (float*)d_out;

    char* ws = (char*)d_ws;
    size_t off = 0;
    auto alloc = [&](size_t bytes) {
        void* p = ws + off;
        off += (bytes + 255) & ~(size_t)255;
        return p;
    };
    unsigned short* xb = (unsigned short*)alloc((size_t)N_NODES * F_IN * 2);
    unsigned short* h0 = (unsigned short*)alloc((size_t)N_NODES * DIM * 2);
    unsigned short* h1 = (unsigned short*)alloc((size_t)N_NODES * DIM * 2);
    unsigned short* aggb = (unsigned short*)alloc((size_t)N_NODES * DIM * 2);
    unsigned short* Bt[5];
    Bt[0] = (unsigned short*)alloc((size_t)2 * F_IN * DIM * 2);
    for (int i = 1; i < 5; ++i) Bt[i] = (unsigned short*)alloc((size_t)2 * DIM * DIM * 2);
    int* offs = (int*)alloc((N_NODES + 1) * 4);
    int* bcnt = (int*)alloc(NBKT * 4);
    int* bbase = (int*)alloc((NBKT + 1) * 4);
    int* gbase = (int*)alloc(NBKT * 4);
    uint2* edata = (uint2*)alloc((size_t)N_EDGES * 8);
    uint2* edata2 = (uint2*)alloc((size_t)N_EDGES * 8);

    const int* src = ei;
    const int* dstp = ei + N_EDGES;

    hipMemsetAsync(bcnt, 0, NBKT * 4, stream);
    bucket_hist<<<(N_EDGES + 4095) / 4096, 256, 0, stream>>>(dstp, bcnt, N_EDGES);
    scan_bkt<<<1, 256, 0, stream>>>(bcnt, bbase, gbase);
    bucket_scatter<<<(N_EDGES + 4095) / 4096, 256, 0, stream>>>(src, dstp, ew, gbase, edata2,
                                                                N_EDGES);
    bucket_sort<<<NBKT, 256, 0, stream>>>(bbase, edata2, edata, offs);

    conv_x<<<((N_NODES * F_IN / 4) + 255) / 256, 256, 0, stream>>>(x, xb, N_NODES * F_IN / 4);
    pack_w<<<(2 * F_IN * DIM + 255) / 256, 256, 0, stream>>>(Wr[0], Wo[0], Bt[0], F_IN);
    {
        dim3 pg((2 * DIM * DIM + 255) / 256, 4);
        pack_w4<<<pg, 256, 0, stream>>>(Wr[1], Wo[1], Wr[2], Wo[2], Wr[3], Wo[3], Wr[4], Wo[4],
                                        Bt[1], Bt[2], Bt[3], Bt[4]);
    }

    const int ggrid = ((NRT + 7) / 8) * 16;  // 16-block chunks of 8 rows x 2 cols

    // layer 1 (K = 128)
    agg_bf16<128><<<(N_NODES + 3) / 4, 256, 0, stream>>>(xb, offs, edata, aggb);
    gemm_mfma<128><<<ggrid, 256, 0, stream>>>(aggb, xb, Bt[0], br[0], h0);

    const unsigned short* hp = h0;
    unsigned short* hn = h1;
    for (int L = 1; L < 5; ++L) {
        agg_bf16<256><<<(N_NODES + 3) / 4, 256, 0, stream>>>(hp, offs, edata, aggb);
        gemm_mfma<256><<<ggrid, 256, 0, stream>>>(aggb, hp, Bt[L], br[L], hn);
        unsigned short* t2 = (unsigned short*)hp;
        hp = hn;
        hn = t2;
    }

    pool_head_kernel<<<NUM_GRAPHS, 256, 0, stream>>>(hp, batch, Wfc1, bfc1, Wfc2, bfc2, out);
}